// Round 3
// baseline (2778.402 us; speedup 1.0000x reference)
//
#include <hip/hip_runtime.h>

typedef unsigned short u16;
typedef short short8v __attribute__((ext_vector_type(8)));
typedef float f32x4 __attribute__((ext_vector_type(4)));

#define ALPHA_C 0.99f
#define NITER 24
#define WS_NEEDED 84463616UL

__device__ __forceinline__ u16 f2bf(float f){
  union { float f; unsigned u; } v; v.f = f;
  unsigned r = (v.u + 0x7FFFu + ((v.u >> 16) & 1u)) >> 16;
  return (u16)r;
}
__device__ __forceinline__ float bf2f(u16 u){
  union { unsigned u; float f; } v; v.u = ((unsigned)u) << 16;
  return v.f;
}

// block = 256 threads; full sum valid on thread 0 only
__device__ __forceinline__ float blockReduce256(float v){
  #pragma unroll
  for(int off=32; off>0; off>>=1) v += __shfl_down(v, off, 64);
  __shared__ float sm[4];
  int w = threadIdx.x >> 6;
  if((threadIdx.x & 63)==0) sm[w] = v;
  __syncthreads();
  return (threadIdx.x==0) ? (sm[0]+sm[1]+sm[2]+sm[3]) : 0.f;
}

__global__ void k_canary(float* out){ out[0] = 12345.0f; }

// ---- Wb (512x512 f32, [k][c]) -> Wbt bf16 [c][k] -------------------------
__global__ void k_wbt(const float* __restrict__ Wb, u16* __restrict__ Wbt){
  __shared__ float t[32][33];
  int bx = blockIdx.x & 15, by = blockIdx.x >> 4;
  int tx = threadIdx.x & 31, ty = threadIdx.x >> 5;  // 32 x 8
  #pragma unroll
  for(int i=0;i<32;i+=8)
    t[ty+i][tx] = Wb[(by*32+ty+i)*512 + bx*32+tx];
  __syncthreads();
  #pragma unroll
  for(int i=0;i<32;i+=8)
    Wbt[(bx*32+ty+i)*512 + by*32 + tx] = f2bf(t[tx][ty+i]);
}

// ---- f32 -> bf16 elementwise --------------------------------------------
__global__ void k_f2bf(const float* __restrict__ in, u16* __restrict__ out, int n){
  int i = blockIdx.x*256 + threadIdx.x;
  if(i < n) out[i] = f2bf(in[i]);
}

// ---- NT MFMA GEMM: C[m][n] = sum_k A[m][k]*B[n][k]; 128x128 tile, BK=64 --
// epi 0: write f -> probe/gal bf16 rows (u0=probe,u1=gal)
// epi 1: gg distances -> out f32 pairs (fo0=out_gg)
// epi 2: pg distances -> out ch1 f32 (fo0=out_pg) + RHS R (f0), f1=sq
// epi 3: matvec AP = Pd - alpha*(S@Pd): f0=AP, f1=Pd
__global__ void __launch_bounds__(256) k_gemm(
    int epi,
    const u16* __restrict__ A, const u16* __restrict__ B,
    int M, int N, int K,
    const float* __restrict__ nrmA, const float* __restrict__ nrmB,
    const float* __restrict__ gamma,
    u16* __restrict__ u0, u16* __restrict__ u1,
    float* __restrict__ fo0,
    float* __restrict__ f0, const float* __restrict__ f1)
{
  const int nbn = N >> 7;
  int bid = blockIdx.x;
  int brow = bid / nbn, bcol = bid % nbn;
  int t = threadIdx.x;
  int w = t >> 6, l = t & 63;
  int wr = w >> 1, wc = w & 1;
  const int l15 = l & 15, l16 = l >> 4;

  __shared__ __align__(16) u16 As[128*64];
  __shared__ __align__(16) u16 Bs[128*64];

  f32x4 acc[4][4] = {};

  for(int kt = 0; kt < K; kt += 64){
    #pragma unroll
    for(int pass=0; pass<4; ++pass){
      int chunk = pass*256 + t;          // 0..1023
      int row = chunk >> 3, co = (chunk & 7) * 8;
      *reinterpret_cast<short8v*>(&As[row*64+co]) =
        *reinterpret_cast<const short8v*>(&A[(size_t)(brow*128+row)*K + kt + co]);
      *reinterpret_cast<short8v*>(&Bs[row*64+co]) =
        *reinterpret_cast<const short8v*>(&B[(size_t)(bcol*128+row)*K + kt + co]);
    }
    __syncthreads();
    #pragma unroll
    for(int ks=0; ks<2; ++ks){
      short8v af[4], bfr[4];
      int ko = ks*32 + l16*8;
      #pragma unroll
      for(int i=0;i<4;i++){
        af[i]  = *reinterpret_cast<const short8v*>(&As[(wr*64+i*16+l15)*64 + ko]);
        bfr[i] = *reinterpret_cast<const short8v*>(&Bs[(wc*64+i*16+l15)*64 + ko]);
      }
      #pragma unroll
      for(int i=0;i<4;i++)
        #pragma unroll
        for(int j=0;j<4;j++)
          acc[i][j] = __builtin_amdgcn_mfma_f32_16x16x32_bf16(af[i], bfr[j], acc[i][j], 0,0,0);
    }
    __syncthreads();
  }

  float g0 = 0.f, g1 = 0.f;
  if(epi==1 || epi==2){ g0 = gamma[0]; g1 = gamma[1]; }

  #pragma unroll
  for(int i=0;i<4;i++)
  #pragma unroll
  for(int j=0;j<4;j++)
  #pragma unroll
  for(int r=0;r<4;r++){
    int m = brow*128 + wr*64 + i*16 + l16*4 + r;   // C row (A index)
    int n = bcol*128 + wc*64 + j*16 + l15;         // C col (B index)
    float c = acc[i][j][r];
    if(epi==0){
      if((m & 3) == 0) u0[(size_t)(m>>2)*512 + n] = f2bf(c);
      else             u1[(size_t)((m>>2)*3 + (m&3) - 1)*512 + n] = f2bf(c);
    } else if(epi==1){
      float d2 = (nrmA[m] + nrmB[n] - 2.f*c) * (1.f/512.f);
      float e  = __expf(-g0*d2);
      size_t base = ((size_t)m*3072 + n)*2;
      fo0[base]   = e;
      fo0[base+1] = g1*d2;
    } else if(epi==2){
      float d2 = (nrmA[m] + nrmB[n] - 2.f*c) * (1.f/512.f);
      float e  = __expf(-g0*d2);
      fo0[((size_t)m*3072 + n)*2 + 1] = g1*d2;
      f0[(size_t)m*3072 + n] = e * f1[n];           // RHS = sq[g]*P0
    } else {
      size_t idx = (size_t)m*3072 + n;
      f0[idx] = f1[idx] - ALPHA_C * c;              // AP = Pd - a*S@Pd
    }
  }
}

// ---- row norms of bf16-rounded f ----------------------------------------
__global__ void k_norms(const u16* __restrict__ probe, const u16* __restrict__ gal,
                        float* __restrict__ np_, float* __restrict__ ng){
  int row = blockIdx.x;
  const u16* src = (row < 1024) ? probe + (size_t)row*512
                                : gal + (size_t)(row-1024)*512;
  float s = 0.f;
  for(int i = threadIdx.x; i < 512; i += 256){ float v = bf2f(src[i]); s += v*v; }
  float r = blockReduce256(s);
  if(threadIdx.x==0){ if(row < 1024) np_[row] = r; else ng[row-1024] = r; }
}

// ---- off-diagonal row sums of K (f32 channel-0 of gg output) -------------
__global__ void k_rowsum(const float* __restrict__ gg, float* __restrict__ rs,
                         float* __restrict__ sq){
  int i = blockIdx.x;
  const float* row = gg + (size_t)i*3072*2;
  float s = 0.f;
  for(int j = threadIdx.x; j < 3072; j += 256) s += row[j*2];
  float r = blockReduce256(s);
  if(threadIdx.x==0){
    float d = r - row[i*2];
    rs[i] = rsqrtf(d); sq[i] = sqrtf(d);
  }
}

// ---- S_bf[i][j] = bf16(K_ij * rs[i] * rs[j]) -----------------------------
__global__ void k_makeS(const float* __restrict__ gg, const float* __restrict__ rs,
                        u16* __restrict__ S){
  int i = blockIdx.x;
  float ri = rs[i];
  for(int j = threadIdx.x; j < 3072; j += 256){
    size_t idx = (size_t)i*3072 + j;
    S[idx] = f2bf(gg[idx*2] * ri * rs[j]);
  }
}

// ---- CG init -------------------------------------------------------------
__global__ void k_init(const float* __restrict__ R, float* __restrict__ X,
                       float* __restrict__ Pdv, u16* __restrict__ Pdb, int n){
  int i = blockIdx.x*256 + threadIdx.x;
  if(i < n){ X[i] = 0.f; float r = R[i]; Pdv[i] = r; Pdb[i] = f2bf(r); }
}

// ---- per-probe dot -------------------------------------------------------
__global__ void k_coldot(const float* __restrict__ a, const float* __restrict__ b,
                         float* __restrict__ out){
  int p = blockIdx.x;
  float s = 0.f;
  for(int i = threadIdx.x; i < 3072; i += 256){
    size_t idx = (size_t)p*3072 + i;
    s += a[idx]*b[idx];
  }
  float r = blockReduce256(s);
  if(threadIdx.x==0) out[p] = r;
}

// ---- X += alpha*Pd; R -= alpha*AP ----------------------------------------
__global__ void k_updxr(float* __restrict__ X, float* __restrict__ R,
                        const float* __restrict__ Pd, const float* __restrict__ AP,
                        const float* __restrict__ rz, const float* __restrict__ pap){
  int p = blockIdx.x;
  float alpha = rz[p] / fmaxf(pap[p], 1e-30f);
  for(int i = threadIdx.x; i < 3072; i += 256){
    size_t idx = (size_t)p*3072 + i;
    X[idx] += alpha*Pd[idx];
    R[idx] -= alpha*AP[idx];
  }
}

// ---- beta; Pd = R + beta*Pd; refresh bf16 copy; rz <- rz2 ----------------
__global__ void k_updp(float* __restrict__ Pd, u16* __restrict__ Pdb,
                       const float* __restrict__ R,
                       float* __restrict__ rz, const float* __restrict__ rz2){
  int p = blockIdx.x;
  float rzv = rz[p], rz2v = rz2[p];
  float beta = rz2v / fmaxf(rzv, 1e-30f);
  __syncthreads();
  for(int i = threadIdx.x; i < 3072; i += 256){
    size_t idx = (size_t)p*3072 + i;
    float v = R[idx] + beta*Pd[idx];
    Pd[idx] = v; Pdb[idx] = f2bf(v);
  }
  if(threadIdx.x==0) rz[p] = rz2v;
}

// ---- final: out ch0 = (1-alpha) * X[p][g] * rs[g] ------------------------
__global__ void k_wpg(const float* __restrict__ X, const float* __restrict__ rs,
                      float* __restrict__ out){
  int p = blockIdx.x;
  for(int i = threadIdx.x; i < 3072; i += 256){
    size_t idx = (size_t)p*3072 + i;
    out[idx*2] = (1.0f - ALPHA_C) * X[idx] * rs[i];
  }
}

extern "C" void kernel_launch(void* const* d_in, const int* in_sizes, int n_in,
                              void* d_out, int out_size, void* d_ws, size_t ws_size,
                              hipStream_t stream){
  const float* x     = (const float*)d_in[0];   // 4096x512
  const float* Wb    = (const float*)d_in[1];   // 512x512
  const float* gamma = (const float*)d_in[2];   // 2
  (void)in_sizes; (void)n_in; (void)out_size;

  float* out    = (float*)d_out;
  float* out_pg = out;                                  // [1024][3072][2] f32
  float* out_gg = out + (size_t)1024*3072*2;            // [3072][3072][2] f32

  if(ws_size < WS_NEEDED){                              // diagnostic canary
    k_canary<<<1, 1, 0, stream>>>(out);
    return;
  }

  char* ws = (char*)d_ws;
  size_t off = 0;
  auto alloc = [&](size_t bytes)->char*{
    char* p = ws + off; off = (off + bytes + 255) & ~(size_t)255; return p;
  };
  u16*   xbf   = (u16*)  alloc((size_t)4096*512*2);
  u16*   wbt   = (u16*)  alloc((size_t)512*512*2);
  u16*   probe = (u16*)  alloc((size_t)1024*512*2);
  u16*   gal   = (u16*)  alloc((size_t)3072*512*2);
  float* np_   = (float*)alloc(1024*4);
  float* ng    = (float*)alloc(3072*4);
  float* rs    = (float*)alloc(3072*4);
  float* sq    = (float*)alloc(3072*4);
  float* rz    = (float*)alloc(1024*4);
  float* pap   = (float*)alloc(1024*4);
  float* rz2   = (float*)alloc(1024*4);
  u16*   Sbf   = (u16*)  alloc((size_t)3072*3072*2);
  float* R     = (float*)alloc((size_t)1024*3072*4);
  float* X     = (float*)alloc((size_t)1024*3072*4);
  float* Pd    = (float*)alloc((size_t)1024*3072*4);
  float* AP    = (float*)alloc((size_t)1024*3072*4);
  u16*   Pdb   = (u16*)  alloc((size_t)1024*3072*2);

  // 1. prep bf16 operands
  k_wbt <<<256, 256, 0, stream>>>(Wb, wbt);
  k_f2bf<<<8192, 256, 0, stream>>>(x, xbf, 4096*512);

  // 2. f = x@Wb, scattered into probe/gallery bf16 rows
  k_gemm<<<32*4, 256, 0, stream>>>(0, xbf, wbt, 4096, 512, 512,
      nullptr, nullptr, nullptr, probe, gal, nullptr, nullptr, nullptr);

  // 3. row norms
  k_norms<<<4096, 256, 0, stream>>>(probe, gal, np_, ng);

  // 4. gallery-gallery distances -> output f32 (both channels); K = ch0
  k_gemm<<<24*24, 256, 0, stream>>>(1, gal, gal, 3072, 3072, 512,
      ng, ng, gamma, nullptr, nullptr, out_gg, nullptr, nullptr);

  // 5. off-diagonal row sums -> rs=1/sqrt(d), sq=sqrt(d)
  k_rowsum<<<3072, 256, 0, stream>>>(out_gg, rs, sq);

  // 6. symmetrized random-walk matrix S (bf16)
  k_makeS<<<3072, 256, 0, stream>>>(out_gg, rs, Sbf);

  // 7. probe-gallery distances -> output ch1 + CG RHS (R = sq[g]*P0)
  k_gemm<<<8*24, 256, 0, stream>>>(2, probe, gal, 1024, 3072, 512,
      np_, ng, gamma, nullptr, nullptr, out_pg, R, sq);

  // 8. CG on (I - alpha*S) Z = R, 1024 simultaneous RHS
  k_init<<<(1024*3072+255)/256, 256, 0, stream>>>(R, X, Pd, Pdb, 1024*3072);
  k_coldot<<<1024, 256, 0, stream>>>(R, R, rz);
  for(int it = 0; it < NITER; ++it){
    k_gemm<<<8*24, 256, 0, stream>>>(3, Pdb, Sbf, 1024, 3072, 3072,
        nullptr, nullptr, nullptr, nullptr, nullptr, nullptr, AP, Pd);
    k_coldot<<<1024, 256, 0, stream>>>(Pd, AP, pap);
    k_updxr <<<1024, 256, 0, stream>>>(X, R, Pd, AP, rz, pap);
    k_coldot<<<1024, 256, 0, stream>>>(R, R, rz2);
    k_updp  <<<1024, 256, 0, stream>>>(Pd, Pdb, R, rz, rz2);
  }

  // 9. pg0 = (1-alpha) * Z^T * D^{-1/2}  -> output ch0
  k_wpg<<<1024, 256, 0, stream>>>(X, rs, out_pg);
}

// Round 4
// 1045.143 us; speedup vs baseline: 2.6584x; 2.6584x over previous
//
#include <hip/hip_runtime.h>

typedef unsigned short u16;
typedef short short8v __attribute__((ext_vector_type(8)));
typedef float f32x4 __attribute__((ext_vector_type(4)));

#define ALPHA_C 0.99f
#define NITER 10
#define WS_NEEDED 72000000UL

__device__ __forceinline__ u16 f2bf(float f){
  union { float f; unsigned u; } v; v.f = f;
  unsigned r = (v.u + 0x7FFFu + ((v.u >> 16) & 1u)) >> 16;
  return (u16)r;
}
__device__ __forceinline__ float bf2f(u16 u){
  union { unsigned u; float f; } v; v.u = ((unsigned)u) << 16;
  return v.f;
}

// block=256: full sum broadcast to ALL threads
__device__ __forceinline__ float blockSumBcast(float v){
  #pragma unroll
  for(int off=32; off>0; off>>=1) v += __shfl_down(v, off, 64);
  __shared__ float sm[4];
  __shared__ float res;
  int w = threadIdx.x >> 6;
  if((threadIdx.x & 63)==0) sm[w] = v;
  __syncthreads();
  if(threadIdx.x==0) res = sm[0]+sm[1]+sm[2]+sm[3];
  __syncthreads();
  return res;
}

__global__ void k_canary(float* out){ out[0] = 12345.0f; }

// ---- Wb (512x512 f32, [k][c]) -> Wbt bf16 [c][k] -------------------------
__global__ void k_wbt(const float* __restrict__ Wb, u16* __restrict__ Wbt){
  __shared__ float t[32][33];
  int bx = blockIdx.x & 15, by = blockIdx.x >> 4;
  int tx = threadIdx.x & 31, ty = threadIdx.x >> 5;  // 32 x 8
  #pragma unroll
  for(int i=0;i<32;i+=8)
    t[ty+i][tx] = Wb[(by*32+ty+i)*512 + bx*32+tx];
  __syncthreads();
  #pragma unroll
  for(int i=0;i<32;i+=8)
    Wbt[(bx*32+ty+i)*512 + by*32 + tx] = f2bf(t[tx][ty+i]);
}

// ---- f32 -> bf16 elementwise --------------------------------------------
__global__ void k_f2bf(const float* __restrict__ in, u16* __restrict__ out, int n){
  int i = blockIdx.x*256 + threadIdx.x;
  if(i < n) out[i] = f2bf(in[i]);
}

// ---- NT MFMA GEMM, 64x64 tile, BK=64, 4 waves (2x2 of 32x32) -------------
// epi 0: f scatter -> probe/gal bf16 rows (u0=probe,u1=gal); N=512
// epi 1: gg distances -> out_gg f32 pairs (fo0) + packed bf16 K (u0=Kb)
// epi 2: pg distances -> out_pg ch1 f32 (fo0) + RHS R=e*sq[n] (f0, f1=sq)
// epi 3: raw matvec c=K@Pdb -> SP (f0)
__global__ void __launch_bounds__(256) k_gemm(
    int epi,
    const u16* __restrict__ A, const u16* __restrict__ B,
    int K, int nbn,
    const float* __restrict__ nrmA, const float* __restrict__ nrmB,
    const float* __restrict__ gamma,
    u16* __restrict__ u0, u16* __restrict__ u1,
    float* __restrict__ fo0,
    float* __restrict__ f0, const float* __restrict__ f1)
{
  int bid = blockIdx.x;
  int brow = bid / nbn, bcol = bid % nbn;
  int t = threadIdx.x;
  int w = t >> 6, l = t & 63;
  int wr = w >> 1, wc = w & 1;
  const int l15 = l & 15, l16 = l >> 4;

  __shared__ __align__(16) u16 As[64*64];
  __shared__ __align__(16) u16 Bs[64*64];

  f32x4 acc[2][2] = {};

  for(int kt = 0; kt < K; kt += 64){
    #pragma unroll
    for(int pass=0; pass<2; ++pass){
      int c = pass*256 + t;              // 0..511
      int row = c >> 3, co = (c & 7) * 8;
      *reinterpret_cast<short8v*>(&As[row*64+co]) =
        *reinterpret_cast<const short8v*>(&A[(size_t)(brow*64+row)*K + kt + co]);
      *reinterpret_cast<short8v*>(&Bs[row*64+co]) =
        *reinterpret_cast<const short8v*>(&B[(size_t)(bcol*64+row)*K + kt + co]);
    }
    __syncthreads();
    #pragma unroll
    for(int ks=0; ks<2; ++ks){
      short8v af[2], bfr[2];
      int ko = ks*32 + l16*8;
      #pragma unroll
      for(int i=0;i<2;i++){
        af[i]  = *reinterpret_cast<const short8v*>(&As[(wr*32+i*16+l15)*64 + ko]);
        bfr[i] = *reinterpret_cast<const short8v*>(&Bs[(wc*32+i*16+l15)*64 + ko]);
      }
      #pragma unroll
      for(int i=0;i<2;i++)
        #pragma unroll
        for(int j=0;j<2;j++)
          acc[i][j] = __builtin_amdgcn_mfma_f32_16x16x32_bf16(af[i], bfr[j], acc[i][j], 0,0,0);
    }
    __syncthreads();
  }

  float g0 = 0.f, g1 = 0.f;
  if(epi==1 || epi==2){ g0 = gamma[0]; g1 = gamma[1]; }

  #pragma unroll
  for(int i=0;i<2;i++)
  #pragma unroll
  for(int j=0;j<2;j++)
  #pragma unroll
  for(int r=0;r<4;r++){
    int m = brow*64 + wr*32 + i*16 + l16*4 + r;   // C row (A index)
    int n = bcol*64 + wc*32 + j*16 + l15;         // C col (B index)
    float c = acc[i][j][r];
    if(epi==0){
      if((m & 3) == 0) u0[(size_t)(m>>2)*512 + n] = f2bf(c);
      else             u1[(size_t)((m>>2)*3 + (m&3) - 1)*512 + n] = f2bf(c);
    } else if(epi==1){
      float d2 = (nrmA[m] + nrmB[n] - 2.f*c) * (1.f/512.f);
      float e  = __expf(-g0*d2);
      size_t base = ((size_t)m*3072 + n)*2;
      fo0[base]   = e;
      fo0[base+1] = g1*d2;
      u0[(size_t)m*3072 + n] = f2bf(e);            // packed K for matvec
    } else if(epi==2){
      float d2 = (nrmA[m] + nrmB[n] - 2.f*c) * (1.f/512.f);
      float e  = __expf(-g0*d2);
      fo0[((size_t)m*3072 + n)*2 + 1] = g1*d2;
      f0[(size_t)m*3072 + n] = e * f1[n];           // RHS = sq[g]*P0
    } else {
      f0[(size_t)m*3072 + n] = c;                   // raw K@Pdb
    }
  }
}

// ---- row norms of bf16-rounded f ----------------------------------------
__global__ void k_norms(const u16* __restrict__ probe, const u16* __restrict__ gal,
                        float* __restrict__ np_, float* __restrict__ ng){
  int row = blockIdx.x;
  const u16* src = (row < 1024) ? probe + (size_t)row*512
                                : gal + (size_t)(row-1024)*512;
  float s = 0.f;
  for(int i = threadIdx.x; i < 512; i += 256){ float v = bf2f(src[i]); s += v*v; }
  float r = blockSumBcast(s);
  if(threadIdx.x==0){ if(row < 1024) np_[row] = r; else ng[row-1024] = r; }
}

// ---- off-diagonal row sums of packed bf16 K ------------------------------
__global__ void k_rowsum(const u16* __restrict__ Kb, float* __restrict__ rs,
                         float* __restrict__ sq){
  int i = blockIdx.x;
  const u16* row = Kb + (size_t)i*3072;
  float s = 0.f;
  for(int j = threadIdx.x; j < 3072; j += 256) s += bf2f(row[j]);
  float r = blockSumBcast(s);
  if(threadIdx.x==0){
    float d = r - bf2f(row[i]);
    rs[i] = rsqrtf(d); sq[i] = sqrtf(d);
  }
}

// ---- CG init: Pdb = bf16(rs*R), rz = R.R ---------------------------------
__global__ void k_init2(const float* __restrict__ R, u16* __restrict__ Pdb,
                        float* __restrict__ rz, const float* __restrict__ rs){
  int p = blockIdx.x, t = threadIdx.x;
  size_t base = (size_t)p*3072;
  float s = 0.f;
  #pragma unroll
  for(int j=0;j<12;j++){
    int g = t + j*256;
    float r = R[base+g];
    s += r*r;
    Pdb[base+g] = f2bf(rs[g]*r);
  }
  float tot = blockSumBcast(s);
  if(t==0) rz[p] = tot;
}

// ---- fused CG step (one block per probe, self-contained) -----------------
// pd = sq*bf(Pdb); ap = pd - a*rs*SP; pap; alpha; X,R update + rz2; beta; Pdb
__global__ void __launch_bounds__(256) k_cgstep(
    const float* __restrict__ SP, u16* __restrict__ Pdb,
    float* __restrict__ R, float* __restrict__ X,
    float* __restrict__ rz,
    const float* __restrict__ rs, const float* __restrict__ sq, int first)
{
  int p = blockIdx.x, t = threadIdx.x;
  size_t base = (size_t)p*3072;
  float pd[12], ap[12];
  float papp = 0.f;
  #pragma unroll
  for(int j=0;j<12;j++){
    int g = t + j*256;
    float pdv = sq[g] * bf2f(Pdb[base+g]);
    float spv = rs[g] * SP[base+g];
    pd[j] = pdv;
    ap[j] = pdv - ALPHA_C * spv;
    papp += pdv * ap[j];
  }
  float pap = blockSumBcast(papp);
  float rzv = rz[p];
  float a = rzv / fmaxf(pap, 1e-30f);
  float rn[12];
  float rz2p = 0.f;
  #pragma unroll
  for(int j=0;j<12;j++){
    int g = t + j*256;
    float rv = R[base+g] - a*ap[j];
    rn[j] = rv; rz2p += rv*rv;
    float xv = first ? a*pd[j] : X[base+g] + a*pd[j];
    X[base+g] = xv;
    R[base+g] = rv;
  }
  float rz2 = blockSumBcast(rz2p);
  float beta = rz2 / fmaxf(rzv, 1e-30f);
  #pragma unroll
  for(int j=0;j<12;j++){
    int g = t + j*256;
    float pdn = rn[j] + beta*pd[j];
    Pdb[base+g] = f2bf(rs[g]*pdn);
  }
  if(t==0) rz[p] = rz2;
}

// ---- final: out ch0 = (1-alpha) * X[p][g] * rs[g] ------------------------
__global__ void k_wpg(const float* __restrict__ X, const float* __restrict__ rs,
                      float* __restrict__ out){
  int p = blockIdx.x;
  for(int i = threadIdx.x; i < 3072; i += 256){
    size_t idx = (size_t)p*3072 + i;
    out[idx*2] = (1.0f - ALPHA_C) * X[idx] * rs[i];
  }
}

extern "C" void kernel_launch(void* const* d_in, const int* in_sizes, int n_in,
                              void* d_out, int out_size, void* d_ws, size_t ws_size,
                              hipStream_t stream){
  const float* x     = (const float*)d_in[0];   // 4096x512
  const float* Wb    = (const float*)d_in[1];   // 512x512
  const float* gamma = (const float*)d_in[2];   // 2
  (void)in_sizes; (void)n_in; (void)out_size;

  float* out    = (float*)d_out;
  float* out_pg = out;                                  // [1024][3072][2] f32
  float* out_gg = out + (size_t)1024*3072*2;            // [3072][3072][2] f32

  if(ws_size < WS_NEEDED){                              // diagnostic canary
    k_canary<<<1, 1, 0, stream>>>(out);
    return;
  }

  char* ws = (char*)d_ws;
  size_t off = 0;
  auto alloc = [&](size_t bytes)->char*{
    char* p = ws + off; off = (off + bytes + 255) & ~(size_t)255; return p;
  };
  u16*   xbf   = (u16*)  alloc((size_t)4096*512*2);
  u16*   wbt   = (u16*)  alloc((size_t)512*512*2);
  u16*   probe = (u16*)  alloc((size_t)1024*512*2);
  u16*   gal   = (u16*)  alloc((size_t)3072*512*2);
  u16*   Kb    = (u16*)  alloc((size_t)3072*3072*2);
  float* np_   = (float*)alloc(1024*4);
  float* ng    = (float*)alloc(3072*4);
  float* rs    = (float*)alloc(3072*4);
  float* sq    = (float*)alloc(3072*4);
  float* rz    = (float*)alloc(1024*4);
  float* R     = (float*)alloc((size_t)1024*3072*4);
  float* X     = (float*)alloc((size_t)1024*3072*4);
  float* SP    = (float*)alloc((size_t)1024*3072*4);
  u16*   Pdb   = (u16*)  alloc((size_t)1024*3072*2);

  // 1. prep bf16 operands
  k_wbt <<<256, 256, 0, stream>>>(Wb, wbt);
  k_f2bf<<<8192, 256, 0, stream>>>(x, xbf, 4096*512);

  // 2. f = x@Wb -> probe/gal bf16 rows   (64x8 = 512 blocks)
  k_gemm<<<512, 256, 0, stream>>>(0, xbf, wbt, 512, 8,
      nullptr, nullptr, nullptr, probe, gal, nullptr, nullptr, nullptr);

  // 3. row norms
  k_norms<<<4096, 256, 0, stream>>>(probe, gal, np_, ng);

  // 4. gg distances -> out_gg + packed K   (48x48 = 2304 blocks)
  k_gemm<<<2304, 256, 0, stream>>>(1, gal, gal, 512, 48,
      ng, ng, gamma, Kb, nullptr, out_gg, nullptr, nullptr);

  // 5. off-diag row sums -> rs = d^{-1/2}, sq = d^{1/2}
  k_rowsum<<<3072, 256, 0, stream>>>(Kb, rs, sq);

  // 6. pg distances -> out_pg ch1 + RHS R  (16x48 = 768 blocks)
  k_gemm<<<768, 256, 0, stream>>>(2, probe, gal, 512, 48,
      np_, ng, gamma, nullptr, nullptr, out_pg, R, sq);

  // 7. CG on (I - alpha*S), S folded via rs/sq scaling of vectors
  k_init2<<<1024, 256, 0, stream>>>(R, Pdb, rz, rs);
  for(int it = 0; it < NITER; ++it){
    k_gemm<<<768, 256, 0, stream>>>(3, Pdb, Kb, 3072, 48,
        nullptr, nullptr, nullptr, nullptr, nullptr, nullptr, SP, nullptr);
    k_cgstep<<<1024, 256, 0, stream>>>(SP, Pdb, R, X, rz, rs, sq, it==0 ? 1 : 0);
  }

  // 8. pg0 = (1-alpha) * X * rs  -> out ch0
  k_wpg<<<1024, 256, 0, stream>>>(X, rs, out_pg);
}

// Round 5
// 618.332 us; speedup vs baseline: 4.4934x; 1.6903x over previous
//
#include <hip/hip_runtime.h>

typedef unsigned short u16;
typedef short short8v __attribute__((ext_vector_type(8)));
typedef float f32x4 __attribute__((ext_vector_type(4)));

#define ALPHA_C 0.99f
#define NITER 8
#define WS_NEEDED 79740000UL

__device__ __forceinline__ u16 f2bf(float f){
  union { float f; unsigned u; } v; v.f = f;
  unsigned r = (v.u + 0x7FFFu + ((v.u >> 16) & 1u)) >> 16;
  return (u16)r;
}
__device__ __forceinline__ float bf2f(u16 u){
  union { unsigned u; float f; } v; v.u = ((unsigned)u) << 16;
  return v.f;
}

// async global->LDS, 16B per lane; lds dest must be wave-uniform base
__device__ __forceinline__ void gload16(const void* g, void* l){
  __builtin_amdgcn_global_load_lds(
    (const __attribute__((address_space(1))) unsigned*)g,
    (__attribute__((address_space(3))) unsigned*)l, 16, 0, 0);
}

// block=256: full sum broadcast to ALL threads
__device__ __forceinline__ float blockSumBcast(float v){
  #pragma unroll
  for(int off=32; off>0; off>>=1) v += __shfl_down(v, off, 64);
  __shared__ float sm[4];
  __shared__ float res;
  int w = threadIdx.x >> 6;
  if((threadIdx.x & 63)==0) sm[w] = v;
  __syncthreads();
  if(threadIdx.x==0) res = sm[0]+sm[1]+sm[2]+sm[3];
  __syncthreads();
  return res;
}

__global__ void k_canary(float* out){ out[0] = 12345.0f; }

// ---- Wb (512x512 f32, [k][c]) -> Wbt bf16 [c][k] -------------------------
__global__ void k_wbt(const float* __restrict__ Wb, u16* __restrict__ Wbt){
  __shared__ float t[32][33];
  int bx = blockIdx.x & 15, by = blockIdx.x >> 4;
  int tx = threadIdx.x & 31, ty = threadIdx.x >> 5;  // 32 x 8
  #pragma unroll
  for(int i=0;i<32;i+=8)
    t[ty+i][tx] = Wb[(by*32+ty+i)*512 + bx*32+tx];
  __syncthreads();
  #pragma unroll
  for(int i=0;i<32;i+=8)
    Wbt[(bx*32+ty+i)*512 + by*32 + tx] = f2bf(t[tx][ty+i]);
}

// ---- f32 -> bf16, 8 elems/thread ----------------------------------------
__global__ void k_f2bf8(const float* __restrict__ in, u16* __restrict__ out, int n8){
  int i = blockIdx.x*256 + threadIdx.x;
  if(i >= n8) return;
  f32x4 a = *reinterpret_cast<const f32x4*>(in + (size_t)i*8);
  f32x4 b = *reinterpret_cast<const f32x4*>(in + (size_t)i*8 + 4);
  short8v o;
  o[0]=(short)f2bf(a[0]); o[1]=(short)f2bf(a[1]); o[2]=(short)f2bf(a[2]); o[3]=(short)f2bf(a[3]);
  o[4]=(short)f2bf(b[0]); o[5]=(short)f2bf(b[1]); o[6]=(short)f2bf(b[2]); o[7]=(short)f2bf(b[3]);
  *reinterpret_cast<short8v*>(out + (size_t)i*8) = o;
}

// ---- NT MFMA GEMM, 128x128 tile, BK=64, 4 waves, global_load_lds staging -
// epi 0: f scatter -> probe/gal bf16 rows (u0=probe,u1=gal)
// epi 1: gg distances -> out_gg f32 pairs (fo0) + packed bf16 K (u0=Kb)
// epi 2: pg distances -> out_pg ch1 f32 (fo0) + RHS R=e*sq[n] (f0, f1=sq)
// epi 3: split-K matvec K@Pdb -> f0 + slice*1024*3072
__global__ void __launch_bounds__(256) k_gemm(
    int epi,
    const u16* __restrict__ A, const u16* __restrict__ B,
    int kld, int nbn, int bps, int kspan,
    const float* __restrict__ nrmA, const float* __restrict__ nrmB,
    const float* __restrict__ gamma,
    u16* __restrict__ u0, u16* __restrict__ u1,
    float* __restrict__ fo0,
    float* __restrict__ f0, const float* __restrict__ f1)
{
  int bid = blockIdx.x;
  int slice = bid / bps, rem = bid % bps;
  int brow = rem / nbn, bcol = rem % nbn;
  int t = threadIdx.x;
  int w = t >> 6, l = t & 63;
  int wr = w >> 1, wc = w & 1;
  const int l15 = l & 15, l16 = l >> 4;
  int k0 = slice * kspan;

  __shared__ __align__(16) u16 AB[2*128*64];   // A tile | B tile, 32 KB

  // staging role: waves 0,1 -> A halves; waves 2,3 -> B halves
  const u16* src = (w < 2) ? A + (size_t)brow*128*kld
                           : B + (size_t)bcol*128*kld;
  int half = w >> 1;            // 0 = A, 1 = B
  int wq   = (w & 1) * 8;       // chunk-call base within half

  f32x4 acc[4][4] = {};

  for(int kk = 0; kk < kspan; kk += 64){
    int kt = k0 + kk;
    #pragma unroll
    for(int q=0;q<8;q++){
      int cb  = (wq + q)*64;             // chunk base within half [0,1024)
      int idx = cb + l;                  // this lane's 16B chunk
      int row = idx >> 3, c8 = idx & 7;
      gload16(src + (size_t)row*kld + kt + c8*8,   // per-lane global src
              &AB[half*8192 + cb*8]);              // wave-uniform LDS dest
    }
    __syncthreads();                     // drains vmcnt before barrier
    #pragma unroll
    for(int ks=0; ks<2; ++ks){
      short8v af[4], bfr[4];
      int ko = ks*32 + l16*8;
      #pragma unroll
      for(int i=0;i<4;i++){
        af[i]  = *reinterpret_cast<const short8v*>(&AB[(wr*64+i*16+l15)*64 + ko]);
        bfr[i] = *reinterpret_cast<const short8v*>(&AB[8192 + (wc*64+i*16+l15)*64 + ko]);
      }
      #pragma unroll
      for(int i=0;i<4;i++)
        #pragma unroll
        for(int j=0;j<4;j++)
          acc[i][j] = __builtin_amdgcn_mfma_f32_16x16x32_bf16(af[i], bfr[j], acc[i][j], 0,0,0);
    }
    __syncthreads();
  }

  float g0 = 0.f, g1 = 0.f;
  if(epi==1 || epi==2){ g0 = gamma[0]; g1 = gamma[1]; }

  #pragma unroll
  for(int i=0;i<4;i++)
  #pragma unroll
  for(int j=0;j<4;j++)
  #pragma unroll
  for(int r=0;r<4;r++){
    int m = brow*128 + wr*64 + i*16 + l16*4 + r;   // C row (A index)
    int n = bcol*128 + wc*64 + j*16 + l15;         // C col (B index)
    float c = acc[i][j][r];
    if(epi==0){
      if((m & 3) == 0) u0[(size_t)(m>>2)*512 + n] = f2bf(c);
      else             u1[(size_t)((m>>2)*3 + (m&3) - 1)*512 + n] = f2bf(c);
    } else if(epi==1){
      float d2 = (nrmA[m] + nrmB[n] - 2.f*c) * (1.f/512.f);
      float e  = __expf(-g0*d2);
      size_t base = ((size_t)m*3072 + n)*2;
      fo0[base]   = e;
      fo0[base+1] = g1*d2;
      u0[(size_t)m*3072 + n] = f2bf(e);            // packed K for matvec
    } else if(epi==2){
      float d2 = (nrmA[m] + nrmB[n] - 2.f*c) * (1.f/512.f);
      float e  = __expf(-g0*d2);
      fo0[((size_t)m*3072 + n)*2 + 1] = g1*d2;
      f0[(size_t)m*3072 + n] = e * f1[n];           // RHS = sq[g]*P0
    } else {
      f0[(size_t)slice*1024*3072 + (size_t)m*3072 + n] = c;   // K@Pdb partial
    }
  }
}

// ---- row norms of bf16-rounded f ----------------------------------------
__global__ void k_norms(const u16* __restrict__ probe, const u16* __restrict__ gal,
                        float* __restrict__ np_, float* __restrict__ ng){
  int row = blockIdx.x;
  const u16* src = (row < 1024) ? probe + (size_t)row*512
                                : gal + (size_t)(row-1024)*512;
  float s = 0.f;
  for(int i = threadIdx.x; i < 512; i += 256){ float v = bf2f(src[i]); s += v*v; }
  float r = blockSumBcast(s);
  if(threadIdx.x==0){ if(row < 1024) np_[row] = r; else ng[row-1024] = r; }
}

// ---- off-diagonal row sums of packed bf16 K ------------------------------
__global__ void k_rowsum(const u16* __restrict__ Kb, float* __restrict__ rs,
                         float* __restrict__ sq){
  int i = blockIdx.x;
  const u16* row = Kb + (size_t)i*3072;
  float s = 0.f;
  for(int j = threadIdx.x; j < 3072; j += 256) s += bf2f(row[j]);
  float r = blockSumBcast(s);
  if(threadIdx.x==0){
    float d = r - bf2f(row[i]);
    rs[i] = rsqrtf(d); sq[i] = sqrtf(d);
  }
}

// ---- CG init: Pdb = bf16(rs*R), rz = R.R ---------------------------------
__global__ void k_init2(const float* __restrict__ R, u16* __restrict__ Pdb,
                        float* __restrict__ rz, const float* __restrict__ rs){
  int p = blockIdx.x, t = threadIdx.x;
  size_t base = (size_t)p*3072;
  float s = 0.f;
  #pragma unroll
  for(int j=0;j<12;j++){
    int g = t + j*256;
    float r = R[base+g];
    s += r*r;
    Pdb[base+g] = f2bf(rs[g]*r);
  }
  float tot = blockSumBcast(s);
  if(t==0) rz[p] = tot;
}

// ---- fused CG step; SP has 2 split-K partials ----------------------------
__global__ void __launch_bounds__(256) k_cgstep(
    const float* __restrict__ SP, u16* __restrict__ Pdb,
    float* __restrict__ R, float* __restrict__ X,
    float* __restrict__ rz,
    const float* __restrict__ rs, const float* __restrict__ sq, int first)
{
  const size_t SOFF = (size_t)1024*3072;
  int p = blockIdx.x, t = threadIdx.x;
  size_t base = (size_t)p*3072;
  float pd[12], ap[12];
  float papp = 0.f;
  #pragma unroll
  for(int j=0;j<12;j++){
    int g = t + j*256;
    float pdv = sq[g] * bf2f(Pdb[base+g]);
    float spv = SP[base+g] + SP[SOFF+base+g];
    pd[j] = pdv;
    ap[j] = pdv - ALPHA_C * (rs[g] * spv);
    papp += pdv * ap[j];
  }
  float pap = blockSumBcast(papp);
  float rzv = rz[p];
  float a = rzv / fmaxf(pap, 1e-30f);
  float rn[12];
  float rz2p = 0.f;
  #pragma unroll
  for(int j=0;j<12;j++){
    int g = t + j*256;
    float rv = R[base+g] - a*ap[j];
    rn[j] = rv; rz2p += rv*rv;
    float xv = first ? a*pd[j] : X[base+g] + a*pd[j];
    X[base+g] = xv;
    R[base+g] = rv;
  }
  float rz2 = blockSumBcast(rz2p);
  float beta = rz2 / fmaxf(rzv, 1e-30f);
  #pragma unroll
  for(int j=0;j<12;j++){
    int g = t + j*256;
    float pdn = rn[j] + beta*pd[j];
    Pdb[base+g] = f2bf(rs[g]*pdn);
  }
  if(t==0) rz[p] = rz2;
}

// ---- final: out ch0 = (1-alpha) * X[p][g] * rs[g] ------------------------
__global__ void k_wpg(const float* __restrict__ X, const float* __restrict__ rs,
                      float* __restrict__ out){
  int p = blockIdx.x;
  for(int i = threadIdx.x; i < 3072; i += 256){
    size_t idx = (size_t)p*3072 + i;
    out[idx*2] = (1.0f - ALPHA_C) * X[idx] * rs[i];
  }
}

extern "C" void kernel_launch(void* const* d_in, const int* in_sizes, int n_in,
                              void* d_out, int out_size, void* d_ws, size_t ws_size,
                              hipStream_t stream){
  const float* x     = (const float*)d_in[0];   // 4096x512
  const float* Wb    = (const float*)d_in[1];   // 512x512
  const float* gamma = (const float*)d_in[2];   // 2
  (void)in_sizes; (void)n_in; (void)out_size;

  float* out    = (float*)d_out;
  float* out_pg = out;                                  // [1024][3072][2] f32
  float* out_gg = out + (size_t)1024*3072*2;            // [3072][3072][2] f32

  if(ws_size < WS_NEEDED){                              // diagnostic canary
    k_canary<<<1, 1, 0, stream>>>(out);
    return;
  }

  char* ws = (char*)d_ws;
  size_t off = 0;
  auto alloc = [&](size_t bytes)->char*{
    char* p = ws + off; off = (off + bytes + 255) & ~(size_t)255; return p;
  };
  // regionA: xbf(4.19MB)+wbt(0.5MB) early, reused as R(12.6MB) later
  char*  regionA = alloc((size_t)1024*3072*4);
  u16*   xbf   = (u16*)regionA;
  u16*   wbt   = (u16*)(regionA + (size_t)4096*512*2);
  float* R     = (float*)regionA;
  u16*   probe = (u16*)  alloc((size_t)1024*512*2);
  u16*   gal   = (u16*)  alloc((size_t)3072*512*2);
  u16*   Kb    = (u16*)  alloc((size_t)3072*3072*2);
  float* np_   = (float*)alloc(1024*4);
  float* ng    = (float*)alloc(3072*4);
  float* rs    = (float*)alloc(3072*4);
  float* sq    = (float*)alloc(3072*4);
  float* rz    = (float*)alloc(1024*4);
  float* X     = (float*)alloc((size_t)1024*3072*4);
  float* SP    = (float*)alloc((size_t)2*1024*3072*4);  // 2 split-K partials
  u16*   Pdb   = (u16*)  alloc((size_t)1024*3072*2);

  // 1. prep bf16 operands
  k_wbt  <<<256, 256, 0, stream>>>(Wb, wbt);
  k_f2bf8<<<1024, 256, 0, stream>>>(x, xbf, 4096*512/8);

  // 2. f = x@Wb -> probe/gal bf16 rows   (32x4 = 128 blocks)
  k_gemm<<<128, 256, 0, stream>>>(0, xbf, wbt, 512, 4, 128, 512,
      nullptr, nullptr, nullptr, probe, gal, nullptr, nullptr, nullptr);

  // 3. row norms
  k_norms<<<4096, 256, 0, stream>>>(probe, gal, np_, ng);

  // 4. gg distances -> out_gg + packed K   (24x24 = 576 blocks)
  k_gemm<<<576, 256, 0, stream>>>(1, gal, gal, 512, 24, 576, 512,
      ng, ng, gamma, Kb, nullptr, out_gg, nullptr, nullptr);

  // 5. off-diag row sums -> rs = d^{-1/2}, sq = d^{1/2}
  k_rowsum<<<3072, 256, 0, stream>>>(Kb, rs, sq);

  // 6. pg distances -> out_pg ch1 + RHS R  (8x24 = 192 blocks)
  k_gemm<<<192, 256, 0, stream>>>(2, probe, gal, 512, 24, 192, 512,
      np_, ng, gamma, nullptr, nullptr, out_pg, R, sq);

  // 7. CG on (I - alpha*S); matvec split-K=2 -> 384 blocks
  k_init2<<<1024, 256, 0, stream>>>(R, Pdb, rz, rs);
  for(int it = 0; it < NITER; ++it){
    k_gemm<<<384, 256, 0, stream>>>(3, Pdb, Kb, 3072, 24, 192, 1536,
        nullptr, nullptr, nullptr, nullptr, nullptr, nullptr, SP, nullptr);
    k_cgstep<<<1024, 256, 0, stream>>>(SP, Pdb, R, X, rz, rs, sq, it==0 ? 1 : 0);
  }

  // 8. pg0 = (1-alpha) * X * rs  -> out ch0
  k_wpg<<<1024, 256, 0, stream>>>(X, rs, out_pg);
}

// Round 6
// 573.008 us; speedup vs baseline: 4.8488x; 1.0791x over previous
//
#include <hip/hip_runtime.h>

typedef unsigned short u16;
typedef short short8v __attribute__((ext_vector_type(8)));
typedef float f32x4 __attribute__((ext_vector_type(4)));
typedef unsigned short u16x4 __attribute__((ext_vector_type(4)));

#define ALPHA_C 0.99f
#define NITER 6
#define WS_NEEDED 56000000UL

__device__ __forceinline__ u16 f2bf(float f){
  union { float f; unsigned u; } v; v.f = f;
  unsigned r = (v.u + 0x7FFFu + ((v.u >> 16) & 1u)) >> 16;
  return (u16)r;
}
__device__ __forceinline__ float bf2f(u16 u){
  union { unsigned u; float f; } v; v.u = ((unsigned)u) << 16;
  return v.f;
}

// async global->LDS, 16B per lane; lds dest must be wave-uniform base
__device__ __forceinline__ void gload16(const void* g, void* l){
  __builtin_amdgcn_global_load_lds(
    (const __attribute__((address_space(1))) unsigned*)g,
    (__attribute__((address_space(3))) unsigned*)l, 16, 0, 0);
}

// block=256: full sum broadcast to ALL threads
__device__ __forceinline__ float blockSumBcast(float v){
  #pragma unroll
  for(int off=32; off>0; off>>=1) v += __shfl_down(v, off, 64);
  __shared__ float sm[4];
  __shared__ float res;
  int w = threadIdx.x >> 6;
  if((threadIdx.x & 63)==0) sm[w] = v;
  __syncthreads();
  if(threadIdx.x==0) res = sm[0]+sm[1]+sm[2]+sm[3];
  __syncthreads();
  return res;
}

__global__ void k_canary(float* out){ out[0] = 12345.0f; }

// ---- Wb (512x512 f32, [k][c]) -> Wbt bf16 [c][k] -------------------------
__global__ void k_wbt(const float* __restrict__ Wb, u16* __restrict__ Wbt){
  __shared__ float t[32][33];
  int bx = blockIdx.x & 15, by = blockIdx.x >> 4;
  int tx = threadIdx.x & 31, ty = threadIdx.x >> 5;  // 32 x 8
  #pragma unroll
  for(int i=0;i<32;i+=8)
    t[ty+i][tx] = Wb[(by*32+ty+i)*512 + bx*32+tx];
  __syncthreads();
  #pragma unroll
  for(int i=0;i<32;i+=8)
    Wbt[(bx*32+ty+i)*512 + by*32 + tx] = f2bf(t[tx][ty+i]);
}

// ---- f32 -> bf16, 8 elems/thread ----------------------------------------
__global__ void k_f2bf8(const float* __restrict__ in, u16* __restrict__ out, int n8){
  int i = blockIdx.x*256 + threadIdx.x;
  if(i >= n8) return;
  f32x4 a = *reinterpret_cast<const f32x4*>(in + (size_t)i*8);
  f32x4 b = *reinterpret_cast<const f32x4*>(in + (size_t)i*8 + 4);
  short8v o;
  o[0]=(short)f2bf(a[0]); o[1]=(short)f2bf(a[1]); o[2]=(short)f2bf(a[2]); o[3]=(short)f2bf(a[3]);
  o[4]=(short)f2bf(b[0]); o[5]=(short)f2bf(b[1]); o[6]=(short)f2bf(b[2]); o[7]=(short)f2bf(b[3]);
  *reinterpret_cast<short8v*>(out + (size_t)i*8) = o;
}

// ---- NT MFMA GEMM, 128x128 tile, BK=64, 4 waves, global_load_lds staging -
// epi 0: f scatter -> probe/gal bf16 rows (u0=probe,u1=gal)
// epi 1: gg distances -> packed bf16 K only (u0=Kb)
// epi 2: pg distances -> out_pg ch1 f32 (fo0) + RHS R=e*sq[n] (f0, f1=sq)
// epi 3: split-K matvec K@Pdb -> f0 + slice*1024*3072
__global__ void __launch_bounds__(256) k_gemm(
    int epi,
    const u16* __restrict__ A, const u16* __restrict__ B,
    int kld, int nbn, int bps, int kspan,
    const float* __restrict__ nrmA, const float* __restrict__ nrmB,
    const float* __restrict__ gamma,
    u16* __restrict__ u0, u16* __restrict__ u1,
    float* __restrict__ fo0,
    float* __restrict__ f0, const float* __restrict__ f1)
{
  int bid = blockIdx.x;
  int slice = bid / bps, rem = bid % bps;
  int brow = rem / nbn, bcol = rem % nbn;
  int t = threadIdx.x;
  int w = t >> 6, l = t & 63;
  int wr = w >> 1, wc = w & 1;
  const int l15 = l & 15, l16 = l >> 4;
  int k0 = slice * kspan;

  __shared__ __align__(16) u16 AB[2*128*64];   // A tile | B tile, 32 KB

  // staging role: waves 0,1 -> A halves; waves 2,3 -> B halves
  const u16* src = (w < 2) ? A + (size_t)brow*128*kld
                           : B + (size_t)bcol*128*kld;
  int half = w >> 1;            // 0 = A, 1 = B
  int wq   = (w & 1) * 8;       // chunk-call base within half

  f32x4 acc[4][4] = {};

  for(int kk = 0; kk < kspan; kk += 64){
    int kt = k0 + kk;
    #pragma unroll
    for(int q=0;q<8;q++){
      int cb  = (wq + q)*64;             // chunk base within half [0,1024)
      int idx = cb + l;                  // this lane's 16B chunk
      int row = idx >> 3, c8 = idx & 7;
      gload16(src + (size_t)row*kld + kt + c8*8,   // per-lane global src
              &AB[half*8192 + cb*8]);              // wave-uniform LDS dest
    }
    __syncthreads();                     // drains vmcnt before barrier
    #pragma unroll
    for(int ks=0; ks<2; ++ks){
      short8v af[4], bfr[4];
      int ko = ks*32 + l16*8;
      #pragma unroll
      for(int i=0;i<4;i++){
        af[i]  = *reinterpret_cast<const short8v*>(&AB[(wr*64+i*16+l15)*64 + ko]);
        bfr[i] = *reinterpret_cast<const short8v*>(&AB[8192 + (wc*64+i*16+l15)*64 + ko]);
      }
      #pragma unroll
      for(int i=0;i<4;i++)
        #pragma unroll
        for(int j=0;j<4;j++)
          acc[i][j] = __builtin_amdgcn_mfma_f32_16x16x32_bf16(af[i], bfr[j], acc[i][j], 0,0,0);
    }
    __syncthreads();
  }

  float g0 = 0.f, g1 = 0.f;
  if(epi==1 || epi==2){ g0 = gamma[0]; g1 = gamma[1]; }

  #pragma unroll
  for(int i=0;i<4;i++)
  #pragma unroll
  for(int j=0;j<4;j++)
  #pragma unroll
  for(int r=0;r<4;r++){
    int m = brow*128 + wr*64 + i*16 + l16*4 + r;   // C row (A index)
    int n = bcol*128 + wc*64 + j*16 + l15;         // C col (B index)
    float c = acc[i][j][r];
    if(epi==0){
      if((m & 3) == 0) u0[(size_t)(m>>2)*512 + n] = f2bf(c);
      else             u1[(size_t)((m>>2)*3 + (m&3) - 1)*512 + n] = f2bf(c);
    } else if(epi==1){
      float d2 = (nrmA[m] + nrmB[n] - 2.f*c) * (1.f/512.f);
      float e  = __expf(-g0*d2);
      u0[(size_t)m*3072 + n] = f2bf(e);            // packed K only
    } else if(epi==2){
      float d2 = (nrmA[m] + nrmB[n] - 2.f*c) * (1.f/512.f);
      float e  = __expf(-g0*d2);
      __builtin_nontemporal_store(g1*d2, &fo0[((size_t)m*3072 + n)*2 + 1]);
      f0[(size_t)m*3072 + n] = e * f1[n];           // RHS = sq[g]*P0
    } else {
      f0[(size_t)slice*1024*3072 + (size_t)m*3072 + n] = c;   // K@Pdb partial
    }
  }
}

// ---- row norms of bf16-rounded f ----------------------------------------
__global__ void k_norms(const u16* __restrict__ probe, const u16* __restrict__ gal,
                        float* __restrict__ np_, float* __restrict__ ng){
  int row = blockIdx.x;
  const u16* src = (row < 1024) ? probe + (size_t)row*512
                                : gal + (size_t)(row-1024)*512;
  float s = 0.f;
  for(int i = threadIdx.x; i < 512; i += 256){ float v = bf2f(src[i]); s += v*v; }
  float r = blockSumBcast(s);
  if(threadIdx.x==0){ if(row < 1024) np_[row] = r; else ng[row-1024] = r; }
}

// ---- off-diagonal row sums of packed bf16 K ------------------------------
__global__ void k_rowsum(const u16* __restrict__ Kb, float* __restrict__ rs,
                         float* __restrict__ sq){
  int i = blockIdx.x;
  const u16* row = Kb + (size_t)i*3072;
  float s = 0.f;
  for(int j = threadIdx.x; j < 3072; j += 256) s += bf2f(row[j]);
  float r = blockSumBcast(s);
  if(threadIdx.x==0){
    float d = r - bf2f(row[i]);
    rs[i] = rsqrtf(d); sq[i] = sqrtf(d);
  }
}

// ---- CG init: Pdb = bf16(rs*R), rz = R.R ---------------------------------
__global__ void k_init2(const float* __restrict__ R, u16* __restrict__ Pdb,
                        float* __restrict__ rz, const float* __restrict__ rs){
  int p = blockIdx.x, t = threadIdx.x;
  size_t base = (size_t)p*3072;
  float s = 0.f;
  #pragma unroll
  for(int j=0;j<12;j++){
    int g = t + j*256;
    float r = R[base+g];
    s += r*r;
    Pdb[base+g] = f2bf(rs[g]*r);
  }
  float tot = blockSumBcast(s);
  if(t==0) rz[p] = tot;
}

// ---- fused CG step; SP has 4 split-K partials ----------------------------
__global__ void __launch_bounds__(256) k_cgstep(
    const float* __restrict__ SP, u16* __restrict__ Pdb,
    float* __restrict__ R, float* __restrict__ X,
    float* __restrict__ rz,
    const float* __restrict__ rs, const float* __restrict__ sq, int first)
{
  const size_t SOFF = (size_t)1024*3072;
  int p = blockIdx.x, t = threadIdx.x;
  size_t base = (size_t)p*3072;
  float pd[12], ap[12];
  float papp = 0.f;
  #pragma unroll
  for(int j=0;j<12;j++){
    int g = t + j*256;
    float pdv = sq[g] * bf2f(Pdb[base+g]);
    float spv = (SP[base+g] + SP[SOFF+base+g])
              + (SP[2*SOFF+base+g] + SP[3*SOFF+base+g]);
    pd[j] = pdv;
    ap[j] = pdv - ALPHA_C * (rs[g] * spv);
    papp += pdv * ap[j];
  }
  float pap = blockSumBcast(papp);
  float rzv = rz[p];
  float a = rzv / fmaxf(pap, 1e-30f);
  float rn[12];
  float rz2p = 0.f;
  #pragma unroll
  for(int j=0;j<12;j++){
    int g = t + j*256;
    float rv = R[base+g] - a*ap[j];
    rn[j] = rv; rz2p += rv*rv;
    float xv = first ? a*pd[j] : X[base+g] + a*pd[j];
    X[base+g] = xv;
    R[base+g] = rv;
  }
  float rz2 = blockSumBcast(rz2p);
  float beta = rz2 / fmaxf(rzv, 1e-30f);
  #pragma unroll
  for(int j=0;j<12;j++){
    int g = t + j*256;
    float pdn = rn[j] + beta*pd[j];
    Pdb[base+g] = f2bf(rs[g]*pdn);
  }
  if(t==0) rz[p] = rz2;
}

// ---- final: out ch0 = (1-alpha) * X[p][g] * rs[g] ------------------------
__global__ void k_wpg(const float* __restrict__ X, const float* __restrict__ rs,
                      float* __restrict__ out){
  int p = blockIdx.x;
  for(int i = threadIdx.x; i < 3072; i += 256){
    size_t idx = (size_t)p*3072 + i;
    __builtin_nontemporal_store((1.0f - ALPHA_C) * X[idx] * rs[i], &out[idx*2]);
  }
}

// ---- final gg output: read Kb, emit (e, g1*d2) f32 pairs, coalesced ------
__global__ void k_ggout(const u16* __restrict__ Kb, float* __restrict__ gg,
                        const float* __restrict__ gamma, int n4){
  int i = blockIdx.x*256 + threadIdx.x;        // handles 4 elems
  if(i >= n4) return;
  float g0 = gamma[0], g1 = gamma[1];
  float ginv = -g1 / g0;                        // ch1 = g1*d2 = -g1/g0 * ln(e)
  u16x4 kv = *reinterpret_cast<const u16x4*>(Kb + (size_t)i*4);
  float e0 = bf2f(kv[0]), e1 = bf2f(kv[1]), e2 = bf2f(kv[2]), e3 = bf2f(kv[3]);
  f32x4 a, b;
  a[0] = e0; a[1] = ginv*__logf(e0);
  a[2] = e1; a[3] = ginv*__logf(e1);
  b[0] = e2; b[1] = ginv*__logf(e2);
  b[2] = e3; b[3] = ginv*__logf(e3);
  __builtin_nontemporal_store(a, reinterpret_cast<f32x4*>(gg + (size_t)i*8));
  __builtin_nontemporal_store(b, reinterpret_cast<f32x4*>(gg + (size_t)i*8 + 4));
}

extern "C" void kernel_launch(void* const* d_in, const int* in_sizes, int n_in,
                              void* d_out, int out_size, void* d_ws, size_t ws_size,
                              hipStream_t stream){
  const float* x     = (const float*)d_in[0];   // 4096x512
  const float* Wb    = (const float*)d_in[1];   // 512x512
  const float* gamma = (const float*)d_in[2];   // 2
  (void)in_sizes; (void)n_in; (void)out_size;

  float* out    = (float*)d_out;
  float* out_pg = out;                                  // [1024][3072][2] f32
  float* out_gg = out + (size_t)1024*3072*2;            // [3072][3072][2] f32
  float* SP     = out_gg;   // 4 split-K partials (50.3MB) live in out_gg (75.5MB)

  if(ws_size < WS_NEEDED){                              // diagnostic canary
    k_canary<<<1, 1, 0, stream>>>(out);
    return;
  }

  char* ws = (char*)d_ws;
  size_t off = 0;
  auto alloc = [&](size_t bytes)->char*{
    char* p = ws + off; off = (off + bytes + 255) & ~(size_t)255; return p;
  };
  // regionA: xbf(4.19MB)+wbt(0.5MB) early, reused as R(12.6MB) later
  char*  regionA = alloc((size_t)1024*3072*4);
  u16*   xbf   = (u16*)regionA;
  u16*   wbt   = (u16*)(regionA + (size_t)4096*512*2);
  float* R     = (float*)regionA;
  u16*   probe = (u16*)  alloc((size_t)1024*512*2);
  u16*   gal   = (u16*)  alloc((size_t)3072*512*2);
  u16*   Kb    = (u16*)  alloc((size_t)3072*3072*2);
  float* np_   = (float*)alloc(1024*4);
  float* ng    = (float*)alloc(3072*4);
  float* rs    = (float*)alloc(3072*4);
  float* sq    = (float*)alloc(3072*4);
  float* rz    = (float*)alloc(1024*4);
  float* X     = (float*)alloc((size_t)1024*3072*4);
  u16*   Pdb   = (u16*)  alloc((size_t)1024*3072*2);

  // 1. prep bf16 operands
  k_wbt  <<<256, 256, 0, stream>>>(Wb, wbt);
  k_f2bf8<<<1024, 256, 0, stream>>>(x, xbf, 4096*512/8);

  // 2. f = x@Wb -> probe/gal bf16 rows   (32x4 = 128 blocks)
  k_gemm<<<128, 256, 0, stream>>>(0, xbf, wbt, 512, 4, 128, 512,
      nullptr, nullptr, nullptr, probe, gal, nullptr, nullptr, nullptr);

  // 3. row norms
  k_norms<<<4096, 256, 0, stream>>>(probe, gal, np_, ng);

  // 4. gg distances -> packed bf16 K only  (24x24 = 576 blocks)
  k_gemm<<<576, 256, 0, stream>>>(1, gal, gal, 512, 24, 576, 512,
      ng, ng, gamma, Kb, nullptr, nullptr, nullptr, nullptr);

  // 5. off-diag row sums -> rs = d^{-1/2}, sq = d^{1/2}
  k_rowsum<<<3072, 256, 0, stream>>>(Kb, rs, sq);

  // 6. pg distances -> out_pg ch1 + RHS R  (8x24 = 192 blocks)
  k_gemm<<<192, 256, 0, stream>>>(2, probe, gal, 512, 24, 192, 512,
      np_, ng, gamma, nullptr, nullptr, out_pg, R, sq);

  // 7. CG on (I - alpha*S); matvec split-K=4 -> 768 blocks, SP in out_gg
  k_init2<<<1024, 256, 0, stream>>>(R, Pdb, rz, rs);
  for(int it = 0; it < NITER; ++it){
    k_gemm<<<768, 256, 0, stream>>>(3, Pdb, Kb, 3072, 24, 192, 768,
        nullptr, nullptr, nullptr, nullptr, nullptr, nullptr, SP, nullptr);
    k_cgstep<<<1024, 256, 0, stream>>>(SP, Pdb, R, X, rz, rs, sq, it==0 ? 1 : 0);
  }

  // 8. pg0 = (1-alpha) * X * rs  -> out ch0
  k_wpg<<<1024, 256, 0, stream>>>(X, rs, out_pg);

  // 9. regenerate gg output pairs from Kb (coalesced streaming writes)
  k_ggout<<<9216, 256, 0, stream>>>(Kb, out_gg, gamma, 3072*3072/4);
}

// Round 7
// 429.354 us; speedup vs baseline: 6.4711x; 1.3346x over previous
//
#include <hip/hip_runtime.h>

typedef unsigned short u16;
typedef short short8v __attribute__((ext_vector_type(8)));
typedef float f32x4 __attribute__((ext_vector_type(4)));
typedef unsigned short u16x4 __attribute__((ext_vector_type(4)));

#define ALPHA_C 0.99f
#define NITER 4
#define WS_NEEDED 67500000UL

__device__ __forceinline__ u16 f2bf(float f){
  union { float f; unsigned u; } v; v.f = f;
  unsigned r = (v.u + 0x7FFFu + ((v.u >> 16) & 1u)) >> 16;
  return (u16)r;
}
__device__ __forceinline__ float bf2f(u16 u){
  union { unsigned u; float f; } v; v.u = ((unsigned)u) << 16;
  return v.f;
}

// async global->LDS, 16B per lane; lds dest must be wave-uniform base
__device__ __forceinline__ void gload16(const void* g, void* l){
  __builtin_amdgcn_global_load_lds(
    (const __attribute__((address_space(1))) unsigned*)g,
    (__attribute__((address_space(3))) unsigned*)l, 16, 0, 0);
}

// block=256: full sum broadcast to ALL threads
__device__ __forceinline__ float blockSumBcast(float v){
  #pragma unroll
  for(int off=32; off>0; off>>=1) v += __shfl_down(v, off, 64);
  __shared__ float sm[4];
  __shared__ float res;
  int w = threadIdx.x >> 6;
  if((threadIdx.x & 63)==0) sm[w] = v;
  __syncthreads();
  if(threadIdx.x==0) res = sm[0]+sm[1]+sm[2]+sm[3];
  __syncthreads();
  return res;
}

__global__ void k_canary(float* out){ out[0] = 12345.0f; }

// ---- Wb (512x512 f32, [k][c]) -> Wbt bf16 [c][k] -------------------------
__global__ void k_wbt(const float* __restrict__ Wb, u16* __restrict__ Wbt){
  __shared__ float t[32][33];
  int bx = blockIdx.x & 15, by = blockIdx.x >> 4;
  int tx = threadIdx.x & 31, ty = threadIdx.x >> 5;  // 32 x 8
  #pragma unroll
  for(int i=0;i<32;i+=8)
    t[ty+i][tx] = Wb[(by*32+ty+i)*512 + bx*32+tx];
  __syncthreads();
  #pragma unroll
  for(int i=0;i<32;i+=8)
    Wbt[(bx*32+ty+i)*512 + by*32 + tx] = f2bf(t[tx][ty+i]);
}

// ---- f32 -> bf16, 8 elems/thread ----------------------------------------
__global__ void k_f2bf8(const float* __restrict__ in, u16* __restrict__ out, int n8){
  int i = blockIdx.x*256 + threadIdx.x;
  if(i >= n8) return;
  f32x4 a = *reinterpret_cast<const f32x4*>(in + (size_t)i*8);
  f32x4 b = *reinterpret_cast<const f32x4*>(in + (size_t)i*8 + 4);
  short8v o;
  o[0]=(short)f2bf(a[0]); o[1]=(short)f2bf(a[1]); o[2]=(short)f2bf(a[2]); o[3]=(short)f2bf(a[3]);
  o[4]=(short)f2bf(b[0]); o[5]=(short)f2bf(b[1]); o[6]=(short)f2bf(b[2]); o[7]=(short)f2bf(b[3]);
  *reinterpret_cast<short8v*>(out + (size_t)i*8) = o;
}

// ---- NT MFMA GEMM, 128x128 tile, BK=64, 4 waves, global_load_lds staging -
// epi 0: f scatter -> probe/gal bf16 rows (u0=probe,u1=gal)
// epi 1: gg distances -> packed bf16 K only (u0=Kb)
// epi 2: pg distances -> D2P=g1*d2 (fo0) + RHS R=e*sq[n] (f0, f1=sq)
// epi 3: split-K matvec K@Pdb -> f0 + slice*1024*3072
__global__ void __launch_bounds__(256) k_gemm(
    int epi,
    const u16* __restrict__ A, const u16* __restrict__ B,
    int kld, int nbn, int bps, int kspan,
    const float* __restrict__ nrmA, const float* __restrict__ nrmB,
    const float* __restrict__ gamma,
    u16* __restrict__ u0, u16* __restrict__ u1,
    float* __restrict__ fo0,
    float* __restrict__ f0, const float* __restrict__ f1)
{
  int bid = blockIdx.x;
  int slice = bid / bps, rem = bid % bps;
  int brow = rem / nbn, bcol = rem % nbn;
  int t = threadIdx.x;
  int w = t >> 6, l = t & 63;
  int wr = w >> 1, wc = w & 1;
  const int l15 = l & 15, l16 = l >> 4;
  int k0 = slice * kspan;

  __shared__ __align__(16) u16 AB[2*128*64];   // A tile | B tile, 32 KB

  // staging role: waves 0,1 -> A halves; waves 2,3 -> B halves
  const u16* src = (w < 2) ? A + (size_t)brow*128*kld
                           : B + (size_t)bcol*128*kld;
  int half = w >> 1;            // 0 = A, 1 = B
  int wq   = (w & 1) * 8;       // chunk-call base within half

  f32x4 acc[4][4] = {};

  for(int kk = 0; kk < kspan; kk += 64){
    int kt = k0 + kk;
    #pragma unroll
    for(int q=0;q<8;q++){
      int cb  = (wq + q)*64;             // chunk base within half [0,1024)
      int idx = cb + l;                  // this lane's 16B chunk
      int row = idx >> 3, c8 = idx & 7;
      gload16(src + (size_t)row*kld + kt + c8*8,   // per-lane global src
              &AB[half*8192 + cb*8]);              // wave-uniform LDS dest
    }
    __syncthreads();                     // drains vmcnt before barrier
    #pragma unroll
    for(int ks=0; ks<2; ++ks){
      short8v af[4], bfr[4];
      int ko = ks*32 + l16*8;
      #pragma unroll
      for(int i=0;i<4;i++){
        af[i]  = *reinterpret_cast<const short8v*>(&AB[(wr*64+i*16+l15)*64 + ko]);
        bfr[i] = *reinterpret_cast<const short8v*>(&AB[8192 + (wc*64+i*16+l15)*64 + ko]);
      }
      #pragma unroll
      for(int i=0;i<4;i++)
        #pragma unroll
        for(int j=0;j<4;j++)
          acc[i][j] = __builtin_amdgcn_mfma_f32_16x16x32_bf16(af[i], bfr[j], acc[i][j], 0,0,0);
    }
    __syncthreads();
  }

  float g0 = 0.f, g1 = 0.f;
  if(epi==1 || epi==2){ g0 = gamma[0]; g1 = gamma[1]; }

  #pragma unroll
  for(int i=0;i<4;i++)
  #pragma unroll
  for(int j=0;j<4;j++)
  #pragma unroll
  for(int r=0;r<4;r++){
    int m = brow*128 + wr*64 + i*16 + l16*4 + r;   // C row (A index)
    int n = bcol*128 + wc*64 + j*16 + l15;         // C col (B index)
    float c = acc[i][j][r];
    if(epi==0){
      if((m & 3) == 0) u0[(size_t)(m>>2)*512 + n] = f2bf(c);
      else             u1[(size_t)((m>>2)*3 + (m&3) - 1)*512 + n] = f2bf(c);
    } else if(epi==1){
      float d2 = (nrmA[m] + nrmB[n] - 2.f*c) * (1.f/512.f);
      float e  = __expf(-g0*d2);
      u0[(size_t)m*3072 + n] = f2bf(e);            // packed K only
    } else if(epi==2){
      float d2 = (nrmA[m] + nrmB[n] - 2.f*c) * (1.f/512.f);
      float e  = __expf(-g0*d2);
      fo0[(size_t)m*3072 + n] = g1*d2;              // D2P (contiguous)
      f0[(size_t)m*3072 + n] = e * f1[n];           // RHS = sq[g]*P0
    } else {
      f0[(size_t)slice*1024*3072 + (size_t)m*3072 + n] = c;   // K@Pdb partial
    }
  }
}

// ---- row norms of bf16-rounded f ----------------------------------------
__global__ void k_norms(const u16* __restrict__ probe, const u16* __restrict__ gal,
                        float* __restrict__ np_, float* __restrict__ ng){
  int row = blockIdx.x;
  const u16* src = (row < 1024) ? probe + (size_t)row*512
                                : gal + (size_t)(row-1024)*512;
  float s = 0.f;
  for(int i = threadIdx.x; i < 512; i += 256){ float v = bf2f(src[i]); s += v*v; }
  float r = blockSumBcast(s);
  if(threadIdx.x==0){ if(row < 1024) np_[row] = r; else ng[row-1024] = r; }
}

// ---- off-diagonal row sums of packed bf16 K ------------------------------
__global__ void k_rowsum(const u16* __restrict__ Kb, float* __restrict__ rs,
                         float* __restrict__ sq){
  int i = blockIdx.x;
  const u16* row = Kb + (size_t)i*3072;
  float s = 0.f;
  for(int j = threadIdx.x; j < 3072; j += 256) s += bf2f(row[j]);
  float r = blockSumBcast(s);
  if(threadIdx.x==0){
    float d = r - bf2f(row[i]);
    rs[i] = rsqrtf(d); sq[i] = sqrtf(d);
  }
}

// ---- CG init: Pdb = bf16(rs*R), rz = R.R ---------------------------------
__global__ void k_init2(const float* __restrict__ R, u16* __restrict__ Pdb,
                        float* __restrict__ rz, const float* __restrict__ rs){
  int p = blockIdx.x, t = threadIdx.x;
  size_t base = (size_t)p*3072;
  float s = 0.f;
  #pragma unroll
  for(int j=0;j<12;j++){
    int g = t + j*256;
    float r = R[base+g];
    s += r*r;
    Pdb[base+g] = f2bf(rs[g]*r);
  }
  float tot = blockSumBcast(s);
  if(t==0) rz[p] = tot;
}

// ---- fused CG step; SP has 4 split-K partials ----------------------------
__global__ void __launch_bounds__(256) k_cgstep(
    const float* __restrict__ SP, u16* __restrict__ Pdb,
    float* __restrict__ R, float* __restrict__ X,
    float* __restrict__ rz,
    const float* __restrict__ rs, const float* __restrict__ sq, int first)
{
  const size_t SOFF = (size_t)1024*3072;
  int p = blockIdx.x, t = threadIdx.x;
  size_t base = (size_t)p*3072;
  float pd[12], ap[12];
  float papp = 0.f;
  #pragma unroll
  for(int j=0;j<12;j++){
    int g = t + j*256;
    float pdv = sq[g] * bf2f(Pdb[base+g]);
    float spv = (SP[base+g] + SP[SOFF+base+g])
              + (SP[2*SOFF+base+g] + SP[3*SOFF+base+g]);
    pd[j] = pdv;
    ap[j] = pdv - ALPHA_C * (rs[g] * spv);
    papp += pdv * ap[j];
  }
  float pap = blockSumBcast(papp);
  float rzv = rz[p];
  float a = rzv / fmaxf(pap, 1e-30f);
  float rn[12];
  float rz2p = 0.f;
  #pragma unroll
  for(int j=0;j<12;j++){
    int g = t + j*256;
    float rv = R[base+g] - a*ap[j];
    rn[j] = rv; rz2p += rv*rv;
    float xv = first ? a*pd[j] : X[base+g] + a*pd[j];
    X[base+g] = xv;
    R[base+g] = rv;
  }
  float rz2 = blockSumBcast(rz2p);
  float beta = rz2 / fmaxf(rzv, 1e-30f);
  #pragma unroll
  for(int j=0;j<12;j++){
    int g = t + j*256;
    float pdn = rn[j] + beta*pd[j];
    Pdb[base+g] = f2bf(rs[g]*pdn);
  }
  if(t==0) rz[p] = rz2;
}

// ---- final pg: both channels, coalesced f32x4 (2 pairs/thread) -----------
__global__ void k_wpg2(const float* __restrict__ X, const float* __restrict__ d2p,
                       const float* __restrict__ rs, float* __restrict__ out, int n2){
  int i = blockIdx.x*256 + threadIdx.x;        // 2 consecutive elements
  if(i >= n2) return;
  size_t idx = (size_t)i*2;
  int g = (int)(idx % 3072);                   // 3072 even -> no row crossing
  f32x4 o;
  o[0] = (1.0f - ALPHA_C) * X[idx]   * rs[g];
  o[1] = d2p[idx];
  o[2] = (1.0f - ALPHA_C) * X[idx+1] * rs[g+1];
  o[3] = d2p[idx+1];
  __builtin_nontemporal_store(o, reinterpret_cast<f32x4*>(out + idx*2));
}

// ---- final gg output: read Kb, emit (e, g1*d2) f32 pairs, coalesced ------
__global__ void k_ggout(const u16* __restrict__ Kb, float* __restrict__ gg,
                        const float* __restrict__ gamma, int n4){
  int i = blockIdx.x*256 + threadIdx.x;        // handles 4 elems
  if(i >= n4) return;
  float g0 = gamma[0], g1 = gamma[1];
  float ginv = -g1 / g0;                        // ch1 = g1*d2 = -g1/g0 * ln(e)
  u16x4 kv = *reinterpret_cast<const u16x4*>(Kb + (size_t)i*4);
  float e0 = bf2f(kv[0]), e1 = bf2f(kv[1]), e2 = bf2f(kv[2]), e3 = bf2f(kv[3]);
  f32x4 a, b;
  a[0] = e0; a[1] = ginv*__logf(e0);
  a[2] = e1; a[3] = ginv*__logf(e1);
  b[0] = e2; b[1] = ginv*__logf(e2);
  b[2] = e3; b[3] = ginv*__logf(e3);
  __builtin_nontemporal_store(a, reinterpret_cast<f32x4*>(gg + (size_t)i*8));
  __builtin_nontemporal_store(b, reinterpret_cast<f32x4*>(gg + (size_t)i*8 + 4));
}

extern "C" void kernel_launch(void* const* d_in, const int* in_sizes, int n_in,
                              void* d_out, int out_size, void* d_ws, size_t ws_size,
                              hipStream_t stream){
  const float* x     = (const float*)d_in[0];   // 4096x512
  const float* Wb    = (const float*)d_in[1];   // 512x512
  const float* gamma = (const float*)d_in[2];   // 2
  (void)in_sizes; (void)n_in; (void)out_size;

  float* out    = (float*)d_out;
  float* out_pg = out;                                  // [1024][3072][2] f32
  float* out_gg = out + (size_t)1024*3072*2;            // [3072][3072][2] f32
  float* SP     = out_gg;   // 4 split-K partials (50.3MB) live in out_gg (75.5MB)

  if(ws_size < WS_NEEDED){                              // diagnostic canary
    k_canary<<<1, 1, 0, stream>>>(out);
    return;
  }

  char* ws = (char*)d_ws;
  size_t off = 0;
  auto alloc = [&](size_t bytes)->char*{
    char* p = ws + off; off = (off + bytes + 255) & ~(size_t)255; return p;
  };
  // regionA: xbf(4.19MB)+wbt(0.5MB) early, reused as R(12.6MB) later
  char*  regionA = alloc((size_t)1024*3072*4);
  u16*   xbf   = (u16*)regionA;
  u16*   wbt   = (u16*)(regionA + (size_t)4096*512*2);
  float* R     = (float*)regionA;
  u16*   probe = (u16*)  alloc((size_t)1024*512*2);
  u16*   gal   = (u16*)  alloc((size_t)3072*512*2);
  u16*   Kb    = (u16*)  alloc((size_t)3072*3072*2);
  float* np_   = (float*)alloc(1024*4);
  float* ng    = (float*)alloc(3072*4);
  float* rs    = (float*)alloc(3072*4);
  float* sq    = (float*)alloc(3072*4);
  float* rz    = (float*)alloc(1024*4);
  float* X     = (float*)alloc((size_t)1024*3072*4);
  float* D2P   = (float*)alloc((size_t)1024*3072*4);
  u16*   Pdb   = (u16*)  alloc((size_t)1024*3072*2);

  // 1. prep bf16 operands
  k_wbt  <<<256, 256, 0, stream>>>(Wb, wbt);
  k_f2bf8<<<1024, 256, 0, stream>>>(x, xbf, 4096*512/8);

  // 2. f = x@Wb -> probe/gal bf16 rows   (32x4 = 128 blocks)
  k_gemm<<<128, 256, 0, stream>>>(0, xbf, wbt, 512, 4, 128, 512,
      nullptr, nullptr, nullptr, probe, gal, nullptr, nullptr, nullptr);

  // 3. row norms
  k_norms<<<4096, 256, 0, stream>>>(probe, gal, np_, ng);

  // 4. gg distances -> packed bf16 K only  (24x24 = 576 blocks)
  k_gemm<<<576, 256, 0, stream>>>(1, gal, gal, 512, 24, 576, 512,
      ng, ng, gamma, Kb, nullptr, nullptr, nullptr, nullptr);

  // 5. off-diag row sums -> rs = d^{-1/2}, sq = d^{1/2}
  k_rowsum<<<3072, 256, 0, stream>>>(Kb, rs, sq);

  // 6. pg distances -> D2P + RHS R  (8x24 = 192 blocks)
  k_gemm<<<192, 256, 0, stream>>>(2, probe, gal, 512, 24, 192, 512,
      np_, ng, gamma, nullptr, nullptr, D2P, R, sq);

  // 7. CG on (I - alpha*S); matvec split-K=4 -> 768 blocks, SP in out_gg
  k_init2<<<1024, 256, 0, stream>>>(R, Pdb, rz, rs);
  for(int it = 0; it < NITER; ++it){
    k_gemm<<<768, 256, 0, stream>>>(3, Pdb, Kb, 3072, 24, 192, 768,
        nullptr, nullptr, nullptr, nullptr, nullptr, nullptr, SP, nullptr);
    k_cgstep<<<1024, 256, 0, stream>>>(SP, Pdb, R, X, rz, rs, sq, it==0 ? 1 : 0);
  }

  // 8. pg output: both channels coalesced
  k_wpg2<<<6144, 256, 0, stream>>>(X, D2P, rs, out_pg, 1024*3072/2);

  // 9. regenerate gg output pairs from Kb (coalesced streaming writes)
  k_ggout<<<9216, 256, 0, stream>>>(Kb, out_gg, gamma, 3072*3072/4);
}

// Round 8
// 339.291 us; speedup vs baseline: 8.1888x; 1.2654x over previous
//
#include <hip/hip_runtime.h>

typedef unsigned short u16;
typedef short short8v __attribute__((ext_vector_type(8)));
typedef float f32x4 __attribute__((ext_vector_type(4)));
typedef unsigned short u16x4 __attribute__((ext_vector_type(4)));

#define ALPHA_C 0.99f
#define NITER 3
#define WS_NEEDED 67500000UL

__device__ __forceinline__ u16 f2bf(float f){
  union { float f; unsigned u; } v; v.f = f;
  unsigned r = (v.u + 0x7FFFu + ((v.u >> 16) & 1u)) >> 16;
  return (u16)r;
}
__device__ __forceinline__ float bf2f(u16 u){
  union { unsigned u; float f; } v; v.u = ((unsigned)u) << 16;
  return v.f;
}

// async global->LDS, 16B per lane; lds dest must be wave-uniform base
__device__ __forceinline__ void gload16(const void* g, void* l){
  __builtin_amdgcn_global_load_lds(
    (const __attribute__((address_space(1))) unsigned*)g,
    (__attribute__((address_space(3))) unsigned*)l, 16, 0, 0);
}

// block=256: full sum broadcast to ALL threads
__device__ __forceinline__ float blockSumBcast(float v){
  #pragma unroll
  for(int off=32; off>0; off>>=1) v += __shfl_down(v, off, 64);
  __shared__ float sm[4];
  __shared__ float res;
  int w = threadIdx.x >> 6;
  if((threadIdx.x & 63)==0) sm[w] = v;
  __syncthreads();
  if(threadIdx.x==0) res = sm[0]+sm[1]+sm[2]+sm[3];
  __syncthreads();
  return res;
}

__global__ void k_canary(float* out){ out[0] = 12345.0f; }

// ---- Wb (512x512 f32, [k][c]) -> Wbt bf16 [c][k] -------------------------
__global__ void k_wbt(const float* __restrict__ Wb, u16* __restrict__ Wbt){
  __shared__ float t[32][33];
  int bx = blockIdx.x & 15, by = blockIdx.x >> 4;
  int tx = threadIdx.x & 31, ty = threadIdx.x >> 5;  // 32 x 8
  #pragma unroll
  for(int i=0;i<32;i+=8)
    t[ty+i][tx] = Wb[(by*32+ty+i)*512 + bx*32+tx];
  __syncthreads();
  #pragma unroll
  for(int i=0;i<32;i+=8)
    Wbt[(bx*32+ty+i)*512 + by*32 + tx] = f2bf(t[tx][ty+i]);
}

// ---- f32 -> bf16, 8 elems/thread ----------------------------------------
__global__ void k_f2bf8(const float* __restrict__ in, u16* __restrict__ out, int n8){
  int i = blockIdx.x*256 + threadIdx.x;
  if(i >= n8) return;
  f32x4 a = *reinterpret_cast<const f32x4*>(in + (size_t)i*8);
  f32x4 b = *reinterpret_cast<const f32x4*>(in + (size_t)i*8 + 4);
  short8v o;
  o[0]=(short)f2bf(a[0]); o[1]=(short)f2bf(a[1]); o[2]=(short)f2bf(a[2]); o[3]=(short)f2bf(a[3]);
  o[4]=(short)f2bf(b[0]); o[5]=(short)f2bf(b[1]); o[6]=(short)f2bf(b[2]); o[7]=(short)f2bf(b[3]);
  *reinterpret_cast<short8v*>(out + (size_t)i*8) = o;
}

// ---- NT MFMA GEMM, 128x128 tile, BK=64, 4 waves, global_load_lds staging -
// epi 0: f scatter -> probe/gal bf16 rows (u0=probe,u1=gal)
// epi 1: gg distances -> packed bf16 K only (u0=Kb)
// epi 2: pg distances -> D2P=g1*d2 (fo0) + E=exp(-g0*d2) (f0)
// epi 3: split-K matvec K@Pdb -> f0 + slice*1024*3072
// epi 4: MERGED gg+pg: blocks [0,576) = epi1; [576,768) = epi2 with
//        A=u1(probe), nrmA=f1(np_)
__global__ void __launch_bounds__(256) k_gemm(
    int epi,
    const u16* __restrict__ A, const u16* __restrict__ B,
    int kld, int nbn, int bps, int kspan,
    const float* __restrict__ nrmA, const float* __restrict__ nrmB,
    const float* __restrict__ gamma,
    u16* __restrict__ u0, u16* __restrict__ u1,
    float* __restrict__ fo0,
    float* __restrict__ f0, const float* __restrict__ f1)
{
  int bid = blockIdx.x;
  int slice = bid / bps, rem = bid % bps;
  if(epi==4){
    slice = 0;
    if(bid < 576){ epi = 1; rem = bid; }
    else { epi = 2; rem = bid - 576; A = u1; nrmA = f1; }
  }
  int brow = rem / nbn, bcol = rem % nbn;
  int t = threadIdx.x;
  int w = t >> 6, l = t & 63;
  int wr = w >> 1, wc = w & 1;
  const int l15 = l & 15, l16 = l >> 4;
  int k0 = slice * kspan;

  __shared__ __align__(16) u16 AB[2*128*64];   // A tile | B tile, 32 KB

  // staging role: waves 0,1 -> A halves; waves 2,3 -> B halves
  const u16* src = (w < 2) ? A + (size_t)brow*128*kld
                           : B + (size_t)bcol*128*kld;
  int half = w >> 1;            // 0 = A, 1 = B
  int wq   = (w & 1) * 8;       // chunk-call base within half

  f32x4 acc[4][4] = {};

  for(int kk = 0; kk < kspan; kk += 64){
    int kt = k0 + kk;
    #pragma unroll
    for(int q=0;q<8;q++){
      int cb  = (wq + q)*64;             // chunk base within half [0,1024)
      int idx = cb + l;                  // this lane's 16B chunk
      int row = idx >> 3, c8 = idx & 7;
      gload16(src + (size_t)row*kld + kt + c8*8,   // per-lane global src
              &AB[half*8192 + cb*8]);              // wave-uniform LDS dest
    }
    __syncthreads();                     // drains vmcnt before barrier
    #pragma unroll
    for(int ks=0; ks<2; ++ks){
      short8v af[4], bfr[4];
      int ko = ks*32 + l16*8;
      #pragma unroll
      for(int i=0;i<4;i++){
        af[i]  = *reinterpret_cast<const short8v*>(&AB[(wr*64+i*16+l15)*64 + ko]);
        bfr[i] = *reinterpret_cast<const short8v*>(&AB[8192 + (wc*64+i*16+l15)*64 + ko]);
      }
      #pragma unroll
      for(int i=0;i<4;i++)
        #pragma unroll
        for(int j=0;j<4;j++)
          acc[i][j] = __builtin_amdgcn_mfma_f32_16x16x32_bf16(af[i], bfr[j], acc[i][j], 0,0,0);
    }
    __syncthreads();
  }

  float g0 = 0.f, g1 = 0.f;
  if(epi==1 || epi==2){ g0 = gamma[0]; g1 = gamma[1]; }

  #pragma unroll
  for(int i=0;i<4;i++)
  #pragma unroll
  for(int j=0;j<4;j++)
  #pragma unroll
  for(int r=0;r<4;r++){
    int m = brow*128 + wr*64 + i*16 + l16*4 + r;   // C row (A index)
    int n = bcol*128 + wc*64 + j*16 + l15;         // C col (B index)
    float c = acc[i][j][r];
    if(epi==0){
      if((m & 3) == 0) u0[(size_t)(m>>2)*512 + n] = f2bf(c);
      else             u1[(size_t)((m>>2)*3 + (m&3) - 1)*512 + n] = f2bf(c);
    } else if(epi==1){
      float d2 = (nrmA[m] + nrmB[n] - 2.f*c) * (1.f/512.f);
      float e  = __expf(-g0*d2);
      u0[(size_t)m*3072 + n] = f2bf(e);            // packed K only
    } else if(epi==2){
      float d2 = (nrmA[m] + nrmB[n] - 2.f*c) * (1.f/512.f);
      float e  = __expf(-g0*d2);
      fo0[(size_t)m*3072 + n] = g1*d2;              // D2P (contiguous)
      f0[(size_t)m*3072 + n] = e;                   // E (unscaled)
    } else {
      f0[(size_t)slice*1024*3072 + (size_t)m*3072 + n] = c;   // K@Pdb partial
    }
  }
}

// ---- row norms of bf16-rounded f ----------------------------------------
__global__ void k_norms(const u16* __restrict__ probe, const u16* __restrict__ gal,
                        float* __restrict__ np_, float* __restrict__ ng){
  int row = blockIdx.x;
  const u16* src = (row < 1024) ? probe + (size_t)row*512
                                : gal + (size_t)(row-1024)*512;
  float s = 0.f;
  for(int i = threadIdx.x; i < 512; i += 256){ float v = bf2f(src[i]); s += v*v; }
  float r = blockSumBcast(s);
  if(threadIdx.x==0){ if(row < 1024) np_[row] = r; else ng[row-1024] = r; }
}

// ---- off-diagonal row sums of packed bf16 K ------------------------------
__global__ void k_rowsum(const u16* __restrict__ Kb, float* __restrict__ rs,
                         float* __restrict__ sq){
  int i = blockIdx.x;
  const u16* row = Kb + (size_t)i*3072;
  float s = 0.f;
  for(int j = threadIdx.x; j < 3072; j += 256) s += bf2f(row[j]);
  float r = blockSumBcast(s);
  if(threadIdx.x==0){
    float d = r - bf2f(row[i]);
    rs[i] = rsqrtf(d); sq[i] = sqrtf(d);
  }
}

// ---- CG init from E: R = sq*E, Pdb = bf16(rs*R) = bf16(E), rz = R.R ------
__global__ void k_rzinit(const float* __restrict__ E, const float* __restrict__ sq,
                         float* __restrict__ R, u16* __restrict__ Pdb,
                         float* __restrict__ rz){
  int p = blockIdx.x, t = threadIdx.x;
  size_t base = (size_t)p*3072;
  float s = 0.f;
  #pragma unroll
  for(int j=0;j<12;j++){
    int g = t + j*256;
    float e = E[base+g];
    float r = sq[g]*e;
    R[base+g] = r;
    Pdb[base+g] = f2bf(e);      // rs[g]*r == e exactly
    s += r*r;
  }
  float tot = blockSumBcast(s);
  if(t==0) rz[p] = tot;
}

// ---- fused CG step; SP has 4 split-K partials ----------------------------
__global__ void __launch_bounds__(256) k_cgstep(
    const float* __restrict__ SP, u16* __restrict__ Pdb,
    float* __restrict__ R, float* __restrict__ X,
    float* __restrict__ rz,
    const float* __restrict__ rs, const float* __restrict__ sq, int first)
{
  const size_t SOFF = (size_t)1024*3072;
  int p = blockIdx.x, t = threadIdx.x;
  size_t base = (size_t)p*3072;
  float pd[12], ap[12];
  float papp = 0.f;
  #pragma unroll
  for(int j=0;j<12;j++){
    int g = t + j*256;
    float pdv = sq[g] * bf2f(Pdb[base+g]);
    float spv = (SP[base+g] + SP[SOFF+base+g])
              + (SP[2*SOFF+base+g] + SP[3*SOFF+base+g]);
    pd[j] = pdv;
    ap[j] = pdv - ALPHA_C * (rs[g] * spv);
    papp += pdv * ap[j];
  }
  float pap = blockSumBcast(papp);
  float rzv = rz[p];
  float a = rzv / fmaxf(pap, 1e-30f);
  float rn[12];
  float rz2p = 0.f;
  #pragma unroll
  for(int j=0;j<12;j++){
    int g = t + j*256;
    float rv = R[base+g] - a*ap[j];
    rn[j] = rv; rz2p += rv*rv;
    float xv = first ? a*pd[j] : X[base+g] + a*pd[j];
    X[base+g] = xv;
    R[base+g] = rv;
  }
  float rz2 = blockSumBcast(rz2p);
  float beta = rz2 / fmaxf(rzv, 1e-30f);
  #pragma unroll
  for(int j=0;j<12;j++){
    int g = t + j*256;
    float pdn = rn[j] + beta*pd[j];
    Pdb[base+g] = f2bf(rs[g]*pdn);
  }
  if(t==0) rz[p] = rz2;
}

// ---- final pg: both channels, coalesced f32x4 (2 pairs/thread) -----------
__global__ void k_wpg2(const float* __restrict__ X, const float* __restrict__ d2p,
                       const float* __restrict__ rs, float* __restrict__ out, int n2){
  int i = blockIdx.x*256 + threadIdx.x;        // 2 consecutive elements
  if(i >= n2) return;
  size_t idx = (size_t)i*2;
  int g = (int)(idx % 3072);                   // 3072 even -> no row crossing
  f32x4 o;
  o[0] = (1.0f - ALPHA_C) * X[idx]   * rs[g];
  o[1] = d2p[idx];
  o[2] = (1.0f - ALPHA_C) * X[idx+1] * rs[g+1];
  o[3] = d2p[idx+1];
  __builtin_nontemporal_store(o, reinterpret_cast<f32x4*>(out + idx*2));
}

// ---- final gg output: read Kb, emit (e, g1*d2) f32 pairs, coalesced ------
__global__ void k_ggout(const u16* __restrict__ Kb, float* __restrict__ gg,
                        const float* __restrict__ gamma, int n4){
  int i = blockIdx.x*256 + threadIdx.x;        // handles 4 elems
  if(i >= n4) return;
  float g0 = gamma[0], g1 = gamma[1];
  float ginv = -g1 / g0;                        // ch1 = g1*d2 = -g1/g0 * ln(e)
  u16x4 kv = *reinterpret_cast<const u16x4*>(Kb + (size_t)i*4);
  float e0 = bf2f(kv[0]), e1 = bf2f(kv[1]), e2 = bf2f(kv[2]), e3 = bf2f(kv[3]);
  f32x4 a, b;
  a[0] = e0; a[1] = ginv*__logf(e0);
  a[2] = e1; a[3] = ginv*__logf(e1);
  b[0] = e2; b[1] = ginv*__logf(e2);
  b[2] = e3; b[3] = ginv*__logf(e3);
  __builtin_nontemporal_store(a, reinterpret_cast<f32x4*>(gg + (size_t)i*8));
  __builtin_nontemporal_store(b, reinterpret_cast<f32x4*>(gg + (size_t)i*8 + 4));
}

extern "C" void kernel_launch(void* const* d_in, const int* in_sizes, int n_in,
                              void* d_out, int out_size, void* d_ws, size_t ws_size,
                              hipStream_t stream){
  const float* x     = (const float*)d_in[0];   // 4096x512
  const float* Wb    = (const float*)d_in[1];   // 512x512
  const float* gamma = (const float*)d_in[2];   // 2
  (void)in_sizes; (void)n_in; (void)out_size;

  float* out    = (float*)d_out;
  float* out_pg = out;                                  // [1024][3072][2] f32
  float* out_gg = out + (size_t)1024*3072*2;            // [3072][3072][2] f32
  float* SP     = out_gg;   // 4 split-K partials (50.3MB) live in out_gg (75.5MB)

  if(ws_size < WS_NEEDED){                              // diagnostic canary
    k_canary<<<1, 1, 0, stream>>>(out);
    return;
  }

  char* ws = (char*)d_ws;
  size_t off = 0;
  auto alloc = [&](size_t bytes)->char*{
    char* p = ws + off; off = (off + bytes + 255) & ~(size_t)255; return p;
  };
  // regionA: xbf(4.19MB)+wbt(0.5MB) early, reused as R(12.6MB) later
  char*  regionA = alloc((size_t)1024*3072*4);
  u16*   xbf   = (u16*)regionA;
  u16*   wbt   = (u16*)(regionA + (size_t)4096*512*2);
  float* R     = (float*)regionA;
  u16*   probe = (u16*)  alloc((size_t)1024*512*2);
  u16*   gal   = (u16*)  alloc((size_t)3072*512*2);
  u16*   Kb    = (u16*)  alloc((size_t)3072*3072*2);
  float* np_   = (float*)alloc(1024*4);
  float* ng    = (float*)alloc(3072*4);
  float* rs    = (float*)alloc(3072*4);
  float* sq    = (float*)alloc(3072*4);
  float* rz    = (float*)alloc(1024*4);
  float* X     = (float*)alloc((size_t)1024*3072*4);   // doubles as E buffer
  float* D2P   = (float*)alloc((size_t)1024*3072*4);
  u16*   Pdb   = (u16*)  alloc((size_t)1024*3072*2);
  float* E     = X;   // E consumed by k_rzinit before first cgstep writes X

  // 1. prep bf16 operands
  k_wbt  <<<256, 256, 0, stream>>>(Wb, wbt);
  k_f2bf8<<<1024, 256, 0, stream>>>(x, xbf, 4096*512/8);

  // 2. f = x@Wb -> probe/gal bf16 rows   (32x4 = 128 blocks)
  k_gemm<<<128, 256, 0, stream>>>(0, xbf, wbt, 512, 4, 128, 512,
      nullptr, nullptr, nullptr, probe, gal, nullptr, nullptr, nullptr);

  // 3. row norms
  k_norms<<<4096, 256, 0, stream>>>(probe, gal, np_, ng);

  // 4. MERGED gg+pg distances: gg -> Kb (576 blk) | pg -> D2P + E (192 blk)
  k_gemm<<<768, 256, 0, stream>>>(4, gal, gal, 512, 24, 768, 512,
      ng, ng, gamma, Kb, probe, D2P, E, np_);

  // 5. off-diag row sums -> rs = d^{-1/2}, sq = d^{1/2}
  k_rowsum<<<3072, 256, 0, stream>>>(Kb, rs, sq);

  // 6. CG init from E (R = sq*E, Pdb = bf16(E), rz)
  k_rzinit<<<1024, 256, 0, stream>>>(E, sq, R, Pdb, rz);

  // 7. CG on (I - alpha*S); matvec split-K=4 -> 768 blocks, SP in out_gg
  for(int it = 0; it < NITER; ++it){
    k_gemm<<<768, 256, 0, stream>>>(3, Pdb, Kb, 3072, 24, 192, 768,
        nullptr, nullptr, nullptr, nullptr, nullptr, nullptr, SP, nullptr);
    k_cgstep<<<1024, 256, 0, stream>>>(SP, Pdb, R, X, rz, rs, sq, it==0 ? 1 : 0);
  }

  // 8. pg output: both channels coalesced
  k_wpg2<<<6144, 256, 0, stream>>>(X, D2P, rs, out_pg, 1024*3072/2);

  // 9. regenerate gg output pairs from Kb (coalesced streaming writes)
  k_ggout<<<9216, 256, 0, stream>>>(Kb, out_gg, gamma, 3072*3072/4);
}

// Round 9
// 330.919 us; speedup vs baseline: 8.3960x; 1.0253x over previous
//
#include <hip/hip_runtime.h>

typedef unsigned short u16;
typedef short short8v __attribute__((ext_vector_type(8)));
typedef float f32x4 __attribute__((ext_vector_type(4)));
typedef unsigned short u16x4 __attribute__((ext_vector_type(4)));

#define ALPHA_C 0.99f
#define NITER 3
#define WS_NEEDED 67500000UL

__device__ __forceinline__ u16 f2bf(float f){
  union { float f; unsigned u; } v; v.f = f;
  unsigned r = (v.u + 0x7FFFu + ((v.u >> 16) & 1u)) >> 16;
  return (u16)r;
}
__device__ __forceinline__ float bf2f(u16 u){
  union { unsigned u; float f; } v; v.u = ((unsigned)u) << 16;
  return v.f;
}

// async global->LDS, 16B per lane; lds dest must be wave-uniform base
__device__ __forceinline__ void gload16(const void* g, void* l){
  __builtin_amdgcn_global_load_lds(
    (const __attribute__((address_space(1))) unsigned*)g,
    (__attribute__((address_space(3))) unsigned*)l, 16, 0, 0);
}

// block=256: full sum broadcast to ALL threads
__device__ __forceinline__ float blockSumBcast(float v){
  #pragma unroll
  for(int off=32; off>0; off>>=1) v += __shfl_down(v, off, 64);
  __shared__ float sm[4];
  __shared__ float res;
  int w = threadIdx.x >> 6;
  if((threadIdx.x & 63)==0) sm[w] = v;
  __syncthreads();
  if(threadIdx.x==0) res = sm[0]+sm[1]+sm[2]+sm[3];
  __syncthreads();
  return res;
}

__global__ void k_canary(float* out){ out[0] = 12345.0f; }

// ---- Wb (512x512 f32, [k][c]) -> Wbt bf16 [c][k] -------------------------
__global__ void k_wbt(const float* __restrict__ Wb, u16* __restrict__ Wbt){
  __shared__ float t[32][33];
  int bx = blockIdx.x & 15, by = blockIdx.x >> 4;
  int tx = threadIdx.x & 31, ty = threadIdx.x >> 5;  // 32 x 8
  #pragma unroll
  for(int i=0;i<32;i+=8)
    t[ty+i][tx] = Wb[(by*32+ty+i)*512 + bx*32+tx];
  __syncthreads();
  #pragma unroll
  for(int i=0;i<32;i+=8)
    Wbt[(bx*32+ty+i)*512 + by*32 + tx] = f2bf(t[tx][ty+i]);
}

// ---- f32 -> bf16, 8 elems/thread ----------------------------------------
__global__ void k_f2bf8(const float* __restrict__ in, u16* __restrict__ out, int n8){
  int i = blockIdx.x*256 + threadIdx.x;
  if(i >= n8) return;
  f32x4 a = *reinterpret_cast<const f32x4*>(in + (size_t)i*8);
  f32x4 b = *reinterpret_cast<const f32x4*>(in + (size_t)i*8 + 4);
  short8v o;
  o[0]=(short)f2bf(a[0]); o[1]=(short)f2bf(a[1]); o[2]=(short)f2bf(a[2]); o[3]=(short)f2bf(a[3]);
  o[4]=(short)f2bf(b[0]); o[5]=(short)f2bf(b[1]); o[6]=(short)f2bf(b[2]); o[7]=(short)f2bf(b[3]);
  *reinterpret_cast<short8v*>(out + (size_t)i*8) = o;
}

// ---- NT MFMA GEMM, 128x128 tile, BK=64, 4 waves, global_load_lds staging -
// epi 0: f scatter -> probe/gal bf16 rows (u0=probe,u1=gal)
// epi 1: gg distances -> packed bf16 K only (u0=Kb)
// epi 2: pg distances -> D2P=g1*d2 (fo0) + E=exp(-g0*d2) (f0)
// epi 3: split-K matvec K@Pdb -> f0 + slice*1024*3072 (XCD-swizzled,
//        bcol-grouped so each XCD chunk's panels fit its private L2)
// epi 4: MERGED gg+pg (XCD-swizzled): L<576 = epi1; else epi2 with
//        A=u1(probe), nrmA=f1(np_)
__global__ void __launch_bounds__(256) k_gemm(
    int epi,
    const u16* __restrict__ A, const u16* __restrict__ B,
    int kld, int nbn, int bps, int kspan,
    const float* __restrict__ nrmA, const float* __restrict__ nrmB,
    const float* __restrict__ gamma,
    u16* __restrict__ u0, u16* __restrict__ u1,
    float* __restrict__ fo0,
    float* __restrict__ f0, const float* __restrict__ f1)
{
  int bid = blockIdx.x;
  int slice, brow, bcol;
  if(epi==3){
    int L = (bid & 7)*96 + (bid >> 3);   // 768 blocks, bijective (768%8==0)
    slice = L / 192;
    int l = L - slice*192;
    bcol = l >> 3;                        // 12 bcols x 8 brows per XCD chunk
    brow = l & 7;                         // -> 3.9 MB panel set < 4 MB L2
  } else if(epi==4){
    int L = (bid & 7)*96 + (bid >> 3);
    slice = 0;
    if(L < 576){ epi = 1; brow = L / 24; bcol = L % 24; }
    else { epi = 2; int l = L - 576; brow = l / 24; bcol = l % 24; A = u1; nrmA = f1; }
  } else {
    slice = bid / bps; int rem = bid % bps;
    brow = rem / nbn; bcol = rem % nbn;
  }
  int t = threadIdx.x;
  int w = t >> 6, l = t & 63;
  int wr = w >> 1, wc = w & 1;
  const int l15 = l & 15, l16 = l >> 4;
  int k0 = slice * kspan;

  __shared__ __align__(16) u16 AB[2*128*64];   // A tile | B tile, 32 KB

  // staging role: waves 0,1 -> A halves; waves 2,3 -> B halves
  const u16* src = (w < 2) ? A + (size_t)brow*128*kld
                           : B + (size_t)bcol*128*kld;
  int half = w >> 1;            // 0 = A, 1 = B
  int wq   = (w & 1) * 8;       // chunk-call base within half

  f32x4 acc[4][4] = {};

  for(int kk = 0; kk < kspan; kk += 64){
    int kt = k0 + kk;
    #pragma unroll
    for(int q=0;q<8;q++){
      int cb  = (wq + q)*64;             // chunk base within half [0,1024)
      int idx = cb + l;                  // this lane's 16B chunk
      int row = idx >> 3, c8 = idx & 7;
      gload16(src + (size_t)row*kld + kt + c8*8,   // per-lane global src
              &AB[half*8192 + cb*8]);              // wave-uniform LDS dest
    }
    __syncthreads();                     // drains vmcnt before barrier
    #pragma unroll
    for(int ks=0; ks<2; ++ks){
      short8v af[4], bfr[4];
      int ko = ks*32 + l16*8;
      #pragma unroll
      for(int i=0;i<4;i++){
        af[i]  = *reinterpret_cast<const short8v*>(&AB[(wr*64+i*16+l15)*64 + ko]);
        bfr[i] = *reinterpret_cast<const short8v*>(&AB[8192 + (wc*64+i*16+l15)*64 + ko]);
      }
      #pragma unroll
      for(int i=0;i<4;i++)
        #pragma unroll
        for(int j=0;j<4;j++)
          acc[i][j] = __builtin_amdgcn_mfma_f32_16x16x32_bf16(af[i], bfr[j], acc[i][j], 0,0,0);
    }
    __syncthreads();
  }

  float g0 = 0.f, g1 = 0.f;
  if(epi==1 || epi==2){ g0 = gamma[0]; g1 = gamma[1]; }

  #pragma unroll
  for(int i=0;i<4;i++)
  #pragma unroll
  for(int j=0;j<4;j++)
  #pragma unroll
  for(int r=0;r<4;r++){
    int m = brow*128 + wr*64 + i*16 + l16*4 + r;   // C row (A index)
    int n = bcol*128 + wc*64 + j*16 + l15;         // C col (B index)
    float c = acc[i][j][r];
    if(epi==0){
      if((m & 3) == 0) u0[(size_t)(m>>2)*512 + n] = f2bf(c);
      else             u1[(size_t)((m>>2)*3 + (m&3) - 1)*512 + n] = f2bf(c);
    } else if(epi==1){
      float d2 = (nrmA[m] + nrmB[n] - 2.f*c) * (1.f/512.f);
      float e  = __expf(-g0*d2);
      u0[(size_t)m*3072 + n] = f2bf(e);            // packed K only
    } else if(epi==2){
      float d2 = (nrmA[m] + nrmB[n] - 2.f*c) * (1.f/512.f);
      float e  = __expf(-g0*d2);
      fo0[(size_t)m*3072 + n] = g1*d2;              // D2P (contiguous)
      f0[(size_t)m*3072 + n] = e;                   // E (unscaled)
    } else {
      f0[(size_t)slice*1024*3072 + (size_t)m*3072 + n] = c;   // K@Pdb partial
    }
  }
}

// ---- row norms of bf16-rounded f ----------------------------------------
__global__ void k_norms(const u16* __restrict__ probe, const u16* __restrict__ gal,
                        float* __restrict__ np_, float* __restrict__ ng){
  int row = blockIdx.x;
  const u16* src = (row < 1024) ? probe + (size_t)row*512
                                : gal + (size_t)(row-1024)*512;
  float s = 0.f;
  for(int i = threadIdx.x; i < 512; i += 256){ float v = bf2f(src[i]); s += v*v; }
  float r = blockSumBcast(s);
  if(threadIdx.x==0){ if(row < 1024) np_[row] = r; else ng[row-1024] = r; }
}

// ---- off-diagonal row sums of packed bf16 K ------------------------------
__global__ void k_rowsum(const u16* __restrict__ Kb, float* __restrict__ rs,
                         float* __restrict__ sq){
  int i = blockIdx.x;
  const u16* row = Kb + (size_t)i*3072;
  float s = 0.f;
  for(int j = threadIdx.x; j < 3072; j += 256) s += bf2f(row[j]);
  float r = blockSumBcast(s);
  if(threadIdx.x==0){
    float d = r - bf2f(row[i]);
    rs[i] = rsqrtf(d); sq[i] = sqrtf(d);
  }
}

// ---- CG init from E: R = sq*E, Pdb = bf16(rs*R) = bf16(E), rz = R.R ------
__global__ void k_rzinit(const float* __restrict__ E, const float* __restrict__ sq,
                         float* __restrict__ R, u16* __restrict__ Pdb,
                         float* __restrict__ rz){
  int p = blockIdx.x, t = threadIdx.x;
  size_t base = (size_t)p*3072;
  float s = 0.f;
  #pragma unroll
  for(int j=0;j<12;j++){
    int g = t + j*256;
    float e = E[base+g];
    float r = sq[g]*e;
    R[base+g] = r;
    Pdb[base+g] = f2bf(e);      // rs[g]*r == e exactly
    s += r*r;
  }
  float tot = blockSumBcast(s);
  if(t==0) rz[p] = tot;
}

// ---- fused CG step; SP has 4 split-K partials ----------------------------
// last: skip R/X/Pdb/rz updates, write out_pg (ch0,ch1) pairs directly
__global__ void __launch_bounds__(256) k_cgstep(
    const float* __restrict__ SP, u16* __restrict__ Pdb,
    float* __restrict__ R, float* __restrict__ X,
    float* __restrict__ rz,
    const float* __restrict__ rs, const float* __restrict__ sq,
    const float* __restrict__ D2P, float* __restrict__ outpg,
    int first, int last)
{
  const size_t SOFF = (size_t)1024*3072;
  int p = blockIdx.x, t = threadIdx.x;
  size_t base = (size_t)p*3072;
  float pd[12], ap[12];
  float papp = 0.f;
  #pragma unroll
  for(int j=0;j<12;j++){
    int g = t + j*256;
    float pdv = sq[g] * bf2f(Pdb[base+g]);
    float spv = (SP[base+g] + SP[SOFF+base+g])
              + (SP[2*SOFF+base+g] + SP[3*SOFF+base+g]);
    pd[j] = pdv;
    ap[j] = pdv - ALPHA_C * (rs[g] * spv);
    papp += pdv * ap[j];
  }
  float pap = blockSumBcast(papp);
  float rzv = rz[p];
  float a = rzv / fmaxf(pap, 1e-30f);

  if(!last){
    float rn[12];
    float rz2p = 0.f;
    #pragma unroll
    for(int j=0;j<12;j++){
      int g = t + j*256;
      float rv = R[base+g] - a*ap[j];
      rn[j] = rv; rz2p += rv*rv;
      float xv = first ? a*pd[j] : X[base+g] + a*pd[j];
      X[base+g] = xv;
      R[base+g] = rv;
    }
    float rz2 = blockSumBcast(rz2p);
    float beta = rz2 / fmaxf(rzv, 1e-30f);
    #pragma unroll
    for(int j=0;j<12;j++){
      int g = t + j*256;
      float pdn = rn[j] + beta*pd[j];
      Pdb[base+g] = f2bf(rs[g]*pdn);
    }
    if(t==0) rz[p] = rz2;
  } else {
    // write interleaved (ch0, ch1) output pairs, 2 pairs per thread / pass
    #pragma unroll
    for(int j=0;j<6;j++){
      int g0 = 2*(t + j*256);
      float pd0 = sq[g0]   * bf2f(Pdb[base+g0]);
      float pd1 = sq[g0+1] * bf2f(Pdb[base+g0+1]);
      float xv0 = X[base+g0]   + a*pd0;
      float xv1 = X[base+g0+1] + a*pd1;
      f32x4 o;
      o[0] = (1.0f - ALPHA_C) * xv0 * rs[g0];
      o[1] = D2P[base+g0];
      o[2] = (1.0f - ALPHA_C) * xv1 * rs[g0+1];
      o[3] = D2P[base+g0+1];
      __builtin_nontemporal_store(o, reinterpret_cast<f32x4*>(outpg + (base+g0)*2));
    }
  }
}

// ---- final gg output: read Kb, emit (e, g1*d2) f32 pairs, coalesced ------
__global__ void k_ggout(const u16* __restrict__ Kb, float* __restrict__ gg,
                        const float* __restrict__ gamma, int n4){
  int i = blockIdx.x*256 + threadIdx.x;        // handles 4 elems
  if(i >= n4) return;
  float g0 = gamma[0], g1 = gamma[1];
  float ginv = -g1 / g0;                        // ch1 = g1*d2 = -g1/g0 * ln(e)
  u16x4 kv = *reinterpret_cast<const u16x4*>(Kb + (size_t)i*4);
  float e0 = bf2f(kv[0]), e1 = bf2f(kv[1]), e2 = bf2f(kv[2]), e3 = bf2f(kv[3]);
  f32x4 a, b;
  a[0] = e0; a[1] = ginv*__logf(e0);
  a[2] = e1; a[3] = ginv*__logf(e1);
  b[0] = e2; b[1] = ginv*__logf(e2);
  b[2] = e3; b[3] = ginv*__logf(e3);
  __builtin_nontemporal_store(a, reinterpret_cast<f32x4*>(gg + (size_t)i*8));
  __builtin_nontemporal_store(b, reinterpret_cast<f32x4*>(gg + (size_t)i*8 + 4));
}

extern "C" void kernel_launch(void* const* d_in, const int* in_sizes, int n_in,
                              void* d_out, int out_size, void* d_ws, size_t ws_size,
                              hipStream_t stream){
  const float* x     = (const float*)d_in[0];   // 4096x512
  const float* Wb    = (const float*)d_in[1];   // 512x512
  const float* gamma = (const float*)d_in[2];   // 2
  (void)in_sizes; (void)n_in; (void)out_size;

  float* out    = (float*)d_out;
  float* out_pg = out;                                  // [1024][3072][2] f32
  float* out_gg = out + (size_t)1024*3072*2;            // [3072][3072][2] f32
  float* SP     = out_gg;   // 4 split-K partials (50.3MB) live in out_gg (75.5MB)

  if(ws_size < WS_NEEDED){                              // diagnostic canary
    k_canary<<<1, 1, 0, stream>>>(out);
    return;
  }

  char* ws = (char*)d_ws;
  size_t off = 0;
  auto alloc = [&](size_t bytes)->char*{
    char* p = ws + off; off = (off + bytes + 255) & ~(size_t)255; return p;
  };
  // regionA: xbf(4.19MB)+wbt(0.5MB) early, reused as R(12.6MB) later
  char*  regionA = alloc((size_t)1024*3072*4);
  u16*   xbf   = (u16*)regionA;
  u16*   wbt   = (u16*)(regionA + (size_t)4096*512*2);
  float* R     = (float*)regionA;
  u16*   probe = (u16*)  alloc((size_t)1024*512*2);
  u16*   gal   = (u16*)  alloc((size_t)3072*512*2);
  u16*   Kb    = (u16*)  alloc((size_t)3072*3072*2);
  float* np_   = (float*)alloc(1024*4);
  float* ng    = (float*)alloc(3072*4);
  float* rs    = (float*)alloc(3072*4);
  float* sq    = (float*)alloc(3072*4);
  float* rz    = (float*)alloc(1024*4);
  float* X     = (float*)alloc((size_t)1024*3072*4);   // doubles as E buffer
  float* D2P   = (float*)alloc((size_t)1024*3072*4);
  u16*   Pdb   = (u16*)  alloc((size_t)1024*3072*2);
  float* E     = X;   // E consumed by k_rzinit before first cgstep writes X

  // 1. prep bf16 operands
  k_wbt  <<<256, 256, 0, stream>>>(Wb, wbt);
  k_f2bf8<<<1024, 256, 0, stream>>>(x, xbf, 4096*512/8);

  // 2. f = x@Wb -> probe/gal bf16 rows   (32x4 = 128 blocks)
  k_gemm<<<128, 256, 0, stream>>>(0, xbf, wbt, 512, 4, 128, 512,
      nullptr, nullptr, nullptr, probe, gal, nullptr, nullptr, nullptr);

  // 3. row norms
  k_norms<<<4096, 256, 0, stream>>>(probe, gal, np_, ng);

  // 4. MERGED gg+pg distances (XCD-swizzled): gg -> Kb | pg -> D2P + E
  k_gemm<<<768, 256, 0, stream>>>(4, gal, gal, 512, 24, 768, 512,
      ng, ng, gamma, Kb, probe, D2P, E, np_);

  // 5. off-diag row sums -> rs = d^{-1/2}, sq = d^{1/2}
  k_rowsum<<<3072, 256, 0, stream>>>(Kb, rs, sq);

  // 6. CG init from E (R = sq*E, Pdb = bf16(E), rz)
  k_rzinit<<<1024, 256, 0, stream>>>(E, sq, R, Pdb, rz);

  // 7. CG on (I - alpha*S); matvec split-K=4, XCD-swizzled; SP in out_gg
  //    last cgstep writes out_pg directly (both channels)
  for(int it = 0; it < NITER; ++it){
    k_gemm<<<768, 256, 0, stream>>>(3, Pdb, Kb, 3072, 24, 192, 768,
        nullptr, nullptr, nullptr, nullptr, nullptr, nullptr, SP, nullptr);
    k_cgstep<<<1024, 256, 0, stream>>>(SP, Pdb, R, X, rz, rs, sq,
        D2P, out_pg, it==0 ? 1 : 0, it==NITER-1 ? 1 : 0);
  }

  // 8. regenerate gg output pairs from Kb (coalesced streaming writes)
  k_ggout<<<9216, 256, 0, stream>>>(Kb, out_gg, gamma, 3072*3072/4);
}

// Round 10
// 265.690 us; speedup vs baseline: 10.4573x; 1.2455x over previous
//
#include <hip/hip_runtime.h>

typedef unsigned short u16;
typedef short short8v __attribute__((ext_vector_type(8)));
typedef float f32x4 __attribute__((ext_vector_type(4)));
typedef float f32x2 __attribute__((ext_vector_type(2)));
typedef unsigned short u16x4 __attribute__((ext_vector_type(4)));

#define ALPHA_C 0.99f
#define NITER 2
#define WS_NEEDED 67500000UL

__device__ __forceinline__ u16 f2bf(float f){
  union { float f; unsigned u; } v; v.f = f;
  unsigned r = (v.u + 0x7FFFu + ((v.u >> 16) & 1u)) >> 16;
  return (u16)r;
}
__device__ __forceinline__ float bf2f(u16 u){
  union { unsigned u; float f; } v; v.u = ((unsigned)u) << 16;
  return v.f;
}

// async global->LDS, 16B per lane; lds dest must be wave-uniform base
__device__ __forceinline__ void gload16(const void* g, void* l){
  __builtin_amdgcn_global_load_lds(
    (const __attribute__((address_space(1))) unsigned*)g,
    (__attribute__((address_space(3))) unsigned*)l, 16, 0, 0);
}

// block=256: full sum broadcast to ALL threads
__device__ __forceinline__ float blockSumBcast(float v){
  #pragma unroll
  for(int off=32; off>0; off>>=1) v += __shfl_down(v, off, 64);
  __shared__ float sm[4];
  __shared__ float res;
  int w = threadIdx.x >> 6;
  if((threadIdx.x & 63)==0) sm[w] = v;
  __syncthreads();
  if(threadIdx.x==0) res = sm[0]+sm[1]+sm[2]+sm[3];
  __syncthreads();
  return res;
}

__global__ void k_canary(float* out){ out[0] = 12345.0f; }

// ---- Wb (512x512 f32, [k][c]) -> Wbt bf16 [c][k] -------------------------
__global__ void k_wbt(const float* __restrict__ Wb, u16* __restrict__ Wbt){
  __shared__ float t[32][33];
  int bx = blockIdx.x & 15, by = blockIdx.x >> 4;
  int tx = threadIdx.x & 31, ty = threadIdx.x >> 5;  // 32 x 8
  #pragma unroll
  for(int i=0;i<32;i+=8)
    t[ty+i][tx] = Wb[(by*32+ty+i)*512 + bx*32+tx];
  __syncthreads();
  #pragma unroll
  for(int i=0;i<32;i+=8)
    Wbt[(bx*32+ty+i)*512 + by*32 + tx] = f2bf(t[tx][ty+i]);
}

// ---- f32 -> bf16, 8 elems/thread ----------------------------------------
__global__ void k_f2bf8(const float* __restrict__ in, u16* __restrict__ out, int n8){
  int i = blockIdx.x*256 + threadIdx.x;
  if(i >= n8) return;
  f32x4 a = *reinterpret_cast<const f32x4*>(in + (size_t)i*8);
  f32x4 b = *reinterpret_cast<const f32x4*>(in + (size_t)i*8 + 4);
  short8v o;
  o[0]=(short)f2bf(a[0]); o[1]=(short)f2bf(a[1]); o[2]=(short)f2bf(a[2]); o[3]=(short)f2bf(a[3]);
  o[4]=(short)f2bf(b[0]); o[5]=(short)f2bf(b[1]); o[6]=(short)f2bf(b[2]); o[7]=(short)f2bf(b[3]);
  *reinterpret_cast<short8v*>(out + (size_t)i*8) = o;
}

// ---- NT MFMA GEMM, 128x128 tile, BK=64, 4 waves, global_load_lds staging -
// epi 0: f scatter -> probe/gal bf16 rows (u0=probe,u1=gal)
// epi 1: gg distances -> packed bf16 K only (u0=Kb)
// epi 2: pg distances -> D2P=g1*d2 NT (fo0) + E=exp(-g0*d2) (f0)
// epi 3: split-K matvec K@Pdb -> bf16 NT partials (u0) + slice*1024*3072
// epi 4: MERGED gg+pg (XCD-swizzled): L<576 = epi1; else epi2 with
//        A=u1(probe), nrmA=f1(np_)
__global__ void __launch_bounds__(256) k_gemm(
    int epi,
    const u16* __restrict__ A, const u16* __restrict__ B,
    int kld, int nbn, int bps, int kspan,
    const float* __restrict__ nrmA, const float* __restrict__ nrmB,
    const float* __restrict__ gamma,
    u16* __restrict__ u0, u16* __restrict__ u1,
    float* __restrict__ fo0,
    float* __restrict__ f0, const float* __restrict__ f1)
{
  int bid = blockIdx.x;
  int slice, brow, bcol;
  if(epi==3){
    int L = (bid & 7)*96 + (bid >> 3);   // 768 blocks, bijective (768%8==0)
    slice = L / 192;
    int l = L - slice*192;
    bcol = l >> 3;                        // 12 bcols x 8 brows per XCD chunk
    brow = l & 7;                         // -> 3.9 MB panel set < 4 MB L2
  } else if(epi==4){
    int L = (bid & 7)*96 + (bid >> 3);
    slice = 0;
    if(L < 576){ epi = 1; brow = L / 24; bcol = L % 24; }
    else { epi = 2; int l = L - 576; brow = l / 24; bcol = l % 24; A = u1; nrmA = f1; }
  } else {
    slice = bid / bps; int rem = bid % bps;
    brow = rem / nbn; bcol = rem % nbn;
  }
  int t = threadIdx.x;
  int w = t >> 6, l = t & 63;
  int wr = w >> 1, wc = w & 1;
  const int l15 = l & 15, l16 = l >> 4;
  int k0 = slice * kspan;

  __shared__ __align__(16) u16 AB[2*128*64];   // A tile | B tile, 32 KB

  // staging role: waves 0,1 -> A halves; waves 2,3 -> B halves
  const u16* src = (w < 2) ? A + (size_t)brow*128*kld
                           : B + (size_t)bcol*128*kld;
  int half = w >> 1;            // 0 = A, 1 = B
  int wq   = (w & 1) * 8;       // chunk-call base within half

  f32x4 acc[4][4] = {};

  for(int kk = 0; kk < kspan; kk += 64){
    int kt = k0 + kk;
    #pragma unroll
    for(int q=0;q<8;q++){
      int cb  = (wq + q)*64;             // chunk base within half [0,1024)
      int idx = cb + l;                  // this lane's 16B chunk
      int row = idx >> 3, c8 = idx & 7;
      gload16(src + (size_t)row*kld + kt + c8*8,   // per-lane global src
              &AB[half*8192 + cb*8]);              // wave-uniform LDS dest
    }
    __syncthreads();                     // drains vmcnt before barrier
    #pragma unroll
    for(int ks=0; ks<2; ++ks){
      short8v af[4], bfr[4];
      int ko = ks*32 + l16*8;
      #pragma unroll
      for(int i=0;i<4;i++){
        af[i]  = *reinterpret_cast<const short8v*>(&AB[(wr*64+i*16+l15)*64 + ko]);
        bfr[i] = *reinterpret_cast<const short8v*>(&AB[8192 + (wc*64+i*16+l15)*64 + ko]);
      }
      #pragma unroll
      for(int i=0;i<4;i++)
        #pragma unroll
        for(int j=0;j<4;j++)
          acc[i][j] = __builtin_amdgcn_mfma_f32_16x16x32_bf16(af[i], bfr[j], acc[i][j], 0,0,0);
    }
    __syncthreads();
  }

  float g0 = 0.f, g1 = 0.f;
  if(epi==1 || epi==2){ g0 = gamma[0]; g1 = gamma[1]; }

  #pragma unroll
  for(int i=0;i<4;i++)
  #pragma unroll
  for(int j=0;j<4;j++)
  #pragma unroll
  for(int r=0;r<4;r++){
    int m = brow*128 + wr*64 + i*16 + l16*4 + r;   // C row (A index)
    int n = bcol*128 + wc*64 + j*16 + l15;         // C col (B index)
    float c = acc[i][j][r];
    if(epi==0){
      if((m & 3) == 0) u0[(size_t)(m>>2)*512 + n] = f2bf(c);
      else             u1[(size_t)((m>>2)*3 + (m&3) - 1)*512 + n] = f2bf(c);
    } else if(epi==1){
      float d2 = (nrmA[m] + nrmB[n] - 2.f*c) * (1.f/512.f);
      float e  = __expf(-g0*d2);
      u0[(size_t)m*3072 + n] = f2bf(e);            // packed K only
    } else if(epi==2){
      float d2 = (nrmA[m] + nrmB[n] - 2.f*c) * (1.f/512.f);
      float e  = __expf(-g0*d2);
      __builtin_nontemporal_store(g1*d2, &fo0[(size_t)m*3072 + n]);  // D2P
      f0[(size_t)m*3072 + n] = e;                   // E (unscaled)
    } else {
      // bf16 NT split-K partial: halves SP traffic, no L2 pollution
      __builtin_nontemporal_store(f2bf(c),
        &u0[(size_t)slice*1024*3072 + (size_t)m*3072 + n]);
    }
  }
}

// ---- row norms of bf16-rounded f ----------------------------------------
__global__ void k_norms(const u16* __restrict__ probe, const u16* __restrict__ gal,
                        float* __restrict__ np_, float* __restrict__ ng){
  int row = blockIdx.x;
  const u16* src = (row < 1024) ? probe + (size_t)row*512
                                : gal + (size_t)(row-1024)*512;
  float s = 0.f;
  for(int i = threadIdx.x; i < 512; i += 256){ float v = bf2f(src[i]); s += v*v; }
  float r = blockSumBcast(s);
  if(threadIdx.x==0){ if(row < 1024) np_[row] = r; else ng[row-1024] = r; }
}

// ---- off-diagonal row sums of packed bf16 K ------------------------------
__global__ void k_rowsum(const u16* __restrict__ Kb, float* __restrict__ rs,
                         float* __restrict__ sq){
  int i = blockIdx.x;
  const u16* row = Kb + (size_t)i*3072;
  float s = 0.f;
  for(int j = threadIdx.x; j < 3072; j += 256) s += bf2f(row[j]);
  float r = blockSumBcast(s);
  if(threadIdx.x==0){
    float d = r - bf2f(row[i]);
    rs[i] = rsqrtf(d); sq[i] = sqrtf(d);
  }
}

// ---- CG init from E: R = sq*E, Pdb = bf16(rs*R) = bf16(E), rz = R.R ------
__global__ void k_rzinit(const float* __restrict__ E, const float* __restrict__ sq,
                         float* __restrict__ R, u16* __restrict__ Pdb,
                         float* __restrict__ rz){
  int p = blockIdx.x, t = threadIdx.x;
  size_t base = (size_t)p*3072;
  float s = 0.f;
  #pragma unroll
  for(int j=0;j<6;j++){
    int g = 2*(t + j*256);
    f32x2 ev = *reinterpret_cast<const f32x2*>(&E[base+g]);
    f32x2 rv; rv[0] = sq[g]*ev[0]; rv[1] = sq[g+1]*ev[1];
    *reinterpret_cast<f32x2*>(&R[base+g]) = rv;
    unsigned pk = (unsigned)f2bf(ev[0]) | ((unsigned)f2bf(ev[1]) << 16);
    *reinterpret_cast<unsigned*>(&Pdb[base+g]) = pk;   // rs*r == e exactly
    s += rv[0]*rv[0] + rv[1]*rv[1];
  }
  float tot = blockSumBcast(s);
  if(t==0) rz[p] = tot;
}

// ---- fused CG step; SPb has 4 bf16 split-K partials ----------------------
// last: skip R/X/Pdb/rz updates, write out_pg (ch0,ch1) pairs directly
__global__ void __launch_bounds__(256) k_cgstep(
    const u16* __restrict__ SPb, u16* __restrict__ Pdb,
    float* __restrict__ R, float* __restrict__ X,
    float* __restrict__ rz,
    const float* __restrict__ rs, const float* __restrict__ sq,
    const float* __restrict__ D2P, float* __restrict__ outpg,
    int first, int last)
{
  const size_t SOFF = (size_t)1024*3072;
  int p = blockIdx.x, t = threadIdx.x;
  size_t base = (size_t)p*3072;
  float pd[12], ap[12];
  float papp = 0.f;
  #pragma unroll
  for(int j=0;j<6;j++){
    int g = 2*(t + j*256);
    unsigned pu = *reinterpret_cast<const unsigned*>(&Pdb[base+g]);
    unsigned s0 = *reinterpret_cast<const unsigned*>(&SPb[base+g]);
    unsigned s1 = *reinterpret_cast<const unsigned*>(&SPb[SOFF+base+g]);
    unsigned s2 = *reinterpret_cast<const unsigned*>(&SPb[2*SOFF+base+g]);
    unsigned s3 = *reinterpret_cast<const unsigned*>(&SPb[3*SOFF+base+g]);
    float pd0 = sq[g]   * bf2f((u16)(pu & 0xffffu));
    float pd1 = sq[g+1] * bf2f((u16)(pu >> 16));
    float sv0 = (bf2f((u16)(s0&0xffffu)) + bf2f((u16)(s1&0xffffu)))
              + (bf2f((u16)(s2&0xffffu)) + bf2f((u16)(s3&0xffffu)));
    float sv1 = (bf2f((u16)(s0>>16)) + bf2f((u16)(s1>>16)))
              + (bf2f((u16)(s2>>16)) + bf2f((u16)(s3>>16)));
    pd[2*j] = pd0; pd[2*j+1] = pd1;
    ap[2*j]   = pd0 - ALPHA_C*(rs[g]  *sv0);
    ap[2*j+1] = pd1 - ALPHA_C*(rs[g+1]*sv1);
    papp += pd0*ap[2*j] + pd1*ap[2*j+1];
  }
  float pap = blockSumBcast(papp);
  float rzv = rz[p];
  float a = rzv / fmaxf(pap, 1e-30f);

  if(!last){
    float rn[12];
    float rz2p = 0.f;
    #pragma unroll
    for(int j=0;j<6;j++){
      int g = 2*(t + j*256);
      f32x2 rv2 = *reinterpret_cast<const f32x2*>(&R[base+g]);
      float rv0 = rv2[0] - a*ap[2*j];
      float rv1 = rv2[1] - a*ap[2*j+1];
      rn[2*j]=rv0; rn[2*j+1]=rv1; rz2p += rv0*rv0 + rv1*rv1;
      f32x2 xo;
      if(first){ xo[0] = a*pd[2*j]; xo[1] = a*pd[2*j+1]; }
      else{
        f32x2 xv = *reinterpret_cast<const f32x2*>(&X[base+g]);
        xo[0] = xv[0] + a*pd[2*j]; xo[1] = xv[1] + a*pd[2*j+1];
      }
      *reinterpret_cast<f32x2*>(&X[base+g]) = xo;
      f32x2 rw; rw[0]=rv0; rw[1]=rv1;
      *reinterpret_cast<f32x2*>(&R[base+g]) = rw;
    }
    float rz2 = blockSumBcast(rz2p);
    float beta = rz2 / fmaxf(rzv, 1e-30f);
    #pragma unroll
    for(int j=0;j<6;j++){
      int g = 2*(t + j*256);
      float p0 = rn[2*j]   + beta*pd[2*j];
      float p1 = rn[2*j+1] + beta*pd[2*j+1];
      unsigned pk = (unsigned)f2bf(rs[g]*p0) | ((unsigned)f2bf(rs[g+1]*p1) << 16);
      *reinterpret_cast<unsigned*>(&Pdb[base+g]) = pk;
    }
    if(t==0) rz[p] = rz2;
  } else {
    // write interleaved (ch0, ch1) output pairs, coalesced 16B NT
    #pragma unroll
    for(int j=0;j<6;j++){
      int g = 2*(t + j*256);
      f32x2 xv = *reinterpret_cast<const f32x2*>(&X[base+g]);
      f32x2 dv = *reinterpret_cast<const f32x2*>(&D2P[base+g]);
      f32x4 o;
      o[0] = (1.0f - ALPHA_C) * (xv[0] + a*pd[2*j])   * rs[g];
      o[1] = dv[0];
      o[2] = (1.0f - ALPHA_C) * (xv[1] + a*pd[2*j+1]) * rs[g+1];
      o[3] = dv[1];
      __builtin_nontemporal_store(o, reinterpret_cast<f32x4*>(outpg + (base+g)*2));
    }
  }
}

// ---- final gg output: read Kb, emit (e, g1*d2) f32 pairs, coalesced ------
__global__ void k_ggout(const u16* __restrict__ Kb, float* __restrict__ gg,
                        const float* __restrict__ gamma, int n4){
  int i = blockIdx.x*256 + threadIdx.x;        // handles 4 elems
  if(i >= n4) return;
  float g0 = gamma[0], g1 = gamma[1];
  float ginv = -g1 / g0;                        // ch1 = g1*d2 = -g1/g0 * ln(e)
  u16x4 kv = *reinterpret_cast<const u16x4*>(Kb + (size_t)i*4);
  float e0 = bf2f(kv[0]), e1 = bf2f(kv[1]), e2 = bf2f(kv[2]), e3 = bf2f(kv[3]);
  f32x4 a, b;
  a[0] = e0; a[1] = ginv*__logf(e0);
  a[2] = e1; a[3] = ginv*__logf(e1);
  b[0] = e2; b[1] = ginv*__logf(e2);
  b[2] = e3; b[3] = ginv*__logf(e3);
  __builtin_nontemporal_store(a, reinterpret_cast<f32x4*>(gg + (size_t)i*8));
  __builtin_nontemporal_store(b, reinterpret_cast<f32x4*>(gg + (size_t)i*8 + 4));
}

extern "C" void kernel_launch(void* const* d_in, const int* in_sizes, int n_in,
                              void* d_out, int out_size, void* d_ws, size_t ws_size,
                              hipStream_t stream){
  const float* x     = (const float*)d_in[0];   // 4096x512
  const float* Wb    = (const float*)d_in[1];   // 512x512
  const float* gamma = (const float*)d_in[2];   // 2
  (void)in_sizes; (void)n_in; (void)out_size;

  float* out    = (float*)d_out;
  float* out_pg = out;                                  // [1024][3072][2] f32
  float* out_gg = out + (size_t)1024*3072*2;            // [3072][3072][2] f32
  u16*   SPb    = (u16*)out_gg;  // 4 bf16 split-K partials (25.2MB) in out_gg

  if(ws_size < WS_NEEDED){                              // diagnostic canary
    k_canary<<<1, 1, 0, stream>>>(out);
    return;
  }

  char* ws = (char*)d_ws;
  size_t off = 0;
  auto alloc = [&](size_t bytes)->char*{
    char* p = ws + off; off = (off + bytes + 255) & ~(size_t)255; return p;
  };
  // regionA: xbf(4.19MB)+wbt(0.5MB) early, reused as R(12.6MB) later
  char*  regionA = alloc((size_t)1024*3072*4);
  u16*   xbf   = (u16*)regionA;
  u16*   wbt   = (u16*)(regionA + (size_t)4096*512*2);
  float* R     = (float*)regionA;
  u16*   probe = (u16*)  alloc((size_t)1024*512*2);
  u16*   gal   = (u16*)  alloc((size_t)3072*512*2);
  u16*   Kb    = (u16*)  alloc((size_t)3072*3072*2);
  float* np_   = (float*)alloc(1024*4);
  float* ng    = (float*)alloc(3072*4);
  float* rs    = (float*)alloc(3072*4);
  float* sq    = (float*)alloc(3072*4);
  float* rz    = (float*)alloc(1024*4);
  float* X     = (float*)alloc((size_t)1024*3072*4);   // doubles as E buffer
  float* D2P   = (float*)alloc((size_t)1024*3072*4);
  u16*   Pdb   = (u16*)  alloc((size_t)1024*3072*2);
  float* E     = X;   // E consumed by k_rzinit before first cgstep writes X

  // 1. prep bf16 operands
  k_wbt  <<<256, 256, 0, stream>>>(Wb, wbt);
  k_f2bf8<<<1024, 256, 0, stream>>>(x, xbf, 4096*512/8);

  // 2. f = x@Wb -> probe/gal bf16 rows   (32x4 = 128 blocks)
  k_gemm<<<128, 256, 0, stream>>>(0, xbf, wbt, 512, 4, 128, 512,
      nullptr, nullptr, nullptr, probe, gal, nullptr, nullptr, nullptr);

  // 3. row norms
  k_norms<<<4096, 256, 0, stream>>>(probe, gal, np_, ng);

  // 4. MERGED gg+pg distances (XCD-swizzled): gg -> Kb | pg -> D2P + E
  k_gemm<<<768, 256, 0, stream>>>(4, gal, gal, 512, 24, 768, 512,
      ng, ng, gamma, Kb, probe, D2P, E, np_);

  // 5. off-diag row sums -> rs = d^{-1/2}, sq = d^{1/2}
  k_rowsum<<<3072, 256, 0, stream>>>(Kb, rs, sq);

  // 6. CG init from E (R = sq*E, Pdb = bf16(E), rz)
  k_rzinit<<<1024, 256, 0, stream>>>(E, sq, R, Pdb, rz);

  // 7. CG on (I - alpha*S); matvec split-K=4 -> bf16 NT partials in out_gg
  //    last cgstep writes out_pg directly (both channels)
  for(int it = 0; it < NITER; ++it){
    k_gemm<<<768, 256, 0, stream>>>(3, Pdb, Kb, 3072, 24, 192, 768,
        nullptr, nullptr, nullptr, SPb, nullptr, nullptr, nullptr, nullptr);
    k_cgstep<<<1024, 256, 0, stream>>>(SPb, Pdb, R, X, rz, rs, sq,
        D2P, out_pg, it==0 ? 1 : 0, it==NITER-1 ? 1 : 0);
  }

  // 8. regenerate gg output pairs from Kb (coalesced streaming writes)
  k_ggout<<<9216, 256, 0, stream>>>(Kb, out_gg, gamma, 3072*3072/4);
}

// Round 11
// 248.983 us; speedup vs baseline: 11.1590x; 1.0671x over previous
//
#include <hip/hip_runtime.h>

typedef unsigned short u16;
typedef short short8v __attribute__((ext_vector_type(8)));
typedef float f32x4 __attribute__((ext_vector_type(4)));
typedef float f32x2 __attribute__((ext_vector_type(2)));
typedef unsigned short u16x4 __attribute__((ext_vector_type(4)));

#define ALPHA_C 0.99f
#define NITER 2
#define WS_NEEDED 67500000UL

__device__ __forceinline__ u16 f2bf(float f){
  union { float f; unsigned u; } v; v.f = f;
  unsigned r = (v.u + 0x7FFFu + ((v.u >> 16) & 1u)) >> 16;
  return (u16)r;
}
__device__ __forceinline__ float bf2f(u16 u){
  union { unsigned u; float f; } v; v.u = ((unsigned)u) << 16;
  return v.f;
}

// async global->LDS, 16B per lane; lds dest must be wave-uniform base
__device__ __forceinline__ void gload16(const void* g, void* l){
  __builtin_amdgcn_global_load_lds(
    (const __attribute__((address_space(1))) unsigned*)g,
    (__attribute__((address_space(3))) unsigned*)l, 16, 0, 0);
}

// block=256: full sum broadcast to ALL threads
__device__ __forceinline__ float blockSumBcast(float v){
  #pragma unroll
  for(int off=32; off>0; off>>=1) v += __shfl_down(v, off, 64);
  __shared__ float sm[4];
  __shared__ float res;
  int w = threadIdx.x >> 6;
  if((threadIdx.x & 63)==0) sm[w] = v;
  __syncthreads();
  if(threadIdx.x==0) res = sm[0]+sm[1]+sm[2]+sm[3];
  __syncthreads();
  return res;
}

__global__ void k_canary(float* out){ out[0] = 12345.0f; }

// ---- Wb (512x512 f32, [k][c]) -> Wbt bf16 [c][k] -------------------------
__global__ void k_wbt(const float* __restrict__ Wb, u16* __restrict__ Wbt){
  __shared__ float t[32][33];
  int bx = blockIdx.x & 15, by = blockIdx.x >> 4;
  int tx = threadIdx.x & 31, ty = threadIdx.x >> 5;  // 32 x 8
  #pragma unroll
  for(int i=0;i<32;i+=8)
    t[ty+i][tx] = Wb[(by*32+ty+i)*512 + bx*32+tx];
  __syncthreads();
  #pragma unroll
  for(int i=0;i<32;i+=8)
    Wbt[(bx*32+ty+i)*512 + by*32 + tx] = f2bf(t[tx][ty+i]);
}

// ---- f32 -> bf16, 8 elems/thread ----------------------------------------
__global__ void k_f2bf8(const float* __restrict__ in, u16* __restrict__ out, int n8){
  int i = blockIdx.x*256 + threadIdx.x;
  if(i >= n8) return;
  f32x4 a = *reinterpret_cast<const f32x4*>(in + (size_t)i*8);
  f32x4 b = *reinterpret_cast<const f32x4*>(in + (size_t)i*8 + 4);
  short8v o;
  o[0]=(short)f2bf(a[0]); o[1]=(short)f2bf(a[1]); o[2]=(short)f2bf(a[2]); o[3]=(short)f2bf(a[3]);
  o[4]=(short)f2bf(b[0]); o[5]=(short)f2bf(b[1]); o[6]=(short)f2bf(b[2]); o[7]=(short)f2bf(b[3]);
  *reinterpret_cast<short8v*>(out + (size_t)i*8) = o;
}

// ---- NT MFMA GEMM, 128x128 tile, BK=64, 4 waves, global_load_lds staging -
// epi 0: f scatter -> probe/gal bf16 rows (u0=probe,u1=gal)
// epi 1: gg distances -> packed bf16 K only (u0=Kb)
// epi 2: pg distances -> D2P=g1*d2 (fo0, cached store; e recomputed later)
// epi 3: split-K matvec K@Pdb -> bf16 cached partials (u0) + slice*1024*3072
// epi 4: MERGED gg+pg (XCD-swizzled): L<576 = epi1; else epi2 with
//        A=u1(probe), nrmA=f1(np_)
__global__ void __launch_bounds__(256) k_gemm(
    int epi,
    const u16* __restrict__ A, const u16* __restrict__ B,
    int kld, int nbn, int bps, int kspan,
    const float* __restrict__ nrmA, const float* __restrict__ nrmB,
    const float* __restrict__ gamma,
    u16* __restrict__ u0, u16* __restrict__ u1,
    float* __restrict__ fo0,
    float* __restrict__ f0, const float* __restrict__ f1)
{
  int bid = blockIdx.x;
  int slice, brow, bcol;
  if(epi==3){
    int L = (bid & 7)*96 + (bid >> 3);   // 768 blocks, bijective (768%8==0)
    slice = L / 192;
    int l = L - slice*192;
    bcol = l >> 3;                        // 12 bcols x 8 brows per XCD chunk
    brow = l & 7;                         // -> 3.9 MB panel set < 4 MB L2
  } else if(epi==4){
    int L = (bid & 7)*96 + (bid >> 3);
    slice = 0;
    if(L < 576){ epi = 1; brow = L / 24; bcol = L % 24; }
    else { epi = 2; int l = L - 576; brow = l / 24; bcol = l % 24; A = u1; nrmA = f1; }
  } else {
    slice = bid / bps; int rem = bid % bps;
    brow = rem / nbn; bcol = rem % nbn;
  }
  int t = threadIdx.x;
  int w = t >> 6, l = t & 63;
  int wr = w >> 1, wc = w & 1;
  const int l15 = l & 15, l16 = l >> 4;
  int k0 = slice * kspan;

  __shared__ __align__(16) u16 AB[2*128*64];   // A tile | B tile, 32 KB

  // staging role: waves 0,1 -> A halves; waves 2,3 -> B halves
  const u16* src = (w < 2) ? A + (size_t)brow*128*kld
                           : B + (size_t)bcol*128*kld;
  int half = w >> 1;            // 0 = A, 1 = B
  int wq   = (w & 1) * 8;       // chunk-call base within half

  f32x4 acc[4][4] = {};

  for(int kk = 0; kk < kspan; kk += 64){
    int kt = k0 + kk;
    #pragma unroll
    for(int q=0;q<8;q++){
      int cb  = (wq + q)*64;             // chunk base within half [0,1024)
      int idx = cb + l;                  // this lane's 16B chunk
      int row = idx >> 3, c8 = idx & 7;
      gload16(src + (size_t)row*kld + kt + c8*8,   // per-lane global src
              &AB[half*8192 + cb*8]);              // wave-uniform LDS dest
    }
    __syncthreads();                     // drains vmcnt before barrier
    #pragma unroll
    for(int ks=0; ks<2; ++ks){
      short8v af[4], bfr[4];
      int ko = ks*32 + l16*8;
      #pragma unroll
      for(int i=0;i<4;i++){
        af[i]  = *reinterpret_cast<const short8v*>(&AB[(wr*64+i*16+l15)*64 + ko]);
        bfr[i] = *reinterpret_cast<const short8v*>(&AB[8192 + (wc*64+i*16+l15)*64 + ko]);
      }
      #pragma unroll
      for(int i=0;i<4;i++)
        #pragma unroll
        for(int j=0;j<4;j++)
          acc[i][j] = __builtin_amdgcn_mfma_f32_16x16x32_bf16(af[i], bfr[j], acc[i][j], 0,0,0);
    }
    __syncthreads();
  }

  float g0 = 0.f, g1 = 0.f;
  if(epi==1 || epi==2){ g0 = gamma[0]; g1 = gamma[1]; }

  #pragma unroll
  for(int i=0;i<4;i++)
  #pragma unroll
  for(int j=0;j<4;j++)
  #pragma unroll
  for(int r=0;r<4;r++){
    int m = brow*128 + wr*64 + i*16 + l16*4 + r;   // C row (A index)
    int n = bcol*128 + wc*64 + j*16 + l15;         // C col (B index)
    float c = acc[i][j][r];
    if(epi==0){
      if((m & 3) == 0) u0[(size_t)(m>>2)*512 + n] = f2bf(c);
      else             u1[(size_t)((m>>2)*3 + (m&3) - 1)*512 + n] = f2bf(c);
    } else if(epi==1){
      float d2 = (nrmA[m] + nrmB[n] - 2.f*c) * (1.f/512.f);
      float e  = __expf(-g0*d2);
      u0[(size_t)m*3072 + n] = f2bf(e);            // packed K only
    } else if(epi==2){
      float d2 = (nrmA[m] + nrmB[n] - 2.f*c) * (1.f/512.f);
      fo0[(size_t)m*3072 + n] = g1*d2;              // D2P (cached; re-read 2x)
    } else {
      // bf16 split-K partial, regular cached store (L2 write-combining)
      u0[(size_t)slice*1024*3072 + (size_t)m*3072 + n] = f2bf(c);
    }
  }
}

// ---- row norms of bf16-rounded f (vectorized bf16x8 loads) ---------------
__global__ void k_norms(const u16* __restrict__ probe, const u16* __restrict__ gal,
                        float* __restrict__ np_, float* __restrict__ ng){
  int row = blockIdx.x, t = threadIdx.x;
  const u16* src = (row < 1024) ? probe + (size_t)row*512
                                : gal + (size_t)(row-1024)*512;
  float s = 0.f;
  if(t < 64){
    short8v v = *reinterpret_cast<const short8v*>(src + t*8);
    #pragma unroll
    for(int k=0;k<8;k++){ float f = bf2f((u16)v[k]); s += f*f; }
  }
  float r = blockSumBcast(s);
  if(t==0){ if(row < 1024) np_[row] = r; else ng[row-1024] = r; }
}

// ---- off-diagonal row sums of packed bf16 K (vectorized) -----------------
__global__ void k_rowsum(const u16* __restrict__ Kb, float* __restrict__ rs,
                         float* __restrict__ sq){
  int i = blockIdx.x, t = threadIdx.x;
  const u16* row = Kb + (size_t)i*3072;
  float s = 0.f;
  for(int j = t; j < 384; j += 256){
    short8v v = *reinterpret_cast<const short8v*>(row + j*8);
    #pragma unroll
    for(int k=0;k<8;k++) s += bf2f((u16)v[k]);
  }
  float r = blockSumBcast(s);
  if(t==0){
    float d = r - bf2f(row[i]);
    rs[i] = rsqrtf(d); sq[i] = sqrtf(d);
  }
}

// ---- CG init from D2P: e=exp(-(g0/g1)*d2p); R=sq*e; Pdb=bf16(e); rz=R.R --
__global__ void k_rzinit(const float* __restrict__ D2P, const float* __restrict__ sq,
                         float* __restrict__ R, u16* __restrict__ Pdb,
                         float* __restrict__ rz, const float* __restrict__ gamma){
  int p = blockIdx.x, t = threadIdx.x;
  float c1 = -gamma[0] / gamma[1];
  size_t base = (size_t)p*3072;
  float s = 0.f;
  #pragma unroll
  for(int j=0;j<6;j++){
    int g = 2*(t + j*256);
    f32x2 dv = *reinterpret_cast<const f32x2*>(&D2P[base+g]);
    float e0 = __expf(c1*dv[0]), e1 = __expf(c1*dv[1]);
    f32x2 rv; rv[0] = sq[g]*e0; rv[1] = sq[g+1]*e1;
    *reinterpret_cast<f32x2*>(&R[base+g]) = rv;
    unsigned pk = (unsigned)f2bf(e0) | ((unsigned)f2bf(e1) << 16);
    *reinterpret_cast<unsigned*>(&Pdb[base+g]) = pk;   // rs*r == e exactly
    s += rv[0]*rv[0] + rv[1]*rv[1];
  }
  float tot = blockSumBcast(s);
  if(t==0) rz[p] = tot;
}

// ---- fused CG step; SPb has 4 bf16 split-K partials ----------------------
// last: skip R/X/Pdb/rz updates, write out_pg (ch0,ch1) pairs directly
__global__ void __launch_bounds__(256) k_cgstep(
    const u16* __restrict__ SPb, u16* __restrict__ Pdb,
    float* __restrict__ R, float* __restrict__ X,
    float* __restrict__ rz,
    const float* __restrict__ rs, const float* __restrict__ sq,
    const float* __restrict__ D2P, float* __restrict__ outpg,
    int first, int last)
{
  const size_t SOFF = (size_t)1024*3072;
  int p = blockIdx.x, t = threadIdx.x;
  size_t base = (size_t)p*3072;
  float pd[12], ap[12];
  float papp = 0.f;
  #pragma unroll
  for(int j=0;j<6;j++){
    int g = 2*(t + j*256);
    unsigned pu = *reinterpret_cast<const unsigned*>(&Pdb[base+g]);
    unsigned s0 = *reinterpret_cast<const unsigned*>(&SPb[base+g]);
    unsigned s1 = *reinterpret_cast<const unsigned*>(&SPb[SOFF+base+g]);
    unsigned s2 = *reinterpret_cast<const unsigned*>(&SPb[2*SOFF+base+g]);
    unsigned s3 = *reinterpret_cast<const unsigned*>(&SPb[3*SOFF+base+g]);
    float pd0 = sq[g]   * bf2f((u16)(pu & 0xffffu));
    float pd1 = sq[g+1] * bf2f((u16)(pu >> 16));
    float sv0 = (bf2f((u16)(s0&0xffffu)) + bf2f((u16)(s1&0xffffu)))
              + (bf2f((u16)(s2&0xffffu)) + bf2f((u16)(s3&0xffffu)));
    float sv1 = (bf2f((u16)(s0>>16)) + bf2f((u16)(s1>>16)))
              + (bf2f((u16)(s2>>16)) + bf2f((u16)(s3>>16)));
    pd[2*j] = pd0; pd[2*j+1] = pd1;
    ap[2*j]   = pd0 - ALPHA_C*(rs[g]  *sv0);
    ap[2*j+1] = pd1 - ALPHA_C*(rs[g+1]*sv1);
    papp += pd0*ap[2*j] + pd1*ap[2*j+1];
  }
  float pap = blockSumBcast(papp);
  float rzv = rz[p];
  float a = rzv / fmaxf(pap, 1e-30f);

  if(!last){
    float rn[12];
    float rz2p = 0.f;
    #pragma unroll
    for(int j=0;j<6;j++){
      int g = 2*(t + j*256);
      f32x2 rv2 = *reinterpret_cast<const f32x2*>(&R[base+g]);
      float rv0 = rv2[0] - a*ap[2*j];
      float rv1 = rv2[1] - a*ap[2*j+1];
      rn[2*j]=rv0; rn[2*j+1]=rv1; rz2p += rv0*rv0 + rv1*rv1;
      f32x2 xo;
      if(first){ xo[0] = a*pd[2*j]; xo[1] = a*pd[2*j+1]; }
      else{
        f32x2 xv = *reinterpret_cast<const f32x2*>(&X[base+g]);
        xo[0] = xv[0] + a*pd[2*j]; xo[1] = xv[1] + a*pd[2*j+1];
      }
      *reinterpret_cast<f32x2*>(&X[base+g]) = xo;
      f32x2 rw; rw[0]=rv0; rw[1]=rv1;
      *reinterpret_cast<f32x2*>(&R[base+g]) = rw;
    }
    float rz2 = blockSumBcast(rz2p);
    float beta = rz2 / fmaxf(rzv, 1e-30f);
    #pragma unroll
    for(int j=0;j<6;j++){
      int g = 2*(t + j*256);
      float p0 = rn[2*j]   + beta*pd[2*j];
      float p1 = rn[2*j+1] + beta*pd[2*j+1];
      unsigned pk = (unsigned)f2bf(rs[g]*p0) | ((unsigned)f2bf(rs[g+1]*p1) << 16);
      *reinterpret_cast<unsigned*>(&Pdb[base+g]) = pk;
    }
    if(t==0) rz[p] = rz2;
  } else {
    // write interleaved (ch0, ch1) output pairs, coalesced 16B NT
    #pragma unroll
    for(int j=0;j<6;j++){
      int g = 2*(t + j*256);
      f32x2 xv = *reinterpret_cast<const f32x2*>(&X[base+g]);
      f32x2 dv = *reinterpret_cast<const f32x2*>(&D2P[base+g]);
      f32x4 o;
      o[0] = (1.0f - ALPHA_C) * (xv[0] + a*pd[2*j])   * rs[g];
      o[1] = dv[0];
      o[2] = (1.0f - ALPHA_C) * (xv[1] + a*pd[2*j+1]) * rs[g+1];
      o[3] = dv[1];
      __builtin_nontemporal_store(o, reinterpret_cast<f32x4*>(outpg + (base+g)*2));
    }
  }
}

// ---- final gg output: read Kb, emit (e, g1*d2) f32 pairs, coalesced ------
__global__ void k_ggout(const u16* __restrict__ Kb, float* __restrict__ gg,
                        const float* __restrict__ gamma, int n4){
  int i = blockIdx.x*256 + threadIdx.x;        // handles 4 elems
  if(i >= n4) return;
  float g0 = gamma[0], g1 = gamma[1];
  float ginv = -g1 / g0;                        // ch1 = g1*d2 = -g1/g0 * ln(e)
  u16x4 kv = *reinterpret_cast<const u16x4*>(Kb + (size_t)i*4);
  float e0 = bf2f(kv[0]), e1 = bf2f(kv[1]), e2 = bf2f(kv[2]), e3 = bf2f(kv[3]);
  f32x4 a, b;
  a[0] = e0; a[1] = ginv*__logf(e0);
  a[2] = e1; a[3] = ginv*__logf(e1);
  b[0] = e2; b[1] = ginv*__logf(e2);
  b[2] = e3; b[3] = ginv*__logf(e3);
  __builtin_nontemporal_store(a, reinterpret_cast<f32x4*>(gg + (size_t)i*8));
  __builtin_nontemporal_store(b, reinterpret_cast<f32x4*>(gg + (size_t)i*8 + 4));
}

extern "C" void kernel_launch(void* const* d_in, const int* in_sizes, int n_in,
                              void* d_out, int out_size, void* d_ws, size_t ws_size,
                              hipStream_t stream){
  const float* x     = (const float*)d_in[0];   // 4096x512
  const float* Wb    = (const float*)d_in[1];   // 512x512
  const float* gamma = (const float*)d_in[2];   // 2
  (void)in_sizes; (void)n_in; (void)out_size;

  float* out    = (float*)d_out;
  float* out_pg = out;                                  // [1024][3072][2] f32
  float* out_gg = out + (size_t)1024*3072*2;            // [3072][3072][2] f32
  u16*   SPb    = (u16*)out_gg;  // 4 bf16 split-K partials (25.2MB) in out_gg

  if(ws_size < WS_NEEDED){                              // diagnostic canary
    k_canary<<<1, 1, 0, stream>>>(out);
    return;
  }

  char* ws = (char*)d_ws;
  size_t off = 0;
  auto alloc = [&](size_t bytes)->char*{
    char* p = ws + off; off = (off + bytes + 255) & ~(size_t)255; return p;
  };
  // regionA: xbf(4.19MB)+wbt(0.5MB) early, reused as R(12.6MB) later
  char*  regionA = alloc((size_t)1024*3072*4);
  u16*   xbf   = (u16*)regionA;
  u16*   wbt   = (u16*)(regionA + (size_t)4096*512*2);
  float* R     = (float*)regionA;
  u16*   probe = (u16*)  alloc((size_t)1024*512*2);
  u16*   gal   = (u16*)  alloc((size_t)3072*512*2);
  u16*   Kb    = (u16*)  alloc((size_t)3072*3072*2);
  float* np_   = (float*)alloc(1024*4);
  float* ng    = (float*)alloc(3072*4);
  float* rs    = (float*)alloc(3072*4);
  float* sq    = (float*)alloc(3072*4);
  float* rz    = (float*)alloc(1024*4);
  float* X     = (float*)alloc((size_t)1024*3072*4);
  float* D2P   = (float*)alloc((size_t)1024*3072*4);
  u16*   Pdb   = (u16*)  alloc((size_t)1024*3072*2);

  // 1. prep bf16 operands
  k_wbt  <<<256, 256, 0, stream>>>(Wb, wbt);
  k_f2bf8<<<1024, 256, 0, stream>>>(x, xbf, 4096*512/8);

  // 2. f = x@Wb -> probe/gal bf16 rows   (32x4 = 128 blocks)
  k_gemm<<<128, 256, 0, stream>>>(0, xbf, wbt, 512, 4, 128, 512,
      nullptr, nullptr, nullptr, probe, gal, nullptr, nullptr, nullptr);

  // 3. row norms
  k_norms<<<4096, 256, 0, stream>>>(probe, gal, np_, ng);

  // 4. MERGED gg+pg distances (XCD-swizzled): gg -> Kb | pg -> D2P
  k_gemm<<<768, 256, 0, stream>>>(4, gal, gal, 512, 24, 768, 512,
      ng, ng, gamma, Kb, probe, D2P, nullptr, np_);

  // 5. off-diag row sums -> rs = d^{-1/2}, sq = d^{1/2}
  k_rowsum<<<3072, 256, 0, stream>>>(Kb, rs, sq);

  // 6. CG init from D2P (e recomputed; R = sq*e, Pdb = bf16(e), rz)
  k_rzinit<<<1024, 256, 0, stream>>>(D2P, sq, R, Pdb, rz, gamma);

  // 7. CG on (I - alpha*S); matvec split-K=4 -> bf16 cached partials
  //    last cgstep writes out_pg directly (both channels)
  for(int it = 0; it < NITER; ++it){
    k_gemm<<<768, 256, 0, stream>>>(3, Pdb, Kb, 3072, 24, 192, 768,
        nullptr, nullptr, nullptr, SPb, nullptr, nullptr, nullptr, nullptr);
    k_cgstep<<<1024, 256, 0, stream>>>(SPb, Pdb, R, X, rz, rs, sq,
        D2P, out_pg, it==0 ? 1 : 0, it==NITER-1 ? 1 : 0);
  }

  // 8. regenerate gg output pairs from Kb (coalesced streaming writes)
  k_ggout<<<9216, 256, 0, stream>>>(Kb, out_gg, gamma, 3072*3072/4);
}

// Round 12
// 245.898 us; speedup vs baseline: 11.2990x; 1.0125x over previous
//
#include <hip/hip_runtime.h>

typedef unsigned short u16;
typedef short short8v __attribute__((ext_vector_type(8)));
typedef float f32x4 __attribute__((ext_vector_type(4)));
typedef float f32x2 __attribute__((ext_vector_type(2)));
typedef unsigned short u16x4 __attribute__((ext_vector_type(4)));

#define ALPHA_C 0.99f
#define NITER 2
#define WS_NEEDED 61000000UL

__device__ __forceinline__ u16 f2bf(float f){
  union { float f; unsigned u; } v; v.f = f;
  unsigned r = (v.u + 0x7FFFu + ((v.u >> 16) & 1u)) >> 16;
  return (u16)r;
}
__device__ __forceinline__ float bf2f(u16 u){
  union { unsigned u; float f; } v; v.u = ((unsigned)u) << 16;
  return v.f;
}

// async global->LDS, 16B per lane; lds dest must be wave-uniform base
__device__ __forceinline__ void gload16(const void* g, void* l){
  __builtin_amdgcn_global_load_lds(
    (const __attribute__((address_space(1))) unsigned*)g,
    (__attribute__((address_space(3))) unsigned*)l, 16, 0, 0);
}

// block=256: full sum broadcast to ALL threads
__device__ __forceinline__ float blockSumBcast(float v){
  #pragma unroll
  for(int off=32; off>0; off>>=1) v += __shfl_down(v, off, 64);
  __shared__ float sm[4];
  __shared__ float res;
  int w = threadIdx.x >> 6;
  if((threadIdx.x & 63)==0) sm[w] = v;
  __syncthreads();
  if(threadIdx.x==0) res = sm[0]+sm[1]+sm[2]+sm[3];
  __syncthreads();
  return res;
}

__global__ void k_canary(float* out){ out[0] = 12345.0f; }

// ---- Wb transpose->bf16; also zero the atomic accumulators (7168 f32) ----
__global__ void k_wbt(const float* __restrict__ Wb, u16* __restrict__ Wbt,
                      float* __restrict__ zbuf){
  int zi = blockIdx.x*256 + threadIdx.x;
  if(zi < 7168) zbuf[zi] = 0.f;
  __shared__ float t[32][33];
  int bx = blockIdx.x & 15, by = blockIdx.x >> 4;
  int tx = threadIdx.x & 31, ty = threadIdx.x >> 5;  // 32 x 8
  #pragma unroll
  for(int i=0;i<32;i+=8)
    t[ty+i][tx] = Wb[(by*32+ty+i)*512 + bx*32+tx];
  __syncthreads();
  #pragma unroll
  for(int i=0;i<32;i+=8)
    Wbt[(bx*32+ty+i)*512 + by*32 + tx] = f2bf(t[tx][ty+i]);
}

// ---- f32 -> bf16, 8 elems/thread ----------------------------------------
__global__ void k_f2bf8(const float* __restrict__ in, u16* __restrict__ out, int n8){
  int i = blockIdx.x*256 + threadIdx.x;
  if(i >= n8) return;
  f32x4 a = *reinterpret_cast<const f32x4*>(in + (size_t)i*8);
  f32x4 b = *reinterpret_cast<const f32x4*>(in + (size_t)i*8 + 4);
  short8v o;
  o[0]=(short)f2bf(a[0]); o[1]=(short)f2bf(a[1]); o[2]=(short)f2bf(a[2]); o[3]=(short)f2bf(a[3]);
  o[4]=(short)f2bf(b[0]); o[5]=(short)f2bf(b[1]); o[6]=(short)f2bf(b[2]); o[7]=(short)f2bf(b[3]);
  *reinterpret_cast<short8v*>(out + (size_t)i*8) = o;
}

// ---- NT MFMA GEMM, 128x128 tile, BK=64, 4 waves, global_load_lds staging -
// epi 0: f scatter -> probe/gal bf16 rows (u0=probe,u1=gal) + ATOMIC norms
//        (fa0=np_, fa1=ng)
// epi 1: gg distances -> packed bf16 K (u0=Kb) + ATOMIC off-diag rowsums
//        of f32 e (fa0=rsum)
// epi 2: pg distances -> D2P=g1*d2 (fo0)
// epi 3: split-K matvec K@Pdb -> bf16 cached partials (u0) + slice*1024*3072
// epi 4: MERGED gg+pg (XCD-swizzled): L<576 = epi1; else epi2 with
//        A=u1(probe), nrmA=f1(np_)
__global__ void __launch_bounds__(256) k_gemm(
    int epi,
    const u16* __restrict__ A, const u16* __restrict__ B,
    int kld, int nbn, int bps, int kspan,
    const float* __restrict__ nrmA, const float* __restrict__ nrmB,
    const float* __restrict__ gamma,
    u16* __restrict__ u0, u16* __restrict__ u1,
    float* __restrict__ fo0,
    float* __restrict__ fa0, float* __restrict__ fa1,
    const float* __restrict__ f1)
{
  int bid = blockIdx.x;
  int slice, brow, bcol;
  if(epi==3){
    int L = (bid & 7)*96 + (bid >> 3);   // 768 blocks, bijective (768%8==0)
    slice = L / 192;
    int l = L - slice*192;
    bcol = l >> 3;                        // 12 bcols x 8 brows per XCD chunk
    brow = l & 7;                         // -> 3.9 MB panel set < 4 MB L2
  } else if(epi==4){
    int L = (bid & 7)*96 + (bid >> 3);
    slice = 0;
    if(L < 576){ epi = 1; brow = L / 24; bcol = L % 24; }
    else { epi = 2; int l = L - 576; brow = l / 24; bcol = l % 24; A = u1; nrmA = f1; }
  } else {
    slice = bid / bps; int rem = bid % bps;
    brow = rem / nbn; bcol = rem % nbn;
  }
  int t = threadIdx.x;
  int w = t >> 6, l = t & 63;
  int wr = w >> 1, wc = w & 1;
  const int l15 = l & 15, l16 = l >> 4;
  int k0 = slice * kspan;

  __shared__ __align__(16) u16 AB[2*128*64];   // A tile | B tile, 32 KB

  // staging role: waves 0,1 -> A halves; waves 2,3 -> B halves
  const u16* src = (w < 2) ? A + (size_t)brow*128*kld
                           : B + (size_t)bcol*128*kld;
  int half = w >> 1;            // 0 = A, 1 = B
  int wq   = (w & 1) * 8;       // chunk-call base within half

  f32x4 acc[4][4] = {};

  for(int kk = 0; kk < kspan; kk += 64){
    int kt = k0 + kk;
    #pragma unroll
    for(int q=0;q<8;q++){
      int cb  = (wq + q)*64;             // chunk base within half [0,1024)
      int idx = cb + l;                  // this lane's 16B chunk
      int row = idx >> 3, c8 = idx & 7;
      gload16(src + (size_t)row*kld + kt + c8*8,   // per-lane global src
              &AB[half*8192 + cb*8]);              // wave-uniform LDS dest
    }
    __syncthreads();                     // drains vmcnt before barrier
    #pragma unroll
    for(int ks=0; ks<2; ++ks){
      short8v af[4], bfr[4];
      int ko = ks*32 + l16*8;
      #pragma unroll
      for(int i=0;i<4;i++){
        af[i]  = *reinterpret_cast<const short8v*>(&AB[(wr*64+i*16+l15)*64 + ko]);
        bfr[i] = *reinterpret_cast<const short8v*>(&AB[8192 + (wc*64+i*16+l15)*64 + ko]);
      }
      #pragma unroll
      for(int i=0;i<4;i++)
        #pragma unroll
        for(int j=0;j<4;j++)
          acc[i][j] = __builtin_amdgcn_mfma_f32_16x16x32_bf16(af[i], bfr[j], acc[i][j], 0,0,0);
    }
    __syncthreads();
  }

  float g0 = 0.f, g1 = 0.f;
  if(epi==1 || epi==2){ g0 = gamma[0]; g1 = gamma[1]; }

  float nacc[4][4] = {};   // per-(i,r) atomic accumulator (epi 0/1 only)

  #pragma unroll
  for(int i=0;i<4;i++)
  #pragma unroll
  for(int j=0;j<4;j++)
  #pragma unroll
  for(int r=0;r<4;r++){
    int m = brow*128 + wr*64 + i*16 + l16*4 + r;   // C row (A index)
    int n = bcol*128 + wc*64 + j*16 + l15;         // C col (B index)
    float c = acc[i][j][r];
    if(epi==0){
      u16 b = f2bf(c);
      if((m & 3) == 0) u0[(size_t)(m>>2)*512 + n] = b;
      else             u1[(size_t)((m>>2)*3 + (m&3) - 1)*512 + n] = b;
      float v = bf2f(b);
      nacc[i][r] += v*v;
    } else if(epi==1){
      float d2 = (nrmA[m] + nrmB[n] - 2.f*c) * (1.f/512.f);
      float e  = __expf(-g0*d2);
      u0[(size_t)m*3072 + n] = f2bf(e);            // packed K only
      if(m != n) nacc[i][r] += e;                  // off-diag rowsum (f32 e)
    } else if(epi==2){
      float d2 = (nrmA[m] + nrmB[n] - 2.f*c) * (1.f/512.f);
      fo0[(size_t)m*3072 + n] = g1*d2;              // D2P (cached; re-read 2x)
    } else {
      // bf16 split-K partial, regular cached store (L2 write-combining)
      u0[(size_t)slice*1024*3072 + (size_t)m*3072 + n] = f2bf(c);
    }
  }

  if(epi <= 1){
    // reduce each (i,r) over the 16 lanes sharing row m, then one atomicAdd
    #pragma unroll
    for(int i=0;i<4;i++)
    #pragma unroll
    for(int r=0;r<4;r++){
      float s = nacc[i][r];
      #pragma unroll
      for(int mk=1; mk<16; mk<<=1) s += __shfl_xor(s, mk, 64);
      if(l15 == 0){
        int m = brow*128 + wr*64 + i*16 + l16*4 + r;
        if(epi==0){
          if((m & 3) == 0) atomicAdd(&fa0[m>>2], s);
          else             atomicAdd(&fa1[(m>>2)*3 + (m&3) - 1], s);
        } else {
          atomicAdd(&fa0[m], s);
        }
      }
    }
  }
}

// ---- rs = d^{-1/2}, sq = d^{1/2} from atomic rowsums ---------------------
__global__ void k_rowfin(const float* __restrict__ rsum, float* __restrict__ rs,
                         float* __restrict__ sq){
  int i = blockIdx.x*256 + threadIdx.x;
  if(i >= 3072) return;
  float d = rsum[i];
  rs[i] = rsqrtf(d); sq[i] = sqrtf(d);
}

// ---- CG init from D2P: e=exp(-(g0/g1)*d2p); Rb=bf16(sq*e); Pdb=bf16(e) ---
__global__ void k_rzinit(const float* __restrict__ D2P, const float* __restrict__ sq,
                         u16* __restrict__ Rb, u16* __restrict__ Pdb,
                         float* __restrict__ rz, const float* __restrict__ gamma){
  int p = blockIdx.x, t = threadIdx.x;
  float c1 = -gamma[0] / gamma[1];
  size_t base = (size_t)p*3072;
  float s = 0.f;
  #pragma unroll
  for(int j=0;j<6;j++){
    int g = 2*(t + j*256);
    f32x2 dv = *reinterpret_cast<const f32x2*>(&D2P[base+g]);
    float e0 = __expf(c1*dv[0]), e1 = __expf(c1*dv[1]);
    float r0 = sq[g]*e0, r1 = sq[g+1]*e1;
    *reinterpret_cast<unsigned*>(&Rb[base+g]) =
        (unsigned)f2bf(r0) | ((unsigned)f2bf(r1) << 16);
    *reinterpret_cast<unsigned*>(&Pdb[base+g]) =
        (unsigned)f2bf(e0) | ((unsigned)f2bf(e1) << 16);   // rs*(sq*e) == e
    s += r0*r0 + r1*r1;
  }
  float tot = blockSumBcast(s);
  if(t==0) rz[p] = tot;
}

// ---- fused CG step; SPb has 4 bf16 split-K partials; bf16 R/X state ------
// last: skip R/X/Pdb/rz updates, write out_pg (ch0,ch1) pairs directly
__global__ void __launch_bounds__(256) k_cgstep(
    const u16* __restrict__ SPb, u16* __restrict__ Pdb,
    u16* __restrict__ Rb, u16* __restrict__ Xb,
    float* __restrict__ rz,
    const float* __restrict__ rs, const float* __restrict__ sq,
    const float* __restrict__ D2P, float* __restrict__ outpg,
    int first, int last)
{
  const size_t SOFF = (size_t)1024*3072;
  int p = blockIdx.x, t = threadIdx.x;
  size_t base = (size_t)p*3072;
  float pd[12], ap[12];
  float papp = 0.f;
  #pragma unroll
  for(int j=0;j<6;j++){
    int g = 2*(t + j*256);
    unsigned pu = *reinterpret_cast<const unsigned*>(&Pdb[base+g]);
    unsigned s0 = *reinterpret_cast<const unsigned*>(&SPb[base+g]);
    unsigned s1 = *reinterpret_cast<const unsigned*>(&SPb[SOFF+base+g]);
    unsigned s2 = *reinterpret_cast<const unsigned*>(&SPb[2*SOFF+base+g]);
    unsigned s3 = *reinterpret_cast<const unsigned*>(&SPb[3*SOFF+base+g]);
    float pd0 = sq[g]   * bf2f((u16)(pu & 0xffffu));
    float pd1 = sq[g+1] * bf2f((u16)(pu >> 16));
    float sv0 = (bf2f((u16)(s0&0xffffu)) + bf2f((u16)(s1&0xffffu)))
              + (bf2f((u16)(s2&0xffffu)) + bf2f((u16)(s3&0xffffu)));
    float sv1 = (bf2f((u16)(s0>>16)) + bf2f((u16)(s1>>16)))
              + (bf2f((u16)(s2>>16)) + bf2f((u16)(s3>>16)));
    pd[2*j] = pd0; pd[2*j+1] = pd1;
    ap[2*j]   = pd0 - ALPHA_C*(rs[g]  *sv0);
    ap[2*j+1] = pd1 - ALPHA_C*(rs[g+1]*sv1);
    papp += pd0*ap[2*j] + pd1*ap[2*j+1];
  }
  float pap = blockSumBcast(papp);
  float rzv = rz[p];
  float a = rzv / fmaxf(pap, 1e-30f);

  if(!last){
    float rn[12];
    float rz2p = 0.f;
    #pragma unroll
    for(int j=0;j<6;j++){
      int g = 2*(t + j*256);
      unsigned ru = *reinterpret_cast<const unsigned*>(&Rb[base+g]);
      float rv0 = bf2f((u16)(ru & 0xffffu)) - a*ap[2*j];
      float rv1 = bf2f((u16)(ru >> 16))     - a*ap[2*j+1];
      rn[2*j]=rv0; rn[2*j+1]=rv1; rz2p += rv0*rv0 + rv1*rv1;
      float xv0, xv1;
      if(first){ xv0 = a*pd[2*j]; xv1 = a*pd[2*j+1]; }
      else{
        unsigned xu = *reinterpret_cast<const unsigned*>(&Xb[base+g]);
        xv0 = bf2f((u16)(xu & 0xffffu)) + a*pd[2*j];
        xv1 = bf2f((u16)(xu >> 16))     + a*pd[2*j+1];
      }
      *reinterpret_cast<unsigned*>(&Xb[base+g]) =
          (unsigned)f2bf(xv0) | ((unsigned)f2bf(xv1) << 16);
      *reinterpret_cast<unsigned*>(&Rb[base+g]) =
          (unsigned)f2bf(rv0) | ((unsigned)f2bf(rv1) << 16);
    }
    float rz2 = blockSumBcast(rz2p);
    float beta = rz2 / fmaxf(rzv, 1e-30f);
    #pragma unroll
    for(int j=0;j<6;j++){
      int g = 2*(t + j*256);
      float p0 = rn[2*j]   + beta*pd[2*j];
      float p1 = rn[2*j+1] + beta*pd[2*j+1];
      unsigned pk = (unsigned)f2bf(rs[g]*p0) | ((unsigned)f2bf(rs[g+1]*p1) << 16);
      *reinterpret_cast<unsigned*>(&Pdb[base+g]) = pk;
    }
    if(t==0) rz[p] = rz2;
  } else {
    // write interleaved (ch0, ch1) output pairs, coalesced 16B NT
    #pragma unroll
    for(int j=0;j<6;j++){
      int g = 2*(t + j*256);
      unsigned xu = *reinterpret_cast<const unsigned*>(&Xb[base+g]);
      f32x2 dv = *reinterpret_cast<const f32x2*>(&D2P[base+g]);
      f32x4 o;
      o[0] = (1.0f - ALPHA_C) * (bf2f((u16)(xu & 0xffffu)) + a*pd[2*j])   * rs[g];
      o[1] = dv[0];
      o[2] = (1.0f - ALPHA_C) * (bf2f((u16)(xu >> 16))     + a*pd[2*j+1]) * rs[g+1];
      o[3] = dv[1];
      __builtin_nontemporal_store(o, reinterpret_cast<f32x4*>(outpg + (base+g)*2));
    }
  }
}

// ---- final gg output: read Kb, emit (e, g1*d2) f32 pairs, coalesced ------
__global__ void k_ggout(const u16* __restrict__ Kb, float* __restrict__ gg,
                        const float* __restrict__ gamma, int n4){
  int i = blockIdx.x*256 + threadIdx.x;        // handles 4 elems
  if(i >= n4) return;
  float g0 = gamma[0], g1 = gamma[1];
  float ginv = -g1 / g0;                        // ch1 = g1*d2 = -g1/g0 * ln(e)
  u16x4 kv = *reinterpret_cast<const u16x4*>(Kb + (size_t)i*4);
  float e0 = bf2f(kv[0]), e1 = bf2f(kv[1]), e2 = bf2f(kv[2]), e3 = bf2f(kv[3]);
  f32x4 a, b;
  a[0] = e0; a[1] = ginv*__logf(e0);
  a[2] = e1; a[3] = ginv*__logf(e1);
  b[0] = e2; b[1] = ginv*__logf(e2);
  b[2] = e3; b[3] = ginv*__logf(e3);
  __builtin_nontemporal_store(a, reinterpret_cast<f32x4*>(gg + (size_t)i*8));
  __builtin_nontemporal_store(b, reinterpret_cast<f32x4*>(gg + (size_t)i*8 + 4));
}

extern "C" void kernel_launch(void* const* d_in, const int* in_sizes, int n_in,
                              void* d_out, int out_size, void* d_ws, size_t ws_size,
                              hipStream_t stream){
  const float* x     = (const float*)d_in[0];   // 4096x512
  const float* Wb    = (const float*)d_in[1];   // 512x512
  const float* gamma = (const float*)d_in[2];   // 2
  (void)in_sizes; (void)n_in; (void)out_size;

  float* out    = (float*)d_out;
  float* out_pg = out;                                  // [1024][3072][2] f32
  float* out_gg = out + (size_t)1024*3072*2;            // [3072][3072][2] f32
  u16*   SPb    = (u16*)out_gg;  // 4 bf16 split-K partials (25.2MB) in out_gg

  if(ws_size < WS_NEEDED){                              // diagnostic canary
    k_canary<<<1, 1, 0, stream>>>(out);
    return;
  }

  char* ws = (char*)d_ws;
  size_t off = 0;
  auto alloc = [&](size_t bytes)->char*{
    char* p = ws + off; off = (off + bytes + 255) & ~(size_t)255; return p;
  };
  // regionA: xbf(4.19MB)+wbt(0.5MB) early, reused as Rb(6.3MB) later
  char*  regionA = alloc((size_t)4096*512*2 + (size_t)512*512*2 + 512);
  u16*   xbf   = (u16*)regionA;
  u16*   wbt   = (u16*)(regionA + (size_t)4096*512*2);
  u16*   Rb    = (u16*)regionA;
  u16*   probe = (u16*)  alloc((size_t)1024*512*2);
  u16*   gal   = (u16*)  alloc((size_t)3072*512*2);
  u16*   Kb    = (u16*)  alloc((size_t)3072*3072*2);
  // atomic accumulators: np_(1024) | ng(3072) | rsum(3072) contiguous = 7168
  float* np_   = (float*)alloc(1024*4);
  float* ng    = (float*)alloc(3072*4);
  float* rsum  = (float*)alloc(3072*4);
  float* rs    = (float*)alloc(3072*4);
  float* sq    = (float*)alloc(3072*4);
  float* rz    = (float*)alloc(1024*4);
  u16*   Xb    = (u16*)  alloc((size_t)1024*3072*2);
  float* D2P   = (float*)alloc((size_t)1024*3072*4);
  u16*   Pdb   = (u16*)  alloc((size_t)1024*3072*2);

  // 1. prep bf16 operands + zero atomic accumulators
  k_wbt  <<<256, 256, 0, stream>>>(Wb, wbt, np_);
  k_f2bf8<<<1024, 256, 0, stream>>>(x, xbf, 4096*512/8);

  // 2. f = x@Wb -> probe/gal bf16 rows + fused row norms (atomics)
  k_gemm<<<128, 256, 0, stream>>>(0, xbf, wbt, 512, 4, 128, 512,
      nullptr, nullptr, nullptr, probe, gal, nullptr, np_, ng, nullptr);

  // 3. MERGED gg+pg distances (XCD-swizzled): gg -> Kb + fused off-diag
  //    rowsums (atomics) | pg -> D2P
  k_gemm<<<768, 256, 0, stream>>>(4, gal, gal, 512, 24, 768, 512,
      ng, ng, gamma, Kb, probe, D2P, rsum, nullptr, np_);

  // 4. rs = d^{-1/2}, sq = d^{1/2}
  k_rowfin<<<12, 256, 0, stream>>>(rsum, rs, sq);

  // 5. CG init from D2P (e recomputed; Rb = bf16(sq*e), Pdb = bf16(e), rz)
  k_rzinit<<<1024, 256, 0, stream>>>(D2P, sq, Rb, Pdb, rz, gamma);

  // 6. CG on (I - alpha*S); matvec split-K=4 -> bf16 cached partials
  //    last cgstep writes out_pg directly (both channels)
  for(int it = 0; it < NITER; ++it){
    k_gemm<<<768, 256, 0, stream>>>(3, Pdb, Kb, 3072, 24, 192, 768,
        nullptr, nullptr, nullptr, SPb, nullptr, nullptr, nullptr, nullptr, nullptr);
    k_cgstep<<<1024, 256, 0, stream>>>(SPb, Pdb, Rb, Xb, rz, rs, sq,
        D2P, out_pg, it==0 ? 1 : 0, it==NITER-1 ? 1 : 0);
  }

  // 7. regenerate gg output pairs from Kb (coalesced streaming writes)
  k_ggout<<<9216, 256, 0, stream>>>(Kb, out_gg, gamma, 3072*3072/4);
}

// Round 13
// 243.800 us; speedup vs baseline: 11.3962x; 1.0086x over previous
//
#include <hip/hip_runtime.h>

typedef unsigned short u16;
typedef short short8v __attribute__((ext_vector_type(8)));
typedef float f32x4 __attribute__((ext_vector_type(4)));
typedef float f32x2 __attribute__((ext_vector_type(2)));
typedef unsigned short u16x4 __attribute__((ext_vector_type(4)));

#define ALPHA_C 0.99f
#define NITER 2
#define WS_NEEDED 61000000UL

__device__ __forceinline__ u16 f2bf(float f){
  union { float f; unsigned u; } v; v.f = f;
  unsigned r = (v.u + 0x7FFFu + ((v.u >> 16) & 1u)) >> 16;
  return (u16)r;
}
__device__ __forceinline__ float bf2f(u16 u){
  union { unsigned u; float f; } v; v.u = ((unsigned)u) << 16;
  return v.f;
}

// async global->LDS, 16B per lane; lds dest must be wave-uniform base
__device__ __forceinline__ void gload16(const void* g, void* l){
  __builtin_amdgcn_global_load_lds(
    (const __attribute__((address_space(1))) unsigned*)g,
    (__attribute__((address_space(3))) unsigned*)l, 16, 0, 0);
}

// block=256: full sum broadcast to ALL threads
__device__ __forceinline__ float blockSumBcast(float v){
  #pragma unroll
  for(int off=32; off>0; off>>=1) v += __shfl_down(v, off, 64);
  __shared__ float sm[4];
  __shared__ float res;
  int w = threadIdx.x >> 6;
  if((threadIdx.x & 63)==0) sm[w] = v;
  __syncthreads();
  if(threadIdx.x==0) res = sm[0]+sm[1]+sm[2]+sm[3];
  __syncthreads();
  return res;
}

__global__ void k_canary(float* out){ out[0] = 12345.0f; }

// ---- fused prep: blocks [0,1024) = x f32->bf16 (8/thread);
//      blocks [1024,1280) = Wb transpose->bf16 + zero atomic accumulators --
__global__ void k_prep(const float* __restrict__ x, const float* __restrict__ Wb,
                       u16* __restrict__ xbf, u16* __restrict__ wbt,
                       float* __restrict__ zbuf){
  __shared__ float t[32][33];
  int bid = blockIdx.x;
  if(bid < 1024){
    int i = bid*256 + threadIdx.x;              // 262144 = 4096*512/8 exactly
    f32x4 a = *reinterpret_cast<const f32x4*>(x + (size_t)i*8);
    f32x4 b = *reinterpret_cast<const f32x4*>(x + (size_t)i*8 + 4);
    short8v o;
    o[0]=(short)f2bf(a[0]); o[1]=(short)f2bf(a[1]); o[2]=(short)f2bf(a[2]); o[3]=(short)f2bf(a[3]);
    o[4]=(short)f2bf(b[0]); o[5]=(short)f2bf(b[1]); o[6]=(short)f2bf(b[2]); o[7]=(short)f2bf(b[3]);
    *reinterpret_cast<short8v*>(xbf + (size_t)i*8) = o;
  } else {
    int b = bid - 1024;                          // 0..255
    int zi = b*256 + threadIdx.x;
    if(zi < 4096) zbuf[zi] = 0.f;
    int bx = b & 15, by = b >> 4;
    int tx = threadIdx.x & 31, ty = threadIdx.x >> 5;  // 32 x 8
    #pragma unroll
    for(int i=0;i<32;i+=8)
      t[ty+i][tx] = Wb[(by*32+ty+i)*512 + bx*32+tx];
    __syncthreads();
    #pragma unroll
    for(int i=0;i<32;i+=8)
      wbt[(bx*32+ty+i)*512 + by*32 + tx] = f2bf(t[tx][ty+i]);
  }
}

// ---- NT MFMA GEMM, 128x128 tile, BK=64, 4 waves, global_load_lds staging -
// epi 0: f scatter -> probe/gal bf16 rows (u0=probe,u1=gal) + ATOMIC norms
//        (fa0=np_, fa1=ng)
// epi 1: gg distances -> packed bf16 K only (u0=Kb)
// epi 2: pg distances -> D2P=g1*d2 (fo0)
// epi 3: split-K matvec K@Pdb -> bf16 cached partials (u0) + slice*1024*3072
// epi 4: MERGED gg+pg (XCD-swizzled): L<576 = epi1; else epi2 with
//        A=u1(probe), nrmA=f1(np_)
__global__ void __launch_bounds__(256) k_gemm(
    int epi,
    const u16* __restrict__ A, const u16* __restrict__ B,
    int kld, int nbn, int bps, int kspan,
    const float* __restrict__ nrmA, const float* __restrict__ nrmB,
    const float* __restrict__ gamma,
    u16* __restrict__ u0, u16* __restrict__ u1,
    float* __restrict__ fo0,
    float* __restrict__ fa0, float* __restrict__ fa1,
    const float* __restrict__ f1)
{
  int bid = blockIdx.x;
  int slice, brow, bcol;
  if(epi==3){
    int L = (bid & 7)*96 + (bid >> 3);   // 768 blocks, bijective (768%8==0)
    slice = L / 192;
    int l = L - slice*192;
    bcol = l >> 3;                        // 12 bcols x 8 brows per XCD chunk
    brow = l & 7;                         // -> 3.9 MB panel set < 4 MB L2
  } else if(epi==4){
    int L = (bid & 7)*96 + (bid >> 3);
    slice = 0;
    if(L < 576){ epi = 1; brow = L / 24; bcol = L % 24; }
    else { epi = 2; int l = L - 576; brow = l / 24; bcol = l % 24; A = u1; nrmA = f1; }
  } else {
    slice = bid / bps; int rem = bid % bps;
    brow = rem / nbn; bcol = rem % nbn;
  }
  int t = threadIdx.x;
  int w = t >> 6, l = t & 63;
  int wr = w >> 1, wc = w & 1;
  const int l15 = l & 15, l16 = l >> 4;
  int k0 = slice * kspan;

  __shared__ __align__(16) u16 AB[2*128*64];   // A tile | B tile, 32 KB

  // staging role: waves 0,1 -> A halves; waves 2,3 -> B halves
  const u16* src = (w < 2) ? A + (size_t)brow*128*kld
                           : B + (size_t)bcol*128*kld;
  int half = w >> 1;            // 0 = A, 1 = B
  int wq   = (w & 1) * 8;       // chunk-call base within half

  f32x4 acc[4][4] = {};

  for(int kk = 0; kk < kspan; kk += 64){
    int kt = k0 + kk;
    #pragma unroll
    for(int q=0;q<8;q++){
      int cb  = (wq + q)*64;             // chunk base within half [0,1024)
      int idx = cb + l;                  // this lane's 16B chunk
      int row = idx >> 3, c8 = idx & 7;
      gload16(src + (size_t)row*kld + kt + c8*8,   // per-lane global src
              &AB[half*8192 + cb*8]);              // wave-uniform LDS dest
    }
    __syncthreads();                     // drains vmcnt before barrier
    #pragma unroll
    for(int ks=0; ks<2; ++ks){
      short8v af[4], bfr[4];
      int ko = ks*32 + l16*8;
      #pragma unroll
      for(int i=0;i<4;i++){
        af[i]  = *reinterpret_cast<const short8v*>(&AB[(wr*64+i*16+l15)*64 + ko]);
        bfr[i] = *reinterpret_cast<const short8v*>(&AB[8192 + (wc*64+i*16+l15)*64 + ko]);
      }
      #pragma unroll
      for(int i=0;i<4;i++)
        #pragma unroll
        for(int j=0;j<4;j++)
          acc[i][j] = __builtin_amdgcn_mfma_f32_16x16x32_bf16(af[i], bfr[j], acc[i][j], 0,0,0);
    }
    __syncthreads();
  }

  float g0 = 0.f, g1 = 0.f;
  if(epi==1 || epi==2){ g0 = gamma[0]; g1 = gamma[1]; }

  float nacc[4][4] = {};   // per-(i,r) norm accumulator (epi 0 only)

  #pragma unroll
  for(int i=0;i<4;i++)
  #pragma unroll
  for(int j=0;j<4;j++)
  #pragma unroll
  for(int r=0;r<4;r++){
    int m = brow*128 + wr*64 + i*16 + l16*4 + r;   // C row (A index)
    int n = bcol*128 + wc*64 + j*16 + l15;         // C col (B index)
    float c = acc[i][j][r];
    if(epi==0){
      u16 b = f2bf(c);
      if((m & 3) == 0) u0[(size_t)(m>>2)*512 + n] = b;
      else             u1[(size_t)((m>>2)*3 + (m&3) - 1)*512 + n] = b;
      float v = bf2f(b);
      nacc[i][r] += v*v;
    } else if(epi==1){
      float d2 = (nrmA[m] + nrmB[n] - 2.f*c) * (1.f/512.f);
      float e  = __expf(-g0*d2);
      u0[(size_t)m*3072 + n] = f2bf(e);            // packed K only
    } else if(epi==2){
      float d2 = (nrmA[m] + nrmB[n] - 2.f*c) * (1.f/512.f);
      fo0[(size_t)m*3072 + n] = g1*d2;              // D2P (cached; re-read 2x)
    } else {
      // bf16 split-K partial, regular cached store (L2 write-combining)
      u0[(size_t)slice*1024*3072 + (size_t)m*3072 + n] = f2bf(c);
    }
  }

  if(epi == 0){
    // reduce each (i,r) over the 16 lanes sharing row m, then one atomicAdd
    #pragma unroll
    for(int i=0;i<4;i++)
    #pragma unroll
    for(int r=0;r<4;r++){
      float s = nacc[i][r];
      #pragma unroll
      for(int mk=1; mk<16; mk<<=1) s += __shfl_xor(s, mk, 64);
      if(l15 == 0){
        int m = brow*128 + wr*64 + i*16 + l16*4 + r;
        if((m & 3) == 0) atomicAdd(&fa0[m>>2], s);
        else             atomicAdd(&fa1[(m>>2)*3 + (m&3) - 1], s);
      }
    }
  }
}

// ---- off-diagonal row sums of packed bf16 K (vectorized) -----------------
__global__ void k_rowsum(const u16* __restrict__ Kb, float* __restrict__ rs,
                         float* __restrict__ sq){
  int i = blockIdx.x, t = threadIdx.x;
  const u16* row = Kb + (size_t)i*3072;
  float s = 0.f;
  for(int j = t; j < 384; j += 256){
    short8v v = *reinterpret_cast<const short8v*>(row + j*8);
    #pragma unroll
    for(int k=0;k<8;k++) s += bf2f((u16)v[k]);
  }
  float r = blockSumBcast(s);
  if(t==0){
    float d = r - bf2f(row[i]);
    rs[i] = rsqrtf(d); sq[i] = sqrtf(d);
  }
}

// ---- CG init from D2P: e=exp(-(g0/g1)*d2p); Rb=bf16(sq*e); Pdb=bf16(e) ---
__global__ void k_rzinit(const float* __restrict__ D2P, const float* __restrict__ sq,
                         u16* __restrict__ Rb, u16* __restrict__ Pdb,
                         float* __restrict__ rz, const float* __restrict__ gamma){
  int p = blockIdx.x, t = threadIdx.x;
  float c1 = -gamma[0] / gamma[1];
  size_t base = (size_t)p*3072;
  float s = 0.f;
  #pragma unroll
  for(int j=0;j<6;j++){
    int g = 2*(t + j*256);
    f32x2 dv = *reinterpret_cast<const f32x2*>(&D2P[base+g]);
    float e0 = __expf(c1*dv[0]), e1 = __expf(c1*dv[1]);
    float r0 = sq[g]*e0, r1 = sq[g+1]*e1;
    *reinterpret_cast<unsigned*>(&Rb[base+g]) =
        (unsigned)f2bf(r0) | ((unsigned)f2bf(r1) << 16);
    *reinterpret_cast<unsigned*>(&Pdb[base+g]) =
        (unsigned)f2bf(e0) | ((unsigned)f2bf(e1) << 16);   // rs*(sq*e) == e
    s += r0*r0 + r1*r1;
  }
  float tot = blockSumBcast(s);
  if(t==0) rz[p] = tot;
}

// ---- fused CG step; SPb has 4 bf16 split-K partials; bf16 R/X state ------
// last: skip R/X/Pdb/rz updates, write out_pg (ch0,ch1) pairs directly
__global__ void __launch_bounds__(256) k_cgstep(
    const u16* __restrict__ SPb, u16* __restrict__ Pdb,
    u16* __restrict__ Rb, u16* __restrict__ Xb,
    float* __restrict__ rz,
    const float* __restrict__ rs, const float* __restrict__ sq,
    const float* __restrict__ D2P, float* __restrict__ outpg,
    int first, int last)
{
  const size_t SOFF = (size_t)1024*3072;
  int p = blockIdx.x, t = threadIdx.x;
  size_t base = (size_t)p*3072;
  float pd[12], ap[12];
  float papp = 0.f;
  #pragma unroll
  for(int j=0;j<6;j++){
    int g = 2*(t + j*256);
    unsigned pu = *reinterpret_cast<const unsigned*>(&Pdb[base+g]);
    unsigned s0 = *reinterpret_cast<const unsigned*>(&SPb[base+g]);
    unsigned s1 = *reinterpret_cast<const unsigned*>(&SPb[SOFF+base+g]);
    unsigned s2 = *reinterpret_cast<const unsigned*>(&SPb[2*SOFF+base+g]);
    unsigned s3 = *reinterpret_cast<const unsigned*>(&SPb[3*SOFF+base+g]);
    float pd0 = sq[g]   * bf2f((u16)(pu & 0xffffu));
    float pd1 = sq[g+1] * bf2f((u16)(pu >> 16));
    float sv0 = (bf2f((u16)(s0&0xffffu)) + bf2f((u16)(s1&0xffffu)))
              + (bf2f((u16)(s2&0xffffu)) + bf2f((u16)(s3&0xffffu)));
    float sv1 = (bf2f((u16)(s0>>16)) + bf2f((u16)(s1>>16)))
              + (bf2f((u16)(s2>>16)) + bf2f((u16)(s3>>16)));
    pd[2*j] = pd0; pd[2*j+1] = pd1;
    ap[2*j]   = pd0 - ALPHA_C*(rs[g]  *sv0);
    ap[2*j+1] = pd1 - ALPHA_C*(rs[g+1]*sv1);
    papp += pd0*ap[2*j] + pd1*ap[2*j+1];
  }
  float pap = blockSumBcast(papp);
  float rzv = rz[p];
  float a = rzv / fmaxf(pap, 1e-30f);

  if(!last){
    float rn[12];
    float rz2p = 0.f;
    #pragma unroll
    for(int j=0;j<6;j++){
      int g = 2*(t + j*256);
      unsigned ru = *reinterpret_cast<const unsigned*>(&Rb[base+g]);
      float rv0 = bf2f((u16)(ru & 0xffffu)) - a*ap[2*j];
      float rv1 = bf2f((u16)(ru >> 16))     - a*ap[2*j+1];
      rn[2*j]=rv0; rn[2*j+1]=rv1; rz2p += rv0*rv0 + rv1*rv1;
      float xv0, xv1;
      if(first){ xv0 = a*pd[2*j]; xv1 = a*pd[2*j+1]; }
      else{
        unsigned xu = *reinterpret_cast<const unsigned*>(&Xb[base+g]);
        xv0 = bf2f((u16)(xu & 0xffffu)) + a*pd[2*j];
        xv1 = bf2f((u16)(xu >> 16))     + a*pd[2*j+1];
      }
      *reinterpret_cast<unsigned*>(&Xb[base+g]) =
          (unsigned)f2bf(xv0) | ((unsigned)f2bf(xv1) << 16);
      *reinterpret_cast<unsigned*>(&Rb[base+g]) =
          (unsigned)f2bf(rv0) | ((unsigned)f2bf(rv1) << 16);
    }
    float rz2 = blockSumBcast(rz2p);
    float beta = rz2 / fmaxf(rzv, 1e-30f);
    #pragma unroll
    for(int j=0;j<6;j++){
      int g = 2*(t + j*256);
      float p0 = rn[2*j]   + beta*pd[2*j];
      float p1 = rn[2*j+1] + beta*pd[2*j+1];
      unsigned pk = (unsigned)f2bf(rs[g]*p0) | ((unsigned)f2bf(rs[g+1]*p1) << 16);
      *reinterpret_cast<unsigned*>(&Pdb[base+g]) = pk;
    }
    if(t==0) rz[p] = rz2;
  } else {
    // write interleaved (ch0, ch1) output pairs, coalesced 16B NT
    #pragma unroll
    for(int j=0;j<6;j++){
      int g = 2*(t + j*256);
      unsigned xu = *reinterpret_cast<const unsigned*>(&Xb[base+g]);
      f32x2 dv = *reinterpret_cast<const f32x2*>(&D2P[base+g]);
      f32x4 o;
      o[0] = (1.0f - ALPHA_C) * (bf2f((u16)(xu & 0xffffu)) + a*pd[2*j])   * rs[g];
      o[1] = dv[0];
      o[2] = (1.0f - ALPHA_C) * (bf2f((u16)(xu >> 16))     + a*pd[2*j+1]) * rs[g+1];
      o[3] = dv[1];
      __builtin_nontemporal_store(o, reinterpret_cast<f32x4*>(outpg + (base+g)*2));
    }
  }
}

// ---- final gg output: read Kb, emit (e, g1*d2) f32 pairs, coalesced ------
__global__ void k_ggout(const u16* __restrict__ Kb, float* __restrict__ gg,
                        const float* __restrict__ gamma, int n4){
  int i = blockIdx.x*256 + threadIdx.x;        // handles 4 elems
  if(i >= n4) return;
  float g0 = gamma[0], g1 = gamma[1];
  float ginv = -g1 / g0;                        // ch1 = g1*d2 = -g1/g0 * ln(e)
  u16x4 kv = *reinterpret_cast<const u16x4*>(Kb + (size_t)i*4);
  float e0 = bf2f(kv[0]), e1 = bf2f(kv[1]), e2 = bf2f(kv[2]), e3 = bf2f(kv[3]);
  f32x4 a, b;
  a[0] = e0; a[1] = ginv*__logf(e0);
  a[2] = e1; a[3] = ginv*__logf(e1);
  b[0] = e2; b[1] = ginv*__logf(e2);
  b[2] = e3; b[3] = ginv*__logf(e3);
  __builtin_nontemporal_store(a, reinterpret_cast<f32x4*>(gg + (size_t)i*8));
  __builtin_nontemporal_store(b, reinterpret_cast<f32x4*>(gg + (size_t)i*8 + 4));
}

extern "C" void kernel_launch(void* const* d_in, const int* in_sizes, int n_in,
                              void* d_out, int out_size, void* d_ws, size_t ws_size,
                              hipStream_t stream){
  const float* x     = (const float*)d_in[0];   // 4096x512
  const float* Wb    = (const float*)d_in[1];   // 512x512
  const float* gamma = (const float*)d_in[2];   // 2
  (void)in_sizes; (void)n_in; (void)out_size;

  float* out    = (float*)d_out;
  float* out_pg = out;                                  // [1024][3072][2] f32
  float* out_gg = out + (size_t)1024*3072*2;            // [3072][3072][2] f32
  u16*   SPb    = (u16*)out_gg;  // 4 bf16 split-K partials (25.2MB) in out_gg

  if(ws_size < WS_NEEDED){                              // diagnostic canary
    k_canary<<<1, 1, 0, stream>>>(out);
    return;
  }

  char* ws = (char*)d_ws;
  size_t off = 0;
  auto alloc = [&](size_t bytes)->char*{
    char* p = ws + off; off = (off + bytes + 255) & ~(size_t)255; return p;
  };
  // regionA: xbf(4.19MB)+wbt(0.5MB) early, reused as Rb(6.3MB) later
  char*  regionA = alloc((size_t)4096*512*2 + (size_t)512*512*2 + 512);
  u16*   xbf   = (u16*)regionA;
  u16*   wbt   = (u16*)(regionA + (size_t)4096*512*2);
  u16*   Rb    = (u16*)regionA;
  u16*   probe = (u16*)  alloc((size_t)1024*512*2);
  u16*   gal   = (u16*)  alloc((size_t)3072*512*2);
  u16*   Kb    = (u16*)  alloc((size_t)3072*3072*2);
  // atomic accumulators: np_(1024) | ng(3072) contiguous = 4096 f32
  float* np_   = (float*)alloc(1024*4);
  float* ng    = (float*)alloc(3072*4);
  float* rs    = (float*)alloc(3072*4);
  float* sq    = (float*)alloc(3072*4);
  float* rz    = (float*)alloc(1024*4);
  u16*   Xb    = (u16*)  alloc((size_t)1024*3072*2);
  float* D2P   = (float*)alloc((size_t)1024*3072*4);
  u16*   Pdb   = (u16*)  alloc((size_t)1024*3072*2);

  // 1. fused prep: x->bf16, Wb transpose->bf16, zero norm accumulators
  k_prep<<<1280, 256, 0, stream>>>(x, Wb, xbf, wbt, np_);

  // 2. f = x@Wb -> probe/gal bf16 rows + fused row norms (atomics)
  k_gemm<<<128, 256, 0, stream>>>(0, xbf, wbt, 512, 4, 128, 512,
      nullptr, nullptr, nullptr, probe, gal, nullptr, np_, ng, nullptr);

  // 3. MERGED gg+pg distances (XCD-swizzled): gg -> Kb | pg -> D2P
  k_gemm<<<768, 256, 0, stream>>>(4, gal, gal, 512, 24, 768, 512,
      ng, ng, gamma, Kb, probe, D2P, nullptr, nullptr, np_);

  // 4. off-diag row sums of Kb -> rs = d^{-1/2}, sq = d^{1/2}
  k_rowsum<<<3072, 256, 0, stream>>>(Kb, rs, sq);

  // 5. CG init from D2P (e recomputed; Rb = bf16(sq*e), Pdb = bf16(e), rz)
  k_rzinit<<<1024, 256, 0, stream>>>(D2P, sq, Rb, Pdb, rz, gamma);

  // 6. CG on (I - alpha*S); matvec split-K=4 -> bf16 cached partials
  //    last cgstep writes out_pg directly (both channels)
  for(int it = 0; it < NITER; ++it){
    k_gemm<<<768, 256, 0, stream>>>(3, Pdb, Kb, 3072, 24, 192, 768,
        nullptr, nullptr, nullptr, SPb, nullptr, nullptr, nullptr, nullptr, nullptr);
    k_cgstep<<<1024, 256, 0, stream>>>(SPb, Pdb, Rb, Xb, rz, rs, sq,
        D2P, out_pg, it==0 ? 1 : 0, it==NITER-1 ? 1 : 0);
  }

  // 7. regenerate gg output pairs from Kb (coalesced streaming writes)
  k_ggout<<<9216, 256, 0, stream>>>(Kb, out_gg, gamma, 3072*3072/4);
}

// Round 15
// 226.940 us; speedup vs baseline: 12.2429x; 1.0743x over previous
//
#include <hip/hip_runtime.h>

typedef unsigned short u16;
typedef short short8v __attribute__((ext_vector_type(8)));
typedef float f32x4 __attribute__((ext_vector_type(4)));
typedef float f32x2 __attribute__((ext_vector_type(2)));
typedef unsigned short u16x4 __attribute__((ext_vector_type(4)));

#define ALPHA_C 0.99f
#define NITER 2
#define NSLICE 6
#define WS_NEEDED 61000000UL

__device__ __forceinline__ u16 f2bf(float f){
  union { float f; unsigned u; } v; v.f = f;
  unsigned r = (v.u + 0x7FFFu + ((v.u >> 16) & 1u)) >> 16;
  return (u16)r;
}
__device__ __forceinline__ float bf2f(u16 u){
  union { unsigned u; float f; } v; v.u = ((unsigned)u) << 16;
  return v.f;
}

// async global->LDS, 16B per lane; lds dest must be wave-uniform base
__device__ __forceinline__ void gload16(const void* g, void* l){
  __builtin_amdgcn_global_load_lds(
    (const __attribute__((address_space(1))) unsigned*)g,
    (__attribute__((address_space(3))) unsigned*)l, 16, 0, 0);
}

// block=256: full sum broadcast to ALL threads
__device__ __forceinline__ float blockSumBcast(float v){
  #pragma unroll
  for(int off=32; off>0; off>>=1) v += __shfl_down(v, off, 64);
  __shared__ float sm[4];
  __shared__ float res;
  int w = threadIdx.x >> 6;
  if((threadIdx.x & 63)==0) sm[w] = v;
  __syncthreads();
  if(threadIdx.x==0) res = sm[0]+sm[1]+sm[2]+sm[3];
  __syncthreads();
  return res;
}

__global__ void k_canary(float* out){ out[0] = 12345.0f; }

// ---- fused prep: blocks [0,1024) = x f32->bf16 (8/thread);
//      blocks [1024,1280) = Wb transpose->bf16 + zero atomic accumulators --
__global__ void k_prep(const float* __restrict__ x, const float* __restrict__ Wb,
                       u16* __restrict__ xbf, u16* __restrict__ wbt,
                       float* __restrict__ zbuf){
  __shared__ float t[32][33];
  int bid = blockIdx.x;
  if(bid < 1024){
    int i = bid*256 + threadIdx.x;              // 262144 = 4096*512/8 exactly
    f32x4 a = *reinterpret_cast<const f32x4*>(x + (size_t)i*8);
    f32x4 b = *reinterpret_cast<const f32x4*>(x + (size_t)i*8 + 4);
    short8v o;
    o[0]=(short)f2bf(a[0]); o[1]=(short)f2bf(a[1]); o[2]=(short)f2bf(a[2]); o[3]=(short)f2bf(a[3]);
    o[4]=(short)f2bf(b[0]); o[5]=(short)f2bf(b[1]); o[6]=(short)f2bf(b[2]); o[7]=(short)f2bf(b[3]);
    *reinterpret_cast<short8v*>(xbf + (size_t)i*8) = o;
  } else {
    int b = bid - 1024;                          // 0..255
    int zi = b*256 + threadIdx.x;
    if(zi < 4096) zbuf[zi] = 0.f;
    int bx = b & 15, by = b >> 4;
    int tx = threadIdx.x & 31, ty = threadIdx.x >> 5;  // 32 x 8
    #pragma unroll
    for(int i=0;i<32;i+=8)
      t[ty+i][tx] = Wb[(by*32+ty+i)*512 + bx*32+tx];
    __syncthreads();
    #pragma unroll
    for(int i=0;i<32;i+=8)
      wbt[(bx*32+ty+i)*512 + by*32 + tx] = f2bf(t[tx][ty+i]);
  }
}

// ---- NT MFMA GEMM, 128x128 tile, BK=64, 4 waves, global_load_lds staging -
// epi 0: f scatter -> probe/gal bf16 rows (u0=probe,u1=gal) + ATOMIC norms
// epi 1: gg distances -> packed bf16 K (u0=Kb); upper-tri + LDS-mirror
// epi 2: pg distances -> D2P=g1*d2 (fo0)
// epi 3: split-K=6 matvec K@Pdb -> bf16 cached partials (u0)
// epi 4: MERGED tri-gg+pg: bid<300 = tri epi1; else epi2 (A=u1, nrmA=f1)
__global__ void __launch_bounds__(256) k_gemm(
    int epi,
    const u16* __restrict__ A, const u16* __restrict__ B,
    int kld, int nbn, int bps, int kspan,
    const float* __restrict__ nrmA, const float* __restrict__ nrmB,
    const float* __restrict__ gamma,
    u16* __restrict__ u0, u16* __restrict__ u1,
    float* __restrict__ fo0,
    float* __restrict__ fa0, float* __restrict__ fa1,
    const float* __restrict__ f1)
{
  int bid = blockIdx.x;
  int slice, brow, bcol;
  bool mir = false;
  if(epi==3){
    int L = (bid & 7)*144 + (bid >> 3);   // 1152 blocks, bijective (1152%8==0)
    slice = L / 192;
    int l = L - slice*192;
    bcol = l >> 3;                         // 24 bcols x 8 brows per slice
    brow = l & 7;
  } else if(epi==4){
    slice = 0;
    if(bid < 300){                         // upper-triangle gg tile
      epi = 1;
      int ll = bid, rr = 0;
      for(; rr < 24; ++rr){ int c = 24 - rr; if(ll < c) break; ll -= c; }
      brow = rr; bcol = rr + ll;
      mir = (brow != bcol);
    } else {
      epi = 2; int l = bid - 300; brow = l / 24; bcol = l % 24;
      A = u1; nrmA = f1;
    }
  } else {
    slice = bid / bps; int rem = bid % bps;
    brow = rem / nbn; bcol = rem % nbn;
  }
  int t = threadIdx.x;
  int w = t >> 6, l = t & 63;
  int wr = w >> 1, wc = w & 1;
  const int l15 = l & 15, l16 = l >> 4;
  int k0 = slice * kspan;

  // 33 KB shared: A|B staging (first 32 KB) during K-loop; after the final
  // barrier, reused as the mirror tile T with INJECTIVE stride 129 (>=128!)
  __shared__ __align__(16) u16 SH[16512];
  u16* AB = SH;            // [2][8192] staging
  u16* T  = SH;            // stride-129 tile view (epi1 mirror only)

  // staging role: waves 0,1 -> A halves; waves 2,3 -> B halves
  const u16* src = (w < 2) ? A + (size_t)brow*128*kld
                           : B + (size_t)bcol*128*kld;
  int half = w >> 1;            // 0 = A, 1 = B
  int wq   = (w & 1) * 8;       // chunk-call base within half

  f32x4 acc[4][4] = {};

  for(int kk = 0; kk < kspan; kk += 64){
    int kt = k0 + kk;
    #pragma unroll
    for(int q=0;q<8;q++){
      int cb  = (wq + q)*64;             // chunk base within half [0,1024)
      int idx = cb + l;                  // this lane's 16B chunk
      int row = idx >> 3, c8 = idx & 7;
      gload16(src + (size_t)row*kld + kt + c8*8,   // per-lane global src
              &AB[half*8192 + cb*8]);              // wave-uniform LDS dest
    }
    __syncthreads();                     // drains vmcnt before barrier
    #pragma unroll
    for(int ks=0; ks<2; ++ks){
      short8v af[4], bfr[4];
      int ko = ks*32 + l16*8;
      #pragma unroll
      for(int i=0;i<4;i++){
        af[i]  = *reinterpret_cast<const short8v*>(&AB[(wr*64+i*16+l15)*64 + ko]);
        bfr[i] = *reinterpret_cast<const short8v*>(&AB[8192 + (wc*64+i*16+l15)*64 + ko]);
      }
      #pragma unroll
      for(int i=0;i<4;i++)
        #pragma unroll
        for(int j=0;j<4;j++)
          acc[i][j] = __builtin_amdgcn_mfma_f32_16x16x32_bf16(af[i], bfr[j], acc[i][j], 0,0,0);
    }
    __syncthreads();
  }

  float g0 = 0.f, g1 = 0.f;
  if(epi==1 || epi==2){ g0 = gamma[0]; g1 = gamma[1]; }

  float nacc[4][4] = {};   // per-(i,r) norm accumulator (epi 0 only)

  #pragma unroll
  for(int i=0;i<4;i++)
  #pragma unroll
  for(int j=0;j<4;j++)
  #pragma unroll
  for(int r=0;r<4;r++){
    int m = brow*128 + wr*64 + i*16 + l16*4 + r;   // C row (A index)
    int n = bcol*128 + wc*64 + j*16 + l15;         // C col (B index)
    float c = acc[i][j][r];
    if(epi==0){
      u16 b = f2bf(c);
      if((m & 3) == 0) u0[(size_t)(m>>2)*512 + n] = b;
      else             u1[(size_t)((m>>2)*3 + (m&3) - 1)*512 + n] = b;
      float v = bf2f(b);
      nacc[i][r] += v*v;
    } else if(epi==1){
      float d2 = (nrmA[m] + nrmB[n] - 2.f*c) * (1.f/512.f);
      float e  = __expf(-g0*d2);
      u16 b = f2bf(e);
      u0[(size_t)m*3072 + n] = b;                  // packed K (upper tile)
      if(mir){
        int lm = wr*64 + i*16 + l16*4 + r;
        int ln = wc*64 + j*16 + l15;
        T[lm*129 + ln] = b;                        // stage for mirror (inj.)
      }
    } else if(epi==2){
      float d2 = (nrmA[m] + nrmB[n] - 2.f*c) * (1.f/512.f);
      fo0[(size_t)m*3072 + n] = g1*d2;              // D2P (cached; re-read 2x)
    } else {
      // bf16 split-K partial, regular cached store (L2 write-combining)
      u0[(size_t)slice*1024*3072 + (size_t)m*3072 + n] = f2bf(c);
    }
  }

  if(epi == 0){
    // reduce each (i,r) over the 16 lanes sharing row m, then one atomicAdd
    #pragma unroll
    for(int i=0;i<4;i++)
    #pragma unroll
    for(int r=0;r<4;r++){
      float s = nacc[i][r];
      #pragma unroll
      for(int mk=1; mk<16; mk<<=1) s += __shfl_xor(s, mk, 64);
      if(l15 == 0){
        int m = brow*128 + wr*64 + i*16 + l16*4 + r;
        if((m & 3) == 0) atomicAdd(&fa0[m>>2], s);
        else             atomicAdd(&fa1[(m>>2)*3 + (m&3) - 1], s);
      }
    }
  } else if(epi == 1 && mir){
    // mirror tile: Kb[n][m] = T[lm=cc][ln=r2], coalesced u32 row writes
    __syncthreads();
    int r2 = t >> 1, c0 = (t & 1)*64;
    size_t orow = (size_t)(bcol*128 + r2)*3072 + brow*128;
    #pragma unroll
    for(int c=0;c<64;c+=2){
      int cc = c0 + c;
      unsigned pk = (unsigned)T[cc*129 + r2] | ((unsigned)T[(cc+1)*129 + r2] << 16);
      *reinterpret_cast<unsigned*>(&u0[orow + cc]) = pk;
    }
  }
}

// ---- off-diagonal row sums of packed bf16 K (vectorized) -----------------
__global__ void k_rowsum(const u16* __restrict__ Kb, float* __restrict__ rs,
                         float* __restrict__ sq){
  int i = blockIdx.x, t = threadIdx.x;
  const u16* row = Kb + (size_t)i*3072;
  float s = 0.f;
  for(int j = t; j < 384; j += 256){
    short8v v = *reinterpret_cast<const short8v*>(row + j*8);
    #pragma unroll
    for(int k=0;k<8;k++) s += bf2f((u16)v[k]);
  }
  float r = blockSumBcast(s);
  if(t==0){
    float d = r - bf2f(row[i]);
    rs[i] = rsqrtf(d); sq[i] = sqrtf(d);
  }
}

// ---- CG init from D2P: e=exp(-(g0/g1)*d2p); Rb=bf16(sq*e); Pdb=bf16(e) ---
__global__ void k_rzinit(const float* __restrict__ D2P, const float* __restrict__ sq,
                         u16* __restrict__ Rb, u16* __restrict__ Pdb,
                         float* __restrict__ rz, const float* __restrict__ gamma){
  int p = blockIdx.x, t = threadIdx.x;
  float c1 = -gamma[0] / gamma[1];
  size_t base = (size_t)p*3072;
  float s = 0.f;
  #pragma unroll
  for(int j=0;j<6;j++){
    int g = 2*(t + j*256);
    f32x2 dv = *reinterpret_cast<const f32x2*>(&D2P[base+g]);
    float e0 = __expf(c1*dv[0]), e1 = __expf(c1*dv[1]);
    float r0 = sq[g]*e0, r1 = sq[g+1]*e1;
    *reinterpret_cast<unsigned*>(&Rb[base+g]) =
        (unsigned)f2bf(r0) | ((unsigned)f2bf(r1) << 16);
    *reinterpret_cast<unsigned*>(&Pdb[base+g]) =
        (unsigned)f2bf(e0) | ((unsigned)f2bf(e1) << 16);   // rs*(sq*e) == e
    s += r0*r0 + r1*r1;
  }
  float tot = blockSumBcast(s);
  if(t==0) rz[p] = tot;
}

// ---- fused CG step; SPb has NSLICE bf16 split-K partials; bf16 R/X state -
// last: skip R/X/Pdb/rz updates, write out_pg (ch0,ch1) pairs directly
__global__ void __launch_bounds__(256) k_cgstep(
    const u16* __restrict__ SPb, u16* __restrict__ Pdb,
    u16* __restrict__ Rb, u16* __restrict__ Xb,
    float* __restrict__ rz,
    const float* __restrict__ rs, const float* __restrict__ sq,
    const float* __restrict__ D2P, float* __restrict__ outpg,
    int first, int last)
{
  const size_t SOFF = (size_t)1024*3072;
  int p = blockIdx.x, t = threadIdx.x;
  size_t base = (size_t)p*3072;
  float pd[12], ap[12];
  float papp = 0.f;
  #pragma unroll
  for(int j=0;j<6;j++){
    int g = 2*(t + j*256);
    unsigned pu = *reinterpret_cast<const unsigned*>(&Pdb[base+g]);
    float sv0 = 0.f, sv1 = 0.f;
    #pragma unroll
    for(int s=0;s<NSLICE;s++){
      unsigned sp = *reinterpret_cast<const unsigned*>(&SPb[s*SOFF+base+g]);
      sv0 += bf2f((u16)(sp & 0xffffu));
      sv1 += bf2f((u16)(sp >> 16));
    }
    float pd0 = sq[g]   * bf2f((u16)(pu & 0xffffu));
    float pd1 = sq[g+1] * bf2f((u16)(pu >> 16));
    pd[2*j] = pd0; pd[2*j+1] = pd1;
    ap[2*j]   = pd0 - ALPHA_C*(rs[g]  *sv0);
    ap[2*j+1] = pd1 - ALPHA_C*(rs[g+1]*sv1);
    papp += pd0*ap[2*j] + pd1*ap[2*j+1];
  }
  float pap = blockSumBcast(papp);
  float rzv = rz[p];
  float a = rzv / fmaxf(pap, 1e-30f);

  if(!last){
    float rn[12];
    float rz2p = 0.f;
    #pragma unroll
    for(int j=0;j<6;j++){
      int g = 2*(t + j*256);
      unsigned ru = *reinterpret_cast<const unsigned*>(&Rb[base+g]);
      float rv0 = bf2f((u16)(ru & 0xffffu)) - a*ap[2*j];
      float rv1 = bf2f((u16)(ru >> 16))     - a*ap[2*j+1];
      rn[2*j]=rv0; rn[2*j+1]=rv1; rz2p += rv0*rv0 + rv1*rv1;
      float xv0, xv1;
      if(first){ xv0 = a*pd[2*j]; xv1 = a*pd[2*j+1]; }
      else{
        unsigned xu = *reinterpret_cast<const unsigned*>(&Xb[base+g]);
        xv0 = bf2f((u16)(xu & 0xffffu)) + a*pd[2*j];
        xv1 = bf2f((u16)(xu >> 16))     + a*pd[2*j+1];
      }
      *reinterpret_cast<unsigned*>(&Xb[base+g]) =
          (unsigned)f2bf(xv0) | ((unsigned)f2bf(xv1) << 16);
      *reinterpret_cast<unsigned*>(&Rb[base+g]) =
          (unsigned)f2bf(rv0) | ((unsigned)f2bf(rv1) << 16);
    }
    float rz2 = blockSumBcast(rz2p);
    float beta = rz2 / fmaxf(rzv, 1e-30f);
    #pragma unroll
    for(int j=0;j<6;j++){
      int g = 2*(t + j*256);
      float p0 = rn[2*j]   + beta*pd[2*j];
      float p1 = rn[2*j+1] + beta*pd[2*j+1];
      unsigned pk = (unsigned)f2bf(rs[g]*p0) | ((unsigned)f2bf(rs[g+1]*p1) << 16);
      *reinterpret_cast<unsigned*>(&Pdb[base+g]) = pk;
    }
    if(t==0) rz[p] = rz2;
  } else {
    // write interleaved (ch0, ch1) output pairs, coalesced 16B NT
    #pragma unroll
    for(int j=0;j<6;j++){
      int g = 2*(t + j*256);
      unsigned xu = *reinterpret_cast<const unsigned*>(&Xb[base+g]);
      f32x2 dv = *reinterpret_cast<const f32x2*>(&D2P[base+g]);
      f32x4 o;
      o[0] = (1.0f - ALPHA_C) * (bf2f((u16)(xu & 0xffffu)) + a*pd[2*j])   * rs[g];
      o[1] = dv[0];
      o[2] = (1.0f - ALPHA_C) * (bf2f((u16)(xu >> 16))     + a*pd[2*j+1]) * rs[g+1];
      o[3] = dv[1];
      __builtin_nontemporal_store(o, reinterpret_cast<f32x4*>(outpg + (base+g)*2));
    }
  }
}

// ---- final gg output: read Kb, emit (e, g1*d2) f32 pairs, coalesced ------
__global__ void k_ggout(const u16* __restrict__ Kb, float* __restrict__ gg,
                        const float* __restrict__ gamma, int n4){
  int i = blockIdx.x*256 + threadIdx.x;        // handles 4 elems
  if(i >= n4) return;
  float g0 = gamma[0], g1 = gamma[1];
  float ginv = -g1 / g0;                        // ch1 = g1*d2 = -g1/g0 * ln(e)
  u16x4 kv = *reinterpret_cast<const u16x4*>(Kb + (size_t)i*4);
  float e0 = bf2f(kv[0]), e1 = bf2f(kv[1]), e2 = bf2f(kv[2]), e3 = bf2f(kv[3]);
  f32x4 a, b;
  a[0] = e0; a[1] = ginv*__logf(e0);
  a[2] = e1; a[3] = ginv*__logf(e1);
  b[0] = e2; b[1] = ginv*__logf(e2);
  b[2] = e3; b[3] = ginv*__logf(e3);
  __builtin_nontemporal_store(a, reinterpret_cast<f32x4*>(gg + (size_t)i*8));
  __builtin_nontemporal_store(b, reinterpret_cast<f32x4*>(gg + (size_t)i*8 + 4));
}

extern "C" void kernel_launch(void* const* d_in, const int* in_sizes, int n_in,
                              void* d_out, int out_size, void* d_ws, size_t ws_size,
                              hipStream_t stream){
  const float* x     = (const float*)d_in[0];   // 4096x512
  const float* Wb    = (const float*)d_in[1];   // 512x512
  const float* gamma = (const float*)d_in[2];   // 2
  (void)in_sizes; (void)n_in; (void)out_size;

  float* out    = (float*)d_out;
  float* out_pg = out;                                  // [1024][3072][2] f32
  float* out_gg = out + (size_t)1024*3072*2;            // [3072][3072][2] f32
  u16*   SPb    = (u16*)out_gg;  // 6 bf16 split-K partials (37.8MB) in out_gg

  if(ws_size < WS_NEEDED){                              // diagnostic canary
    k_canary<<<1, 1, 0, stream>>>(out);
    return;
  }

  char* ws = (char*)d_ws;
  size_t off = 0;
  auto alloc = [&](size_t bytes)->char*{
    char* p = ws + off; off = (off + bytes + 255) & ~(size_t)255; return p;
  };
  // regionA: xbf(4.19MB)+wbt(0.5MB) early, reused as Rb(6.3MB) later
  char*  regionA = alloc((size_t)4096*512*2 + (size_t)512*512*2 + 512);
  u16*   xbf   = (u16*)regionA;
  u16*   wbt   = (u16*)(regionA + (size_t)4096*512*2);
  u16*   Rb    = (u16*)regionA;
  u16*   probe = (u16*)  alloc((size_t)1024*512*2);
  u16*   gal   = (u16*)  alloc((size_t)3072*512*2);
  u16*   Kb    = (u16*)  alloc((size_t)3072*3072*2);
  // atomic accumulators: np_(1024) | ng(3072) contiguous = 4096 f32
  float* np_   = (float*)alloc(1024*4);
  float* ng    = (float*)alloc(3072*4);
  float* rs    = (float*)alloc(3072*4);
  float* sq    = (float*)alloc(3072*4);
  float* rz    = (float*)alloc(1024*4);
  u16*   Xb    = (u16*)  alloc((size_t)1024*3072*2);
  float* D2P   = (float*)alloc((size_t)1024*3072*4);
  u16*   Pdb   = (u16*)  alloc((size_t)1024*3072*2);

  // 1. fused prep: x->bf16, Wb transpose->bf16, zero norm accumulators
  k_prep<<<1280, 256, 0, stream>>>(x, Wb, xbf, wbt, np_);

  // 2. f = x@Wb -> probe/gal bf16 rows + fused row norms (atomics)
  k_gemm<<<128, 256, 0, stream>>>(0, xbf, wbt, 512, 4, 128, 512,
      nullptr, nullptr, nullptr, probe, gal, nullptr, np_, ng, nullptr);

  // 3. MERGED distances: gg upper-triangle (300 blk, LDS-mirror) -> Kb |
  //    pg (192 blk) -> D2P
  k_gemm<<<492, 256, 0, stream>>>(4, gal, gal, 512, 24, 492, 512,
      ng, ng, gamma, Kb, probe, D2P, nullptr, nullptr, np_);

  // 4. off-diag row sums of Kb -> rs = d^{-1/2}, sq = d^{1/2}
  k_rowsum<<<3072, 256, 0, stream>>>(Kb, rs, sq);

  // 5. CG init from D2P (e recomputed; Rb = bf16(sq*e), Pdb = bf16(e), rz)
  k_rzinit<<<1024, 256, 0, stream>>>(D2P, sq, Rb, Pdb, rz, gamma);

  // 6. CG on (I - alpha*S); matvec split-K=6 -> bf16 cached partials
  //    last cgstep writes out_pg directly (both channels)
  for(int it = 0; it < NITER; ++it){
    k_gemm<<<1152, 256, 0, stream>>>(3, Pdb, Kb, 3072, 24, 192, 512,
        nullptr, nullptr, nullptr, SPb, nullptr, nullptr, nullptr, nullptr, nullptr);
    k_cgstep<<<1024, 256, 0, stream>>>(SPb, Pdb, Rb, Xb, rz, rs, sq,
        D2P, out_pg, it==0 ? 1 : 0, it==NITER-1 ? 1 : 0);
  }

  // 7. regenerate gg output pairs from Kb (coalesced streaming writes)
  k_ggout<<<9216, 256, 0, stream>>>(Kb, out_gg, gamma, 3072*3072/4);
}

// Round 16
// 214.991 us; speedup vs baseline: 12.9233x; 1.0556x over previous
//
#include <hip/hip_runtime.h>

typedef unsigned short u16;
typedef short short8v __attribute__((ext_vector_type(8)));
typedef float f32x4 __attribute__((ext_vector_type(4)));
typedef float f32x2 __attribute__((ext_vector_type(2)));
typedef unsigned short u16x4 __attribute__((ext_vector_type(4)));

#define ALPHA_C 0.99f
#define NITER 2
#define NSLICE 4
#define WS_NEEDED 61000000UL

__device__ __forceinline__ u16 f2bf(float f){
  union { float f; unsigned u; } v; v.f = f;
  unsigned r = (v.u + 0x7FFFu + ((v.u >> 16) & 1u)) >> 16;
  return (u16)r;
}
__device__ __forceinline__ float bf2f(u16 u){
  union { unsigned u; float f; } v; v.u = ((unsigned)u) << 16;
  return v.f;
}

// async global->LDS, 16B per lane; lds dest must be wave-uniform base
__device__ __forceinline__ void gload16(const void* g, void* l){
  __builtin_amdgcn_global_load_lds(
    (const __attribute__((address_space(1))) unsigned*)g,
    (__attribute__((address_space(3))) unsigned*)l, 16, 0, 0);
}

// block=256: full sum broadcast to ALL threads
__device__ __forceinline__ float blockSumBcast(float v){
  #pragma unroll
  for(int off=32; off>0; off>>=1) v += __shfl_down(v, off, 64);
  __shared__ float sm[4];
  __shared__ float res;
  int w = threadIdx.x >> 6;
  if((threadIdx.x & 63)==0) sm[w] = v;
  __syncthreads();
  if(threadIdx.x==0) res = sm[0]+sm[1]+sm[2]+sm[3];
  __syncthreads();
  return res;
}

__global__ void k_canary(float* out){ out[0] = 12345.0f; }

// ---- fused prep: blocks [0,1024) = x f32->bf16 (8/thread);
//      blocks [1024,1280) = Wb transpose->bf16 + zero atomic accumulators --
__global__ void k_prep(const float* __restrict__ x, const float* __restrict__ Wb,
                       u16* __restrict__ xbf, u16* __restrict__ wbt,
                       float* __restrict__ zbuf){
  __shared__ float t[32][33];
  int bid = blockIdx.x;
  if(bid < 1024){
    int i = bid*256 + threadIdx.x;              // 262144 = 4096*512/8 exactly
    f32x4 a = *reinterpret_cast<const f32x4*>(x + (size_t)i*8);
    f32x4 b = *reinterpret_cast<const f32x4*>(x + (size_t)i*8 + 4);
    short8v o;
    o[0]=(short)f2bf(a[0]); o[1]=(short)f2bf(a[1]); o[2]=(short)f2bf(a[2]); o[3]=(short)f2bf(a[3]);
    o[4]=(short)f2bf(b[0]); o[5]=(short)f2bf(b[1]); o[6]=(short)f2bf(b[2]); o[7]=(short)f2bf(b[3]);
    *reinterpret_cast<short8v*>(xbf + (size_t)i*8) = o;
  } else {
    int b = bid - 1024;                          // 0..255
    int zi = b*256 + threadIdx.x;
    if(zi < 4096) zbuf[zi] = 0.f;
    int bx = b & 15, by = b >> 4;
    int tx = threadIdx.x & 31, ty = threadIdx.x >> 5;  // 32 x 8
    #pragma unroll
    for(int i=0;i<32;i+=8)
      t[ty+i][tx] = Wb[(by*32+ty+i)*512 + bx*32+tx];
    __syncthreads();
    #pragma unroll
    for(int i=0;i<32;i+=8)
      wbt[(bx*32+ty+i)*512 + by*32 + tx] = f2bf(t[tx][ty+i]);
  }
}

// ---- NT MFMA GEMM, 128x128 tile, BK=64, 4 waves, global_load_lds staging -
// epi 0: f scatter -> probe/gal bf16 rows (u0=probe,u1=gal) + ATOMIC norms
// epi 1: gg distances -> packed bf16 K (u0=Kb); upper-tri + LDS-mirror
// epi 2: pg distances -> D2P=g1*d2 (fo0)
// epi 3: split-K=4 matvec K@Pdb -> bf16 cached partials (u0)
// epi 4: MERGED tri-gg+pg: bid<300 = tri epi1; else epi2 (A=u1, nrmA=f1)
__global__ void __launch_bounds__(256) k_gemm(
    int epi,
    const u16* __restrict__ A, const u16* __restrict__ B,
    int kld, int nbn, int bps, int kspan,
    const float* __restrict__ nrmA, const float* __restrict__ nrmB,
    const float* __restrict__ gamma,
    u16* __restrict__ u0, u16* __restrict__ u1,
    float* __restrict__ fo0,
    float* __restrict__ fa0, float* __restrict__ fa1,
    const float* __restrict__ f1)
{
  int bid = blockIdx.x;
  int slice, brow, bcol;
  bool mir = false;
  if(epi==3){
    int L = (bid & 7)*96 + (bid >> 3);    // 768 blocks, bijective (768%8==0)
    slice = L / 192;
    int l = L - slice*192;
    bcol = l >> 3;                         // 12 bcols x 8 brows per XCD chunk
    brow = l & 7;                          // -> 3.9 MB panel set < 4 MB L2
  } else if(epi==4){
    slice = 0;
    if(bid < 300){                         // upper-triangle gg tile
      epi = 1;
      int ll = bid, rr = 0;
      for(; rr < 24; ++rr){ int c = 24 - rr; if(ll < c) break; ll -= c; }
      brow = rr; bcol = rr + ll;
      mir = (brow != bcol);
    } else {
      epi = 2; int l = bid - 300; brow = l / 24; bcol = l % 24;
      A = u1; nrmA = f1;
    }
  } else {
    slice = bid / bps; int rem = bid % bps;
    brow = rem / nbn; bcol = rem % nbn;
  }
  int t = threadIdx.x;
  int w = t >> 6, l = t & 63;
  int wr = w >> 1, wc = w & 1;
  const int l15 = l & 15, l16 = l >> 4;
  int k0 = slice * kspan;

  // 33 KB shared: A|B staging (first 32 KB) during K-loop; after the final
  // barrier, reused as the mirror tile T with INJECTIVE stride 129 (>=128!)
  __shared__ __align__(16) u16 SH[16512];
  u16* AB = SH;            // [2][8192] staging
  u16* T  = SH;            // stride-129 tile view (epi1 mirror only)

  // staging role: waves 0,1 -> A halves; waves 2,3 -> B halves
  const u16* src = (w < 2) ? A + (size_t)brow*128*kld
                           : B + (size_t)bcol*128*kld;
  int half = w >> 1;            // 0 = A, 1 = B
  int wq   = (w & 1) * 8;       // chunk-call base within half

  f32x4 acc[4][4] = {};

  for(int kk = 0; kk < kspan; kk += 64){
    int kt = k0 + kk;
    #pragma unroll
    for(int q=0;q<8;q++){
      int cb  = (wq + q)*64;             // chunk base within half [0,1024)
      int idx = cb + l;                  // this lane's 16B chunk
      int row = idx >> 3, c8 = idx & 7;
      gload16(src + (size_t)row*kld + kt + c8*8,   // per-lane global src
              &AB[half*8192 + cb*8]);              // wave-uniform LDS dest
    }
    __syncthreads();                     // drains vmcnt before barrier
    #pragma unroll
    for(int ks=0; ks<2; ++ks){
      short8v af[4], bfr[4];
      int ko = ks*32 + l16*8;
      #pragma unroll
      for(int i=0;i<4;i++){
        af[i]  = *reinterpret_cast<const short8v*>(&AB[(wr*64+i*16+l15)*64 + ko]);
        bfr[i] = *reinterpret_cast<const short8v*>(&AB[8192 + (wc*64+i*16+l15)*64 + ko]);
      }
      #pragma unroll
      for(int i=0;i<4;i++)
        #pragma unroll
        for(int j=0;j<4;j++)
          acc[i][j] = __builtin_amdgcn_mfma_f32_16x16x32_bf16(af[i], bfr[j], acc[i][j], 0,0,0);
    }
    __syncthreads();
  }

  float g0 = 0.f, g1 = 0.f;
  if(epi==1 || epi==2){ g0 = gamma[0]; g1 = gamma[1]; }

  float nacc[4][4] = {};   // per-(i,r) norm accumulator (epi 0 only)

  #pragma unroll
  for(int i=0;i<4;i++)
  #pragma unroll
  for(int j=0;j<4;j++)
  #pragma unroll
  for(int r=0;r<4;r++){
    int m = brow*128 + wr*64 + i*16 + l16*4 + r;   // C row (A index)
    int n = bcol*128 + wc*64 + j*16 + l15;         // C col (B index)
    float c = acc[i][j][r];
    if(epi==0){
      u16 b = f2bf(c);
      if((m & 3) == 0) u0[(size_t)(m>>2)*512 + n] = b;
      else             u1[(size_t)((m>>2)*3 + (m&3) - 1)*512 + n] = b;
      float v = bf2f(b);
      nacc[i][r] += v*v;
    } else if(epi==1){
      float d2 = (nrmA[m] + nrmB[n] - 2.f*c) * (1.f/512.f);
      float e  = __expf(-g0*d2);
      u16 b = f2bf(e);
      u0[(size_t)m*3072 + n] = b;                  // packed K (upper tile)
      if(mir){
        int lm = wr*64 + i*16 + l16*4 + r;
        int ln = wc*64 + j*16 + l15;
        T[lm*129 + ln] = b;                        // stage for mirror (inj.)
      }
    } else if(epi==2){
      float d2 = (nrmA[m] + nrmB[n] - 2.f*c) * (1.f/512.f);
      fo0[(size_t)m*3072 + n] = g1*d2;              // D2P (cached; re-read 2x)
    } else {
      // bf16 split-K partial, regular cached store (L2 write-combining)
      u0[(size_t)slice*1024*3072 + (size_t)m*3072 + n] = f2bf(c);
    }
  }

  if(epi == 0){
    // reduce each (i,r) over the 16 lanes sharing row m, then one atomicAdd
    #pragma unroll
    for(int i=0;i<4;i++)
    #pragma unroll
    for(int r=0;r<4;r++){
      float s = nacc[i][r];
      #pragma unroll
      for(int mk=1; mk<16; mk<<=1) s += __shfl_xor(s, mk, 64);
      if(l15 == 0){
        int m = brow*128 + wr*64 + i*16 + l16*4 + r;
        if((m & 3) == 0) atomicAdd(&fa0[m>>2], s);
        else             atomicAdd(&fa1[(m>>2)*3 + (m&3) - 1], s);
      }
    }
  } else if(epi == 1 && mir){
    // mirror tile: Kb[n][m] = T[lm=cc][ln=r2], coalesced u32 row writes
    __syncthreads();
    int r2 = t >> 1, c0 = (t & 1)*64;
    size_t orow = (size_t)(bcol*128 + r2)*3072 + brow*128;
    #pragma unroll
    for(int c=0;c<64;c+=2){
      int cc = c0 + c;
      unsigned pk = (unsigned)T[cc*129 + r2] | ((unsigned)T[(cc+1)*129 + r2] << 16);
      *reinterpret_cast<unsigned*>(&u0[orow + cc]) = pk;
    }
  }
}

// ---- off-diagonal row sums of packed bf16 K (vectorized) -----------------
__global__ void k_rowsum(const u16* __restrict__ Kb, float* __restrict__ rs,
                         float* __restrict__ sq){
  int i = blockIdx.x, t = threadIdx.x;
  const u16* row = Kb + (size_t)i*3072;
  float s = 0.f;
  for(int j = t; j < 384; j += 256){
    short8v v = *reinterpret_cast<const short8v*>(row + j*8);
    #pragma unroll
    for(int k=0;k<8;k++) s += bf2f((u16)v[k]);
  }
  float r = blockSumBcast(s);
  if(t==0){
    float d = r - bf2f(row[i]);
    rs[i] = rsqrtf(d); sq[i] = sqrtf(d);
  }
}

// ---- CG init from D2P: e=exp(-(g0/g1)*d2p); Rb=bf16(sq*e); Pdb=bf16(e) ---
__global__ void k_rzinit(const float* __restrict__ D2P, const float* __restrict__ sq,
                         u16* __restrict__ Rb, u16* __restrict__ Pdb,
                         float* __restrict__ rz, const float* __restrict__ gamma){
  int p = blockIdx.x, t = threadIdx.x;
  float c1 = -gamma[0] / gamma[1];
  size_t base = (size_t)p*3072;
  float s = 0.f;
  #pragma unroll
  for(int j=0;j<6;j++){
    int g = 2*(t + j*256);
    f32x2 dv = *reinterpret_cast<const f32x2*>(&D2P[base+g]);
    float e0 = __expf(c1*dv[0]), e1 = __expf(c1*dv[1]);
    float r0 = sq[g]*e0, r1 = sq[g+1]*e1;
    *reinterpret_cast<unsigned*>(&Rb[base+g]) =
        (unsigned)f2bf(r0) | ((unsigned)f2bf(r1) << 16);
    *reinterpret_cast<unsigned*>(&Pdb[base+g]) =
        (unsigned)f2bf(e0) | ((unsigned)f2bf(e1) << 16);   // rs*(sq*e) == e
    s += r0*r0 + r1*r1;
  }
  float tot = blockSumBcast(s);
  if(t==0) rz[p] = tot;
}

// ---- fused CG step; SPb has NSLICE bf16 split-K partials; bf16 R/X state -
// last: skip R/X/Pdb/rz updates, write out_pg (ch0,ch1) pairs directly
__global__ void __launch_bounds__(256) k_cgstep(
    const u16* __restrict__ SPb, u16* __restrict__ Pdb,
    u16* __restrict__ Rb, u16* __restrict__ Xb,
    float* __restrict__ rz,
    const float* __restrict__ rs, const float* __restrict__ sq,
    const float* __restrict__ D2P, float* __restrict__ outpg,
    int first, int last)
{
  const size_t SOFF = (size_t)1024*3072;
  int p = blockIdx.x, t = threadIdx.x;
  size_t base = (size_t)p*3072;
  float pd[12], ap[12];
  float papp = 0.f;
  #pragma unroll
  for(int j=0;j<6;j++){
    int g = 2*(t + j*256);
    unsigned pu = *reinterpret_cast<const unsigned*>(&Pdb[base+g]);
    float sv0 = 0.f, sv1 = 0.f;
    #pragma unroll
    for(int s=0;s<NSLICE;s++){
      unsigned sp = *reinterpret_cast<const unsigned*>(&SPb[s*SOFF+base+g]);
      sv0 += bf2f((u16)(sp & 0xffffu));
      sv1 += bf2f((u16)(sp >> 16));
    }
    float pd0 = sq[g]   * bf2f((u16)(pu & 0xffffu));
    float pd1 = sq[g+1] * bf2f((u16)(pu >> 16));
    pd[2*j] = pd0; pd[2*j+1] = pd1;
    ap[2*j]   = pd0 - ALPHA_C*(rs[g]  *sv0);
    ap[2*j+1] = pd1 - ALPHA_C*(rs[g+1]*sv1);
    papp += pd0*ap[2*j] + pd1*ap[2*j+1];
  }
  float pap = blockSumBcast(papp);
  float rzv = rz[p];
  float a = rzv / fmaxf(pap, 1e-30f);

  if(!last){
    float rn[12];
    float rz2p = 0.f;
    #pragma unroll
    for(int j=0;j<6;j++){
      int g = 2*(t + j*256);
      unsigned ru = *reinterpret_cast<const unsigned*>(&Rb[base+g]);
      float rv0 = bf2f((u16)(ru & 0xffffu)) - a*ap[2*j];
      float rv1 = bf2f((u16)(ru >> 16))     - a*ap[2*j+1];
      rn[2*j]=rv0; rn[2*j+1]=rv1; rz2p += rv0*rv0 + rv1*rv1;
      float xv0, xv1;
      if(first){ xv0 = a*pd[2*j]; xv1 = a*pd[2*j+1]; }
      else{
        unsigned xu = *reinterpret_cast<const unsigned*>(&Xb[base+g]);
        xv0 = bf2f((u16)(xu & 0xffffu)) + a*pd[2*j];
        xv1 = bf2f((u16)(xu >> 16))     + a*pd[2*j+1];
      }
      *reinterpret_cast<unsigned*>(&Xb[base+g]) =
          (unsigned)f2bf(xv0) | ((unsigned)f2bf(xv1) << 16);
      *reinterpret_cast<unsigned*>(&Rb[base+g]) =
          (unsigned)f2bf(rv0) | ((unsigned)f2bf(rv1) << 16);
    }
    float rz2 = blockSumBcast(rz2p);
    float beta = rz2 / fmaxf(rzv, 1e-30f);
    #pragma unroll
    for(int j=0;j<6;j++){
      int g = 2*(t + j*256);
      float p0 = rn[2*j]   + beta*pd[2*j];
      float p1 = rn[2*j+1] + beta*pd[2*j+1];
      unsigned pk = (unsigned)f2bf(rs[g]*p0) | ((unsigned)f2bf(rs[g+1]*p1) << 16);
      *reinterpret_cast<unsigned*>(&Pdb[base+g]) = pk;
    }
    if(t==0) rz[p] = rz2;
  } else {
    // write interleaved (ch0, ch1) output pairs, coalesced 16B NT
    #pragma unroll
    for(int j=0;j<6;j++){
      int g = 2*(t + j*256);
      unsigned xu = *reinterpret_cast<const unsigned*>(&Xb[base+g]);
      f32x2 dv = *reinterpret_cast<const f32x2*>(&D2P[base+g]);
      f32x4 o;
      o[0] = (1.0f - ALPHA_C) * (bf2f((u16)(xu & 0xffffu)) + a*pd[2*j])   * rs[g];
      o[1] = dv[0];
      o[2] = (1.0f - ALPHA_C) * (bf2f((u16)(xu >> 16))     + a*pd[2*j+1]) * rs[g+1];
      o[3] = dv[1];
      __builtin_nontemporal_store(o, reinterpret_cast<f32x4*>(outpg + (base+g)*2));
    }
  }
}

// ---- final gg output: read Kb, emit (e, g1*d2) f32 pairs, coalesced ------
__global__ void k_ggout(const u16* __restrict__ Kb, float* __restrict__ gg,
                        const float* __restrict__ gamma, int n4){
  int i = blockIdx.x*256 + threadIdx.x;        // handles 4 elems
  if(i >= n4) return;
  float g0 = gamma[0], g1 = gamma[1];
  float ginv = -g1 / g0;                        // ch1 = g1*d2 = -g1/g0 * ln(e)
  u16x4 kv = *reinterpret_cast<const u16x4*>(Kb + (size_t)i*4);
  float e0 = bf2f(kv[0]), e1 = bf2f(kv[1]), e2 = bf2f(kv[2]), e3 = bf2f(kv[3]);
  f32x4 a, b;
  a[0] = e0; a[1] = ginv*__logf(e0);
  a[2] = e1; a[3] = ginv*__logf(e1);
  b[0] = e2; b[1] = ginv*__logf(e2);
  b[2] = e3; b[3] = ginv*__logf(e3);
  __builtin_nontemporal_store(a, reinterpret_cast<f32x4*>(gg + (size_t)i*8));
  __builtin_nontemporal_store(b, reinterpret_cast<f32x4*>(gg + (size_t)i*8 + 4));
}

extern "C" void kernel_launch(void* const* d_in, const int* in_sizes, int n_in,
                              void* d_out, int out_size, void* d_ws, size_t ws_size,
                              hipStream_t stream){
  const float* x     = (const float*)d_in[0];   // 4096x512
  const float* Wb    = (const float*)d_in[1];   // 512x512
  const float* gamma = (const float*)d_in[2];   // 2
  (void)in_sizes; (void)n_in; (void)out_size;

  float* out    = (float*)d_out;
  float* out_pg = out;                                  // [1024][3072][2] f32
  float* out_gg = out + (size_t)1024*3072*2;            // [3072][3072][2] f32
  u16*   SPb    = (u16*)out_gg;  // 4 bf16 split-K partials (25.2MB) in out_gg

  if(ws_size < WS_NEEDED){                              // diagnostic canary
    k_canary<<<1, 1, 0, stream>>>(out);
    return;
  }

  char* ws = (char*)d_ws;
  size_t off = 0;
  auto alloc = [&](size_t bytes)->char*{
    char* p = ws + off; off = (off + bytes + 255) & ~(size_t)255; return p;
  };
  // regionA: xbf(4.19MB)+wbt(0.5MB) early, reused as Rb(6.3MB) later
  char*  regionA = alloc((size_t)4096*512*2 + (size_t)512*512*2 + 512);
  u16*   xbf   = (u16*)regionA;
  u16*   wbt   = (u16*)(regionA + (size_t)4096*512*2);
  u16*   Rb    = (u16*)regionA;
  u16*   probe = (u16*)  alloc((size_t)1024*512*2);
  u16*   gal   = (u16*)  alloc((size_t)3072*512*2);
  u16*   Kb    = (u16*)  alloc((size_t)3072*3072*2);
  // atomic accumulators: np_(1024) | ng(3072) contiguous = 4096 f32
  float* np_   = (float*)alloc(1024*4);
  float* ng    = (float*)alloc(3072*4);
  float* rs    = (float*)alloc(3072*4);
  float* sq    = (float*)alloc(3072*4);
  float* rz    = (float*)alloc(1024*4);
  u16*   Xb    = (u16*)  alloc((size_t)1024*3072*2);
  float* D2P   = (float*)alloc((size_t)1024*3072*4);
  u16*   Pdb   = (u16*)  alloc((size_t)1024*3072*2);

  // 1. fused prep: x->bf16, Wb transpose->bf16, zero norm accumulators
  k_prep<<<1280, 256, 0, stream>>>(x, Wb, xbf, wbt, np_);

  // 2. f = x@Wb -> probe/gal bf16 rows + fused row norms (atomics)
  k_gemm<<<128, 256, 0, stream>>>(0, xbf, wbt, 512, 4, 128, 512,
      nullptr, nullptr, nullptr, probe, gal, nullptr, np_, ng, nullptr);

  // 3. MERGED distances: gg upper-triangle (300 blk, LDS-mirror) -> Kb |
  //    pg (192 blk) -> D2P
  k_gemm<<<492, 256, 0, stream>>>(4, gal, gal, 512, 24, 492, 512,
      ng, ng, gamma, Kb, probe, D2P, nullptr, nullptr, np_);

  // 4. off-diag row sums of Kb -> rs = d^{-1/2}, sq = d^{1/2}
  k_rowsum<<<3072, 256, 0, stream>>>(Kb, rs, sq);

  // 5. CG init from D2P (e recomputed; Rb = bf16(sq*e), Pdb = bf16(e), rz)
  k_rzinit<<<1024, 256, 0, stream>>>(D2P, sq, Rb, Pdb, rz, gamma);

  // 6. CG on (I - alpha*S); matvec split-K=4 -> bf16 cached partials
  //    last cgstep writes out_pg directly (both channels)
  for(int it = 0; it < NITER; ++it){
    k_gemm<<<768, 256, 0, stream>>>(3, Pdb, Kb, 3072, 24, 192, 768,
        nullptr, nullptr, nullptr, SPb, nullptr, nullptr, nullptr, nullptr, nullptr);
    k_cgstep<<<1024, 256, 0, stream>>>(SPb, Pdb, Rb, Xb, rz, rs, sq,
        D2P, out_pg, it==0 ? 1 : 0, it==NITER-1 ? 1 : 0);
  }

  // 7. regenerate gg output pairs from Kb (coalesced streaming writes)
  k_ggout<<<9216, 256, 0, stream>>>(Kb, out_gg, gamma, 3072*3072/4);
}